// Round 38
// baseline (139.440 us; speedup 1.0000x reference)
//
#include <hip/hip_runtime.h>
#include <math.h>

// Problem constants (from reference)
#define BB   8      // batch
#define MM   4      // MAXM
#define DD   128    // DIM
#define NHH  8      // heads
#define QDD  16     // head dim
#define NN   256    // H*W
#define KO   128    // NH*QD
#define DTILE 8     // D-rows per out_kernel block

typedef float v2f __attribute__((ext_vector_type(2)));
#define PKFMA(a, b, c) __builtin_elementwise_fma((a), (b), (c))

typedef __attribute__((ext_vector_type(8))) short bf16x8;   // 8 bf16 (4 VGPR)
typedef __attribute__((ext_vector_type(4))) float f32x4;    // MFMA acc

__device__ inline unsigned short f2bf(float f) {            // RNE float->bf16
    union { float f; unsigned u; } v; v.f = f;
    unsigned r = v.u + 0x7FFF + ((v.u >> 16) & 1);
    return (unsigned short)(r >> 16);
}
__device__ inline float bf2f(unsigned short h) {
    union { unsigned u; float f; } v; v.u = ((unsigned)h) << 16;
    return v.f;
}
// split x = hi + lo (both bf16)
__device__ inline void bfsplit(float x, unsigned short& hi, unsigned short& lo) {
    hi = f2bf(x);
    lo = f2bf(x - bf2f(hi));
}
// e_mfma: (br | -bi<<16) -> (bi | br<<16)
__device__ inline bf16x8 derive_im(bf16x8 v) {
    union { bf16x8 v; unsigned u[4]; } in, out;
    in.v = v;
#pragma unroll
    for (int w = 0; w < 4; ++w)
        out.u[w] = ((in.u[w] >> 16) ^ 0x8000u) | (in.u[w] << 16);
    return out.v;
}
// a_mfma: (kx | ky<<16) -> (ky | (-kx)<<16)
__device__ inline bf16x8 derive_im2(bf16x8 v) {
    union { bf16x8 v; unsigned u[4]; } in, out;
    in.v = v;
#pragma unroll
    for (int w = 0; w < 4; ++w)
        out.u[w] = (in.u[w] >> 16) | ((in.u[w] ^ 0x8000u) << 16);
    return out.v;
}

// ---------------------------------------------------------------------------
// Kernel 0 (trig-free): pe[m,i,j] = exp(i*m*theta) = ((dx+i*dy)/r)^m.
// ---------------------------------------------------------------------------
__global__ void pe_kernel(float2* __restrict__ peIJ) {
    int bid = blockIdx.x;           // m*N + i
    int m = bid >> 8;
    int i = bid & 255;
    int j = threadIdx.x;
    float dy = (float)((j >> 4) - (i >> 4));
    float dx = (float)((j & 15) - (i & 15));
    float r2 = dx * dx + dy * dy;
    float c1 = 1.f, s1 = 0.f;
    if (r2 > 0.f) {
        float rinv = rsqrtf(r2);
        c1 = dx * rinv; s1 = dy * rinv;
    }
    float c = 1.f, s = 0.f;
    for (int k = 0; k < m; ++k) {   // m is block-uniform (0..3)
        float nc = c * c1 - s * s1;
        s = c * s1 + s * c1;
        c = nc;
    }
    peIJ[(m * NN + i) * NN + j] = make_float2(c, s);
}

// ---------------------------------------------------------------------------
// Kernel 1 (merged convA+convB): blocks 0..95 = convA (emb -> A' split-bf16),
// blocks 96..351 = convB (x -> Bre split-bf16; Bim derived in e_mfma).
// ---------------------------------------------------------------------------
__global__ void convAB_kernel(const float* __restrict__ er, const float* __restrict__ ei,
                              const float* __restrict__ xr, const float* __restrict__ xi,
                              unsigned int* __restrict__ AbfHi, unsigned int* __restrict__ AbfLo,
                              unsigned int* __restrict__ BreHi, unsigned int* __restrict__ BreLo) {
    if (blockIdx.x < 96) {
        int tmh = blockIdx.x;             // 0..95
        int base = tmh * QDD * DD;
#pragma unroll
        for (int it = 0; it < 8; ++it) {
            int idx = threadIdx.x + it * 256;  // q*128+D
            float ar = er[base + idx];
            float ai = ei[base + idx];
            unsigned short arh, arl, aih, ail;
            bfsplit(ar, arh, arl);
            bfsplit(ai, aih, ail);
            AbfHi[base + idx] = (unsigned int)arh | ((unsigned int)aih << 16);
            AbfLo[base + idx] = (unsigned int)arl | ((unsigned int)ail << 16);
        }
        return;
    }
    int bid = blockIdx.x - 96;            // 0..255 = 32 bm x 8 Dg
    int bm = bid >> 3;
    int Dg = bid & 7;
    int D0 = Dg * 16;
    int tid = threadIdx.x;

    __shared__ float sxr[16][257];
    __shared__ float sxi[16][257];

    const float* xrp = xr + (size_t)bm * DD * NN;
    const float* xip = xi + (size_t)bm * DD * NN;
#pragma unroll
    for (int it = 0; it < 16; ++it) {
        int i2 = tid + it * 256;
        int r = i2 >> 8, c = i2 & 255;
        sxr[r][c] = xrp[(size_t)(D0 + r) * NN + c];
        sxi[r][c] = xip[(size_t)(D0 + r) * NN + c];
    }
    __syncthreads();

    int n = tid;
    unsigned int reh[16], rel_[16];
#pragma unroll
    for (int d = 0; d < 16; ++d) {
        float br = sxr[d][n];
        float bi = sxi[d][n];
        unsigned short brh, brl, bih, bil;
        bfsplit(br, brh, brl);
        bfsplit(bi, bih, bil);
        reh[d]  = (unsigned int)brh | ((unsigned int)(bih ^ 0x8000) << 16);
        rel_[d] = (unsigned int)brl | ((unsigned int)(bil ^ 0x8000) << 16);
    }
    size_t ob = (size_t)bm * 32768 + (size_t)n * 128 + D0;
#pragma unroll
    for (int w = 0; w < 4; ++w) {
        ((uint4*)(BreHi + ob))[w] = make_uint4(reh[4*w], reh[4*w+1], reh[4*w+2], reh[4*w+3]);
        ((uint4*)(BreLo + ob))[w] = make_uint4(rel_[4*w], rel_[4*w+1], rel_[4*w+2], rel_[4*w+3]);
    }
}

// ---------------------------------------------------------------------------
// Kernel 2 (e_mfma v5 = v4 + FUSED qe): block = (pair, h, nhalf). 512 blocks.
// ---------------------------------------------------------------------------
__global__ __launch_bounds__(256, 2)
void e_mfma_kernel(const unsigned short* __restrict__ AbfHi,
                   const unsigned short* __restrict__ AbfLo,
                   const unsigned short* __restrict__ BreHi,
                   const unsigned short* __restrict__ BreLo,
                   const float* __restrict__ encr, const float* __restrict__ enci,
                   float2* __restrict__ E,
                   float2* __restrict__ QE,
                   unsigned int* __restrict__ EaHi, unsigned int* __restrict__ EaLo,
                   unsigned int* __restrict__ KbHi, unsigned int* __restrict__ KbLo) {
    int bid = blockIdx.x;                 // 512 = 8 xcd x 64 idx
    int xcd = bid & 7;
    int idx = bid >> 3;                   // 0..63
    int pair = xcd * 4 + (idx & 3);       // b*MM+m (XCD-pinned B panels)
    int h = (idx >> 2) & 7;               // 0..7
    int nhalf = idx >> 5;                 // 0..1
    int b = pair >> 2, m = pair & 3;
    int tid = threadIdx.x;
    int wav = tid >> 6, lane = tid & 63;
    int lo = lane & 15, hi = lane >> 4;

    const unsigned short* AH[3];
    const unsigned short* AL[3];
#pragma unroll
    for (int t = 0; t < 3; ++t) {
        size_t aoff = ((size_t)((t * MM + m) * NHH + h)) * QDD * 256;
        AH[t] = AbfHi + aoff;
        AL[t] = AbfLo + aoff;
    }
    size_t boff = (size_t)pair * 256 * 256;
    const unsigned short* BrH = BreHi + boff;
    const unsigned short* BrL = BreLo + boff;

    f32x4 accRe[3][2], accIm[3][2];
#pragma unroll
    for (int t = 0; t < 3; ++t)
#pragma unroll
        for (int nt = 0; nt < 2; ++nt) {
            accRe[t][nt] = (f32x4)(0.f);
            accIm[t][nt] = (f32x4)(0.f);
        }

#pragma unroll
    for (int ks = 0; ks < 8; ++ks) {
        int k0 = ks * 32;
        int arow = lo * 256 + k0 + hi * 8;
        bf16x8 aH[3], aL[3];
#pragma unroll
        for (int t = 0; t < 3; ++t) {
            aH[t] = *(const bf16x8*)(AH[t] + arow);
            aL[t] = *(const bf16x8*)(AL[t] + arow);
        }
#pragma unroll
        for (int nt = 0; nt < 2; ++nt) {
            int n0 = nhalf * 128 + (wav * 2 + nt) * 16;
            size_t brow = (size_t)(n0 + lo) * 256 + k0 + hi * 8;
            bf16x8 brh = *(const bf16x8*)(BrH + brow);
            bf16x8 brl = *(const bf16x8*)(BrL + brow);
            bf16x8 bih = derive_im(brh);
            bf16x8 bil = derive_im(brl);
#pragma unroll
            for (int t = 0; t < 3; ++t) {
                accRe[t][nt] = __builtin_amdgcn_mfma_f32_16x16x32_bf16(aH[t], brh, accRe[t][nt], 0, 0, 0);
                accRe[t][nt] = __builtin_amdgcn_mfma_f32_16x16x32_bf16(aH[t], brl, accRe[t][nt], 0, 0, 0);
                accRe[t][nt] = __builtin_amdgcn_mfma_f32_16x16x32_bf16(aL[t], brh, accRe[t][nt], 0, 0, 0);
                accIm[t][nt] = __builtin_amdgcn_mfma_f32_16x16x32_bf16(aH[t], bih, accIm[t][nt], 0, 0, 0);
                accIm[t][nt] = __builtin_amdgcn_mfma_f32_16x16x32_bf16(aH[t], bil, accIm[t][nt], 0, 0, 0);
                accIm[t][nt] = __builtin_amdgcn_mfma_f32_16x16x32_bf16(aL[t], bih, accIm[t][nt], 0, 0, 0);
            }
        }
    }

    int bh = b * NHH + h;

    // --- fused qe: QE[b,m,h,i] = sum_q conj(E0[q,i])*enc0[m,h,q] ---
    {
        float cr[4], ci[4];
#pragma unroll
        for (int reg = 0; reg < 4; ++reg) {
            int q = hi * 4 + reg;
            int eb = (m * NHH + h) * QDD + q;
            cr[reg] = encr[eb];
            ci[reg] = enci[eb];
        }
#pragma unroll
        for (int nt = 0; nt < 2; ++nt) {
            int n0 = nhalf * 128 + (wav * 2 + nt) * 16;
            float sr = 0.f, si = 0.f;
#pragma unroll
            for (int reg = 0; reg < 4; ++reg) {
                float erv = accRe[0][nt][reg];
                float eiv = accIm[0][nt][reg];
                sr = fmaf(erv, cr[reg], fmaf( eiv, ci[reg], sr));
                si = fmaf(erv, ci[reg], fmaf(-eiv, cr[reg], si));
            }
            sr += __shfl_xor(sr, 16); si += __shfl_xor(si, 16);
            sr += __shfl_xor(sr, 32); si += __shfl_xor(si, 32);
            if (hi == 0)
                QE[(size_t)((b * MM + m) * NHH + h) * NN + n0 + lo] = make_float2(sr, si);
        }
    }

    // t=0: Ea fragments ; t=1: Kb fragments ; t=2: E float2 (V).
#pragma unroll
    for (int t = 0; t < 3; ++t) {
        size_t ebase = (size_t)((((t * BB + b) * MM + m) * NHH + h) * QDD) * NN;
#pragma unroll
        for (int nt = 0; nt < 2; ++nt) {
            int n0 = nhalf * 128 + (wav * 2 + nt) * 16;
            if (t == 2) {
#pragma unroll
                for (int reg = 0; reg < 4; ++reg) {
                    int q = hi * 4 + reg;
                    E[ebase + (size_t)q * NN + n0 + lo] =
                        make_float2(accRe[t][nt][reg], accIm[t][nt][reg]);
                }
            }
            if (t < 2) {
                unsigned int hiU[4], loU[4];
#pragma unroll
                for (int reg = 0; reg < 4; ++reg) {
                    unsigned short rh, rl, ih, il;
                    bfsplit(accRe[t][nt][reg], rh, rl);
                    bfsplit(accIm[t][nt][reg], ih, il);
                    hiU[reg] = (unsigned int)rh | ((unsigned int)ih << 16);
                    loU[reg] = (unsigned int)rl | ((unsigned int)il << 16);
                }
                int r = n0 >> 4;
                size_t fo = (size_t)bh * 16384 + (size_t)((r * 4 + m) * 64 + lane) * 4;
                unsigned int* tH = (t == 0) ? EaHi : KbHi;
                unsigned int* tL = (t == 0) ? EaLo : KbLo;
                *(uint4*)(tH + fo) = make_uint4(hiU[0], hiU[1], hiU[2], hiU[3]);
                *(uint4*)(tL + fo) = make_uint4(loU[0], loU[1], loU[2], loU[3]);
            }
        }
    }
}

// ---------------------------------------------------------------------------
// Kernel 3 (a_mfma v6 = r33's v4 + MAGNITUDE-ONLY store): 512 blocks.
// Downstream only needs |A|; write Smag float (halves Scores traffic).
// ---------------------------------------------------------------------------
__global__ __launch_bounds__(256, 2)
void a_mfma_kernel(const unsigned short* __restrict__ EaHi,
                   const unsigned short* __restrict__ EaLo,
                   const unsigned short* __restrict__ KbHi,
                   const unsigned short* __restrict__ KbLo,
                   const float2* __restrict__ QE,
                   const float2* __restrict__ peIJ,
                   float* __restrict__ Smag) {
    int bid = blockIdx.x;                 // 512 = 8 xcd x 64 idx
    int xcd = bid & 7;
    int idx = bid >> 3;                   // 0..63
    int bh = xcd * 8 + (idx & 7);         // K-panel XCD-pinned
    int iquad = (idx >> 3) & 3;           // 0..3
    int jhalf = idx >> 5;                 // 0..1
    int b = bh >> 3, h = bh & 7;
    int tid = threadIdx.x;
    int wav = tid >> 6, lane = tid & 63;
    int lo = lane & 15, hi = lane >> 4;
    int it = iquad * 4 + wav;             // this wave's i-tile (0..15)

    const unsigned short* EaH = EaHi + (size_t)bh * 32768;
    const unsigned short* EaL = EaLo + (size_t)bh * 32768;
    const unsigned short* KbH = KbHi + (size_t)bh * 32768;
    const unsigned short* KbL = KbLo + (size_t)bh * 32768;

    f32x4 accRe[8], accIm[8];
#pragma unroll
    for (int nt = 0; nt < 8; ++nt) { accRe[nt] = (f32x4)(0.f); accIm[nt] = (f32x4)(0.f); }

#pragma unroll
    for (int ks = 0; ks < 4; ++ks) {
        size_t arow = (size_t)((it * 4 + ks) * 64 + lane) * 8;   // coalesced
        bf16x8 aH = *(const bf16x8*)(EaH + arow);
        bf16x8 aL = *(const bf16x8*)(EaL + arow);
#pragma unroll
        for (int nt = 0; nt < 8; ++nt) {
            int jt = jhalf * 8 + nt;
            size_t brow = (size_t)((jt * 4 + ks) * 64 + lane) * 8;  // coalesced
            bf16x8 brh = *(const bf16x8*)(KbH + brow);
            bf16x8 brl = *(const bf16x8*)(KbL + brow);
            bf16x8 bih = derive_im2(brh);
            bf16x8 bil = derive_im2(brl);
            accRe[nt] = __builtin_amdgcn_mfma_f32_16x16x32_bf16(aH, brh, accRe[nt], 0, 0, 0);
            accRe[nt] = __builtin_amdgcn_mfma_f32_16x16x32_bf16(aH, brl, accRe[nt], 0, 0, 0);
            accRe[nt] = __builtin_amdgcn_mfma_f32_16x16x32_bf16(aL, brh, accRe[nt], 0, 0, 0);
            accIm[nt] = __builtin_amdgcn_mfma_f32_16x16x32_bf16(aH, bih, accIm[nt], 0, 0, 0);
            accIm[nt] = __builtin_amdgcn_mfma_f32_16x16x32_bf16(aH, bil, accIm[nt], 0, 0, 0);
            accIm[nt] = __builtin_amdgcn_mfma_f32_16x16x32_bf16(aL, bih, accIm[nt], 0, 0, 0);
        }
    }

    // epilogue: + sum_m QE[b,m,h,i]*pe[m,i,j]; write |A|/4 only.
    float2 qe[MM][4];
#pragma unroll
    for (int m = 0; m < MM; ++m)
#pragma unroll
        for (int reg = 0; reg < 4; ++reg) {
            int i = it * 16 + hi * 4 + reg;
            qe[m][reg] = QE[(size_t)((b * MM + m) * NHH + h) * NN + i];
        }

#pragma unroll
    for (int nt = 0; nt < 8; ++nt) {
#pragma unroll
        for (int reg = 0; reg < 4; ++reg) {
            int i = it * 16 + hi * 4 + reg;
            int j = (jhalf * 8 + nt) * 16 + lo;
            float ar = accRe[nt][reg];
            float ai = accIm[nt][reg];
#pragma unroll
            for (int m = 0; m < MM; ++m) {
                float2 p = peIJ[(size_t)(m * NN + i) * NN + j];
                float2 e1 = qe[m][reg];
                ar = fmaf(e1.x, p.x, fmaf(-e1.y, p.y, ar));
                ai = fmaf(e1.x, p.y, fmaf( e1.y, p.x, ai));
            }
            Smag[(size_t)(bh * NN + i) * NN + j] = sqrtf(fmaf(ar, ar, ai * ai)) * 0.25f;
        }
    }
}

// ---------------------------------------------------------------------------
// Kernel 4 (v4: float Smag input, LDS-tiled transpose + fused PA).
// ---------------------------------------------------------------------------
__global__ void softmax_kernel(const float* __restrict__ Smag,
                               const float2* __restrict__ peIJ,
                               float* __restrict__ AwT,
                               float2* __restrict__ PA) {
    int bid = blockIdx.x;                 // bh*16 + itile
    int bh = bid >> 4;
    int itile = bid & 15;
    int i0 = itile * 16;
    int tid = threadIdx.x;
    int ri = tid >> 4;                    // 0..15 row in tile
    int ci = tid & 15;                    // col group
    int i = i0 + ri;

    __shared__ float st[16][257];

    // load 16 cols of row i (already |A|/4)
    const float* ap = Smag + (size_t)(bh * NN + i) * NN + ci * 16;
    float vv[16];
    float mx = -3.4e38f;
#pragma unroll
    for (int k = 0; k < 16; ++k) {
        vv[k] = ap[k];
        mx = fmaxf(mx, vv[k]);
    }
    // row max across 16 lanes
#pragma unroll
    for (int off = 1; off < 16; off <<= 1) mx = fmaxf(mx, __shfl_xor(mx, off));
    // exp + sum
    float sm = 0.f;
#pragma unroll
    for (int k = 0; k < 16; ++k) { vv[k] = __expf(vv[k] - mx); sm += vv[k]; }
#pragma unroll
    for (int off = 1; off < 16; off <<= 1) sm += __shfl_xor(sm, off);
    float inv = 1.f / sm;

    // aw -> LDS; fused PA partials
    float par[MM], pai[MM];
#pragma unroll
    for (int m = 0; m < MM; ++m) { par[m] = 0.f; pai[m] = 0.f; }
#pragma unroll
    for (int k = 0; k < 16; ++k) {
        float aw = vv[k] * inv;
        st[ri][ci * 16 + k] = aw;
#pragma unroll
        for (int m = 0; m < MM; ++m) {
            float2 p = peIJ[(size_t)(m * NN + i) * NN + ci * 16 + k];
            par[m] = fmaf(p.x, aw, par[m]);
            pai[m] = fmaf(p.y, aw, pai[m]);
        }
    }
#pragma unroll
    for (int m = 0; m < MM; ++m) {
#pragma unroll
        for (int off = 1; off < 16; off <<= 1) {
            par[m] += __shfl_xor(par[m], off);
            pai[m] += __shfl_xor(pai[m], off);
        }
    }
    if (ci == 0) {
        int b = bh >> 3, h = bh & 7;
#pragma unroll
        for (int m = 0; m < MM; ++m)
            PA[(size_t)((b * MM + m) * NHH + h) * NN + i] = make_float2(par[m], pai[m]);
    }
    __syncthreads();

    // coalesced transposed write: pass p writes j = p*16 + jg for all 16 i
    int jg = tid >> 4;                    // 0..15
    int il = tid & 15;                    // 0..15
#pragma unroll
    for (int p = 0; p < 16; ++p) {
        int j = p * 16 + jg;
        AwT[(size_t)(bh * NN + j) * NN + i0 + il] = st[il][j];
    }
}

// ---------------------------------------------------------------------------
// Kernel 5 (qh-split + XCD swizzle, PA precomputed): 512 blocks.
// ---------------------------------------------------------------------------
__global__ __launch_bounds__(512)
void res_kernel(const float2* __restrict__ E, const float* __restrict__ AwT,
                const float2* __restrict__ PA,
                const float* __restrict__ encr, const float* __restrict__ enci,
                float2* __restrict__ Res) {
    int bid = blockIdx.x;
    int xcd = bid & 7;
    int idx = bid >> 3;                   // 0..63
    int bh = xcd * 8 + (idx & 7);         // b*NHH+h
    int mqh = idx >> 3;                   // 0..7
    int m  = mqh >> 1;
    int qh = mqh & 1;
    int h = bh & 7;
    int b = bh >> 3;
    int i = threadIdx.x & 255;
    int g = threadIdx.x >> 8;             // j-half 0/1

    __shared__ float2 sv[8][NN];          // 16 KB: this qh's 8 V rows
    __shared__ float2 spA[NN][8];         // 16 KB: g=1 partials (8 acc)
    __shared__ float2 senc[8];

    const float2* V = E + ((size_t)(((2 * BB + b) * MM + m) * NHH + h) * QDD + qh * 8) * NN;
    for (int i2 = threadIdx.x; i2 < 8 * NN; i2 += 512) sv[i2 >> 8][i2 & 255] = V[i2];
    if (threadIdx.x < 8) {
        int eb = ((MM + m) * NHH + h) * QDD + qh * 8 + threadIdx.x;   // enc[1,...]
        senc[threadIdx.x] = make_float2(encr[eb], enci[eb]);
    }
    __syncthreads();

    float accr[8], acci[8];
#pragma unroll
    for (int q = 0; q < 8; ++q) { accr[q] = 0.f; acci[q] = 0.f; }

    const float* awp = AwT + (size_t)((b * NHH + h) * NN) * NN + i;
    int j0 = g * (NN / 2);
    for (int j = j0; j < j0 + NN / 2; ++j) {
        float aw = awp[(size_t)j * NN];       // coalesced over i
#pragma unroll
        for (int q = 0; q < 8; ++q) {
            float2 vv = sv[q][j];             // wave-uniform -> broadcast
            accr[q] = fmaf(vv.x, aw, accr[q]);
            acci[q] = fmaf(vv.y, aw, acci[q]);
        }
    }

    if (g == 1) {
#pragma unroll
        for (int q = 0; q < 8; ++q) spA[i][q] = make_float2(accr[q], acci[q]);
    }
    __syncthreads();
    if (g == 0) {
#pragma unroll
        for (int q = 0; q < 8; ++q) {
            float2 o = spA[i][q];
            accr[q] += o.x; acci[q] += o.y;
        }
        float2 pa = PA[(size_t)((b * MM + m) * NHH + h) * NN + i];
        float par = pa.x, pai = pa.y;

        float2* rp = Res + ((size_t)((b * MM + m) * KO + h * QDD + qh * 8)) * NN + i;
#pragma unroll
        for (int q = 0; q < 8; ++q) {
            float2 e1 = senc[q];
            float rr = accr[q] + e1.x * par - e1.y * pai;
            float ri = acci[q] + e1.x * pai + e1.y * par;
            rp[(size_t)q * NN] = make_float2(rr, ri);
        }
    }
}

// ---------------------------------------------------------------------------
// Kernel 6 (DTILE=8 + XCD swizzle): out[b,m,D,n] = sum_k w_out*res.
// ---------------------------------------------------------------------------
__global__ void out_kernel(const float2* __restrict__ Res,
                           const float* __restrict__ wor, const float* __restrict__ woi,
                           float* __restrict__ out) {
    int bid = blockIdx.x;
    int xcd = bid & 7;
    int idx = bid >> 3;                   // 0..63
    int bm = xcd * 4 + (idx & 3);         // b*MM+m, 0..31
    int dt = idx >> 2;                    // 0..15
    int n = threadIdx.x;
    int D0 = dt * DTILE;
    int m = bm & 3;

    __shared__ float2 sw[DTILE][KO];      // 8 KB
    for (int i2 = threadIdx.x; i2 < DTILE * KO; i2 += 256) {
        int d = i2 >> 7, k = i2 & 127;
        int wb = (m * DD + D0 + d) * KO + k;
        sw[d][k] = make_float2(wor[wb], woi[wb]);
    }
    __syncthreads();

    const float2* rp = Res + (size_t)(bm * KO) * NN + n;
    float ar[DTILE], ai[DTILE];
#pragma unroll
    for (int d = 0; d < DTILE; ++d) { ar[d] = 0.f; ai[d] = 0.f; }

    for (int k = 0; k < KO; ++k) {
        float2 r = rp[(size_t)k * NN];    // coalesced
#pragma unroll
        for (int d = 0; d < DTILE; ++d) {
            float2 w = sw[d][k];          // broadcast
            ar[d] = fmaf(w.x, r.x, fmaf(-w.y, r.y, ar[d]));
            ai[d] = fmaf(w.x, r.y, fmaf( w.y, r.x, ai[d]));
        }
    }
#pragma unroll
    for (int d = 0; d < DTILE; ++d) {
        size_t ob = (size_t)(bm * DD + D0 + d) * NN + n;
        out[ob] = ar[d];
        out[(size_t)BB * MM * DD * NN + ob] = ai[d];
    }
}

// ---------------------------------------------------------------------------
extern "C" void kernel_launch(void* const* d_in, const int* in_sizes, int n_in,
                              void* d_out, int out_size, void* d_ws, size_t ws_size,
                              hipStream_t stream) {
    (void)in_sizes; (void)n_in; (void)out_size; (void)ws_size;

    const float* x_re   = (const float*)d_in[0];
    const float* x_im   = (const float*)d_in[1];
    const float* emb_re = (const float*)d_in[2];
    const float* emb_im = (const float*)d_in[3];
    const float* enc_re = (const float*)d_in[4];
    const float* enc_im = (const float*)d_in[5];
    const float* out_re = (const float*)d_in[6];
    const float* out_im = (const float*)d_in[7];
    float* out = (float*)d_out;

    // Workspace layout (floats). Total ~155.7 MB.
    float* ws = (float*)d_ws;
    size_t off = 0;
    float2* peIJ = (float2*)(ws + off); off += (size_t)MM * NN * NN * 2;          // 524288
    float2* peT  = (float2*)(ws + off); off += (size_t)MM * NN * NN * 2;          // 524288 (dead; hosts PA)
    float2* E    = (float2*)(ws + off); off += (size_t)3 * BB * MM * NHH * QDD * NN * 2; // 25165824
    float2* QE   = (float2*)(ws + off); off += (size_t)BB * MM * NHH * NN * 2;    // 131072
    float2* A    = (float2*)(ws + off); off += (size_t)BB * NHH * NN * NN * 2;    // 8388608 fl
    float*  AwT  = (float*)(ws + off);  off += (size_t)BB * NHH * NN * NN;        // 4194304 fl

    // Region plan (r36-verified; Scores float2 -> Smag float, same region):
    //  1) convAB stages Abf/Bre in A region; e_mfma reads them ->
    //     writes E t2 (V) float2 + QE + Ea/Kb fragments into AwT region.
    //  2) a_mfma reads Ea/Kb(AwT region) -> Smag (16.8MB) in A region.
    //  3) softmax reads Smag(A)+peIJ -> writes AwT + PA (Ea/Kb dead).
    //  4) res reads AwT + PA + V(E t2) -> Res into A region start (Smag dead).
    unsigned int* AbfHi = (unsigned int*)A;
    unsigned int* AbfLo = AbfHi + (size_t)96 * QDD * DD;
    unsigned int* BreHi = AbfLo + (size_t)96 * QDD * DD;
    unsigned int* BreLo = BreHi + (size_t)32 * 256 * 128;

    unsigned int* EaHi = (unsigned int*)AwT;                      // 4 x 1048576 uints
    unsigned int* EaLo = EaHi + (size_t)64 * 16384;               //  = 16.78MB exact
    unsigned int* KbHi = EaLo + (size_t)64 * 16384;
    unsigned int* KbLo = KbHi + (size_t)64 * 16384;

    float*  Smag = (float*)A;   // 16.8MB in 33.5MB A region
    float2* Res  = A;           // first 8.4MB of A region, after Smag is dead
    float2* PA   = peT;         // 1MB needed; peT region (2MB) is dead

    pe_kernel<<<MM * NN, 256, 0, stream>>>(peIJ);
    convAB_kernel<<<96 + 256, 256, 0, stream>>>(emb_re, emb_im, x_re, x_im,
                                                AbfHi, AbfLo, BreHi, BreLo);
    e_mfma_kernel<<<512, 256, 0, stream>>>(
        (const unsigned short*)AbfHi, (const unsigned short*)AbfLo,
        (const unsigned short*)BreHi, (const unsigned short*)BreLo,
        enc_re, enc_im, E, QE,
        EaHi, EaLo, KbHi, KbLo);
    a_mfma_kernel<<<512, 256, 0, stream>>>(
        (const unsigned short*)EaHi, (const unsigned short*)EaLo,
        (const unsigned short*)KbHi, (const unsigned short*)KbLo,
        QE, peIJ, Smag);
    softmax_kernel<<<BB * NHH * 16, 256, 0, stream>>>(Smag, peIJ, AwT, PA);
    res_kernel<<<BB * MM * NHH * 2, 512, 0, stream>>>(E, AwT, PA, enc_re, enc_im, Res);
    out_kernel<<<BB * MM * (DD / DTILE), 256, 0, stream>>>(Res, out_re, out_im, out);
}

// Round 39
// 115.482 us; speedup vs baseline: 1.2075x; 1.2075x over previous
//
#include <hip/hip_runtime.h>
#include <math.h>

// Problem constants (from reference)
#define BB   8      // batch
#define MM   4      // MAXM
#define DD   128    // DIM
#define NHH  8      // heads
#define QDD  16     // head dim
#define NN   256    // H*W
#define KO   128    // NH*QD
#define DTILE 8     // D-rows per out_kernel block

typedef float v2f __attribute__((ext_vector_type(2)));

typedef __attribute__((ext_vector_type(8))) short bf16x8;   // 8 bf16 (4 VGPR)
typedef __attribute__((ext_vector_type(4))) float f32x4;    // MFMA acc

__device__ inline unsigned short f2bf(float f) {            // RNE float->bf16
    union { float f; unsigned u; } v; v.f = f;
    unsigned r = v.u + 0x7FFF + ((v.u >> 16) & 1);
    return (unsigned short)(r >> 16);
}
__device__ inline float bf2f(unsigned short h) {
    union { unsigned u; float f; } v; v.u = ((unsigned)h) << 16;
    return v.f;
}
// split x = hi + lo (both bf16)
__device__ inline void bfsplit(float x, unsigned short& hi, unsigned short& lo) {
    hi = f2bf(x);
    lo = f2bf(x - bf2f(hi));
}
// e_mfma: (br | -bi<<16) -> (bi | br<<16)
__device__ inline bf16x8 derive_im(bf16x8 v) {
    union { bf16x8 v; unsigned u[4]; } in, out;
    in.v = v;
#pragma unroll
    for (int w = 0; w < 4; ++w)
        out.u[w] = ((in.u[w] >> 16) ^ 0x8000u) | (in.u[w] << 16);
    return out.v;
}
// a_mfma: (kx | ky<<16) -> (ky | (-kx)<<16)
__device__ inline bf16x8 derive_im2(bf16x8 v) {
    union { bf16x8 v; unsigned u[4]; } in, out;
    in.v = v;
#pragma unroll
    for (int w = 0; w < 4; ++w)
        out.u[w] = (in.u[w] >> 16) | ((in.u[w] ^ 0x8000u) << 16);
    return out.v;
}

// ---------------------------------------------------------------------------
// Kernel 0 (trig-free): pe[m,i,j] = exp(i*m*theta) = ((dx+i*dy)/r)^m.
// ---------------------------------------------------------------------------
__global__ void pe_kernel(float2* __restrict__ peIJ) {
    int bid = blockIdx.x;           // m*N + i
    int m = bid >> 8;
    int i = bid & 255;
    int j = threadIdx.x;
    float dy = (float)((j >> 4) - (i >> 4));
    float dx = (float)((j & 15) - (i & 15));
    float r2 = dx * dx + dy * dy;
    float c1 = 1.f, s1 = 0.f;
    if (r2 > 0.f) {
        float rinv = rsqrtf(r2);
        c1 = dx * rinv; s1 = dy * rinv;
    }
    float c = 1.f, s = 0.f;
    for (int k = 0; k < m; ++k) {   // m is block-uniform (0..3)
        float nc = c * c1 - s * s1;
        s = c * s1 + s * c1;
        c = nc;
    }
    peIJ[(m * NN + i) * NN + j] = make_float2(c, s);
}

// ---------------------------------------------------------------------------
// Kernel 1 (merged convA+convB): blocks 0..95 = convA (emb -> A' split-bf16),
// blocks 96..351 = convB (x -> Bre split-bf16; Bim derived in e_mfma).
// ---------------------------------------------------------------------------
__global__ void convAB_kernel(const float* __restrict__ er, const float* __restrict__ ei,
                              const float* __restrict__ xr, const float* __restrict__ xi,
                              unsigned int* __restrict__ AbfHi, unsigned int* __restrict__ AbfLo,
                              unsigned int* __restrict__ BreHi, unsigned int* __restrict__ BreLo) {
    if (blockIdx.x < 96) {
        int tmh = blockIdx.x;             // 0..95
        int base = tmh * QDD * DD;
#pragma unroll
        for (int it = 0; it < 8; ++it) {
            int idx = threadIdx.x + it * 256;  // q*128+D
            float ar = er[base + idx];
            float ai = ei[base + idx];
            unsigned short arh, arl, aih, ail;
            bfsplit(ar, arh, arl);
            bfsplit(ai, aih, ail);
            AbfHi[base + idx] = (unsigned int)arh | ((unsigned int)aih << 16);
            AbfLo[base + idx] = (unsigned int)arl | ((unsigned int)ail << 16);
        }
        return;
    }
    int bid = blockIdx.x - 96;            // 0..255 = 32 bm x 8 Dg
    int bm = bid >> 3;
    int Dg = bid & 7;
    int D0 = Dg * 16;
    int tid = threadIdx.x;

    __shared__ float sxr[16][257];
    __shared__ float sxi[16][257];

    const float* xrp = xr + (size_t)bm * DD * NN;
    const float* xip = xi + (size_t)bm * DD * NN;
#pragma unroll
    for (int it = 0; it < 16; ++it) {
        int i2 = tid + it * 256;
        int r = i2 >> 8, c = i2 & 255;
        sxr[r][c] = xrp[(size_t)(D0 + r) * NN + c];
        sxi[r][c] = xip[(size_t)(D0 + r) * NN + c];
    }
    __syncthreads();

    int n = tid;
    unsigned int reh[16], rel_[16];
#pragma unroll
    for (int d = 0; d < 16; ++d) {
        float br = sxr[d][n];
        float bi = sxi[d][n];
        unsigned short brh, brl, bih, bil;
        bfsplit(br, brh, brl);
        bfsplit(bi, bih, bil);
        reh[d]  = (unsigned int)brh | ((unsigned int)(bih ^ 0x8000) << 16);
        rel_[d] = (unsigned int)brl | ((unsigned int)(bil ^ 0x8000) << 16);
    }
    size_t ob = (size_t)bm * 32768 + (size_t)n * 128 + D0;
#pragma unroll
    for (int w = 0; w < 4; ++w) {
        ((uint4*)(BreHi + ob))[w] = make_uint4(reh[4*w], reh[4*w+1], reh[4*w+2], reh[4*w+3]);
        ((uint4*)(BreLo + ob))[w] = make_uint4(rel_[4*w], rel_[4*w+1], rel_[4*w+2], rel_[4*w+3]);
    }
}

// ---------------------------------------------------------------------------
// Kernel 2 (e_mfma v5 = v4 + FUSED qe): block = (pair, h, nhalf). 512 blocks.
// ---------------------------------------------------------------------------
__global__ __launch_bounds__(256, 2)
void e_mfma_kernel(const unsigned short* __restrict__ AbfHi,
                   const unsigned short* __restrict__ AbfLo,
                   const unsigned short* __restrict__ BreHi,
                   const unsigned short* __restrict__ BreLo,
                   const float* __restrict__ encr, const float* __restrict__ enci,
                   float2* __restrict__ E,
                   float2* __restrict__ QE,
                   unsigned int* __restrict__ EaHi, unsigned int* __restrict__ EaLo,
                   unsigned int* __restrict__ KbHi, unsigned int* __restrict__ KbLo) {
    int bid = blockIdx.x;                 // 512 = 8 xcd x 64 idx
    int xcd = bid & 7;
    int idx = bid >> 3;                   // 0..63
    int pair = xcd * 4 + (idx & 3);       // b*MM+m (XCD-pinned B panels)
    int h = (idx >> 2) & 7;               // 0..7
    int nhalf = idx >> 5;                 // 0..1
    int b = pair >> 2, m = pair & 3;
    int tid = threadIdx.x;
    int wav = tid >> 6, lane = tid & 63;
    int lo = lane & 15, hi = lane >> 4;

    const unsigned short* AH[3];
    const unsigned short* AL[3];
#pragma unroll
    for (int t = 0; t < 3; ++t) {
        size_t aoff = ((size_t)((t * MM + m) * NHH + h)) * QDD * 256;
        AH[t] = AbfHi + aoff;
        AL[t] = AbfLo + aoff;
    }
    size_t boff = (size_t)pair * 256 * 256;
    const unsigned short* BrH = BreHi + boff;
    const unsigned short* BrL = BreLo + boff;

    f32x4 accRe[3][2], accIm[3][2];
#pragma unroll
    for (int t = 0; t < 3; ++t)
#pragma unroll
        for (int nt = 0; nt < 2; ++nt) {
            accRe[t][nt] = (f32x4)(0.f);
            accIm[t][nt] = (f32x4)(0.f);
        }

#pragma unroll
    for (int ks = 0; ks < 8; ++ks) {
        int k0 = ks * 32;
        int arow = lo * 256 + k0 + hi * 8;
        bf16x8 aH[3], aL[3];
#pragma unroll
        for (int t = 0; t < 3; ++t) {
            aH[t] = *(const bf16x8*)(AH[t] + arow);
            aL[t] = *(const bf16x8*)(AL[t] + arow);
        }
#pragma unroll
        for (int nt = 0; nt < 2; ++nt) {
            int n0 = nhalf * 128 + (wav * 2 + nt) * 16;
            size_t brow = (size_t)(n0 + lo) * 256 + k0 + hi * 8;
            bf16x8 brh = *(const bf16x8*)(BrH + brow);
            bf16x8 brl = *(const bf16x8*)(BrL + brow);
            bf16x8 bih = derive_im(brh);
            bf16x8 bil = derive_im(brl);
#pragma unroll
            for (int t = 0; t < 3; ++t) {
                accRe[t][nt] = __builtin_amdgcn_mfma_f32_16x16x32_bf16(aH[t], brh, accRe[t][nt], 0, 0, 0);
                accRe[t][nt] = __builtin_amdgcn_mfma_f32_16x16x32_bf16(aH[t], brl, accRe[t][nt], 0, 0, 0);
                accRe[t][nt] = __builtin_amdgcn_mfma_f32_16x16x32_bf16(aL[t], brh, accRe[t][nt], 0, 0, 0);
                accIm[t][nt] = __builtin_amdgcn_mfma_f32_16x16x32_bf16(aH[t], bih, accIm[t][nt], 0, 0, 0);
                accIm[t][nt] = __builtin_amdgcn_mfma_f32_16x16x32_bf16(aH[t], bil, accIm[t][nt], 0, 0, 0);
                accIm[t][nt] = __builtin_amdgcn_mfma_f32_16x16x32_bf16(aL[t], bih, accIm[t][nt], 0, 0, 0);
            }
        }
    }

    int bh = b * NHH + h;

    // --- fused qe: QE[b,m,h,i] = sum_q conj(E0[q,i])*enc0[m,h,q] ---
    {
        float cr[4], ci[4];
#pragma unroll
        for (int reg = 0; reg < 4; ++reg) {
            int q = hi * 4 + reg;
            int eb = (m * NHH + h) * QDD + q;
            cr[reg] = encr[eb];
            ci[reg] = enci[eb];
        }
#pragma unroll
        for (int nt = 0; nt < 2; ++nt) {
            int n0 = nhalf * 128 + (wav * 2 + nt) * 16;
            float sr = 0.f, si = 0.f;
#pragma unroll
            for (int reg = 0; reg < 4; ++reg) {
                float erv = accRe[0][nt][reg];
                float eiv = accIm[0][nt][reg];
                sr = fmaf(erv, cr[reg], fmaf( eiv, ci[reg], sr));
                si = fmaf(erv, ci[reg], fmaf(-eiv, cr[reg], si));
            }
            sr += __shfl_xor(sr, 16); si += __shfl_xor(si, 16);
            sr += __shfl_xor(sr, 32); si += __shfl_xor(si, 32);
            if (hi == 0)
                QE[(size_t)((b * MM + m) * NHH + h) * NN + n0 + lo] = make_float2(sr, si);
        }
    }

    // t=0: Ea fragments ; t=1: Kb fragments ; t=2: E float2 (V).
#pragma unroll
    for (int t = 0; t < 3; ++t) {
        size_t ebase = (size_t)((((t * BB + b) * MM + m) * NHH + h) * QDD) * NN;
#pragma unroll
        for (int nt = 0; nt < 2; ++nt) {
            int n0 = nhalf * 128 + (wav * 2 + nt) * 16;
            if (t == 2) {
#pragma unroll
                for (int reg = 0; reg < 4; ++reg) {
                    int q = hi * 4 + reg;
                    E[ebase + (size_t)q * NN + n0 + lo] =
                        make_float2(accRe[t][nt][reg], accIm[t][nt][reg]);
                }
            }
            if (t < 2) {
                unsigned int hiU[4], loU[4];
#pragma unroll
                for (int reg = 0; reg < 4; ++reg) {
                    unsigned short rh, rl, ih, il;
                    bfsplit(accRe[t][nt][reg], rh, rl);
                    bfsplit(accIm[t][nt][reg], ih, il);
                    hiU[reg] = (unsigned int)rh | ((unsigned int)ih << 16);
                    loU[reg] = (unsigned int)rl | ((unsigned int)il << 16);
                }
                int r = n0 >> 4;
                size_t fo = (size_t)bh * 16384 + (size_t)((r * 4 + m) * 64 + lane) * 4;
                unsigned int* tH = (t == 0) ? EaHi : KbHi;
                unsigned int* tL = (t == 0) ? EaLo : KbLo;
                *(uint4*)(tH + fo) = make_uint4(hiU[0], hiU[1], hiU[2], hiU[3]);
                *(uint4*)(tL + fo) = make_uint4(loU[0], loU[1], loU[2], loU[3]);
            }
        }
    }
}

// ---------------------------------------------------------------------------
// Kernel 3 (score = FUSED a_mfma + softmax + PA): 1024 blocks = (bh, itile).
// Each block: 16 i-rows x all 256 j (4 waves x 4 j-tiles, acc 32 VGPR).
// Scores never hit memory; row softmax block-local; writes AwT (transposed,
// coalesced) + PA.
// ---------------------------------------------------------------------------
__global__ __launch_bounds__(256)
void score_kernel(const unsigned short* __restrict__ EaHi,
                  const unsigned short* __restrict__ EaLo,
                  const unsigned short* __restrict__ KbHi,
                  const unsigned short* __restrict__ KbLo,
                  const float2* __restrict__ QE,
                  const float2* __restrict__ peIJ,
                  float* __restrict__ AwT,
                  float2* __restrict__ PA) {
    int bid = blockIdx.x;                 // 1024 = 8 xcd x 128 idx
    int xcd = bid & 7;
    int idx = bid >> 3;                   // 0..127
    int bh = xcd * 8 + (idx & 7);         // K-panel XCD-pinned
    int it = idx >> 3;                    // 0..15 i-tile
    int b = bh >> 3, h = bh & 7;
    int tid = threadIdx.x;
    int wav = tid >> 6, lane = tid & 63;
    int lo = lane & 15, hi = lane >> 4;

    const unsigned short* EaH = EaHi + (size_t)bh * 32768;
    const unsigned short* EaL = EaLo + (size_t)bh * 32768;
    const unsigned short* KbH = KbHi + (size_t)bh * 32768;
    const unsigned short* KbL = KbLo + (size_t)bh * 32768;

    __shared__ float st[16][257];         // aw staging (block's 16 rows x 256 j)
    __shared__ float sredA[16][4];        // cross-wave max
    __shared__ float sredB[16][4];        // cross-wave sum
    __shared__ float sPA[16][4][2][4];    // PA partials [row][m][comp][wav]

    f32x4 accRe[4], accIm[4];
#pragma unroll
    for (int nt = 0; nt < 4; ++nt) { accRe[nt] = (f32x4)(0.f); accIm[nt] = (f32x4)(0.f); }

#pragma unroll
    for (int ks = 0; ks < 4; ++ks) {
        size_t arow = (size_t)((it * 4 + ks) * 64 + lane) * 8;   // coalesced
        bf16x8 aH = *(const bf16x8*)(EaH + arow);
        bf16x8 aL = *(const bf16x8*)(EaL + arow);
#pragma unroll
        for (int nt = 0; nt < 4; ++nt) {
            int jt = wav * 4 + nt;
            size_t brow = (size_t)((jt * 4 + ks) * 64 + lane) * 8;  // coalesced
            bf16x8 brh = *(const bf16x8*)(KbH + brow);
            bf16x8 brl = *(const bf16x8*)(KbL + brow);
            bf16x8 bih = derive_im2(brh);
            bf16x8 bil = derive_im2(brl);
            accRe[nt] = __builtin_amdgcn_mfma_f32_16x16x32_bf16(aH, brh, accRe[nt], 0, 0, 0);
            accRe[nt] = __builtin_amdgcn_mfma_f32_16x16x32_bf16(aH, brl, accRe[nt], 0, 0, 0);
            accRe[nt] = __builtin_amdgcn_mfma_f32_16x16x32_bf16(aL, brh, accRe[nt], 0, 0, 0);
            accIm[nt] = __builtin_amdgcn_mfma_f32_16x16x32_bf16(aH, bih, accIm[nt], 0, 0, 0);
            accIm[nt] = __builtin_amdgcn_mfma_f32_16x16x32_bf16(aH, bil, accIm[nt], 0, 0, 0);
            accIm[nt] = __builtin_amdgcn_mfma_f32_16x16x32_bf16(aL, bih, accIm[nt], 0, 0, 0);
        }
    }

    // pass 1: + sum_m QE*pe, magnitude. vmag[nt][reg].
    float vmag[4][4];
#pragma unroll
    for (int reg = 0; reg < 4; ++reg) {
        int i = it * 16 + hi * 4 + reg;
        float2 qe4[MM];
#pragma unroll
        for (int m = 0; m < MM; ++m)
            qe4[m] = QE[(size_t)((b * MM + m) * NHH + h) * NN + i];
#pragma unroll
        for (int nt = 0; nt < 4; ++nt) {
            int j = (wav * 4 + nt) * 16 + lo;
            float ar = accRe[nt][reg];
            float ai = accIm[nt][reg];
#pragma unroll
            for (int m = 0; m < MM; ++m) {
                float2 p = peIJ[(size_t)(m * NN + i) * NN + j];
                ar = fmaf(qe4[m].x, p.x, fmaf(-qe4[m].y, p.y, ar));
                ai = fmaf(qe4[m].x, p.y, fmaf( qe4[m].y, p.x, ai));
            }
            vmag[nt][reg] = sqrtf(fmaf(ar, ar, ai * ai)) * 0.25f;
        }
    }

    // row max: over nt regs, then 16-lane lo group, then cross-wave via LDS.
    float mxr[4];
#pragma unroll
    for (int reg = 0; reg < 4; ++reg) {
        mxr[reg] = fmaxf(fmaxf(vmag[0][reg], vmag[1][reg]),
                         fmaxf(vmag[2][reg], vmag[3][reg]));
#pragma unroll
        for (int off = 1; off < 16; off <<= 1)
            mxr[reg] = fmaxf(mxr[reg], __shfl_xor(mxr[reg], off));
    }
    if (lo == 0) {
#pragma unroll
        for (int reg = 0; reg < 4; ++reg) sredA[hi * 4 + reg][wav] = mxr[reg];
    }
    __syncthreads();
    float mx[4];
#pragma unroll
    for (int reg = 0; reg < 4; ++reg) {
        int r = hi * 4 + reg;
        mx[reg] = fmaxf(fmaxf(sredA[r][0], sredA[r][1]),
                        fmaxf(sredA[r][2], sredA[r][3]));
    }

    // exp + row sum
    float smr[4];
#pragma unroll
    for (int reg = 0; reg < 4; ++reg) smr[reg] = 0.f;
#pragma unroll
    for (int nt = 0; nt < 4; ++nt)
#pragma unroll
        for (int reg = 0; reg < 4; ++reg) {
            vmag[nt][reg] = __expf(vmag[nt][reg] - mx[reg]);
            smr[reg] += vmag[nt][reg];
        }
#pragma unroll
    for (int reg = 0; reg < 4; ++reg) {
#pragma unroll
        for (int off = 1; off < 16; off <<= 1)
            smr[reg] += __shfl_xor(smr[reg], off);
    }
    if (lo == 0) {
#pragma unroll
        for (int reg = 0; reg < 4; ++reg) sredB[hi * 4 + reg][wav] = smr[reg];
    }
    __syncthreads();
    float inv[4];
#pragma unroll
    for (int reg = 0; reg < 4; ++reg) {
        int r = hi * 4 + reg;
        inv[reg] = 1.f / (sredB[r][0] + sredB[r][1] + sredB[r][2] + sredB[r][3]);
    }

    // pass 2: aw -> st; PA partials per (m, reg row).
    float par[MM][4], pai[MM][4];
#pragma unroll
    for (int m = 0; m < MM; ++m)
#pragma unroll
        for (int reg = 0; reg < 4; ++reg) { par[m][reg] = 0.f; pai[m][reg] = 0.f; }
#pragma unroll
    for (int reg = 0; reg < 4; ++reg) {
        int i = it * 16 + hi * 4 + reg;
#pragma unroll
        for (int nt = 0; nt < 4; ++nt) {
            int j = (wav * 4 + nt) * 16 + lo;
            float aw = vmag[nt][reg] * inv[reg];
            st[hi * 4 + reg][j] = aw;
#pragma unroll
            for (int m = 0; m < MM; ++m) {
                float2 p = peIJ[(size_t)(m * NN + i) * NN + j];
                par[m][reg] = fmaf(p.x, aw, par[m][reg]);
                pai[m][reg] = fmaf(p.y, aw, pai[m][reg]);
            }
        }
    }
#pragma unroll
    for (int m = 0; m < MM; ++m)
#pragma unroll
        for (int reg = 0; reg < 4; ++reg) {
#pragma unroll
            for (int off = 1; off < 16; off <<= 1) {
                par[m][reg] += __shfl_xor(par[m][reg], off);
                pai[m][reg] += __shfl_xor(pai[m][reg], off);
            }
        }
    if (lo == 0) {
#pragma unroll
        for (int m = 0; m < MM; ++m)
#pragma unroll
            for (int reg = 0; reg < 4; ++reg) {
                sPA[hi * 4 + reg][m][0][wav] = par[m][reg];
                sPA[hi * 4 + reg][m][1][wav] = pai[m][reg];
            }
    }
    __syncthreads();

    if (tid < 16) {
        int r = tid;
#pragma unroll
        for (int m = 0; m < MM; ++m) {
            float pr  = sPA[r][m][0][0] + sPA[r][m][0][1] + sPA[r][m][0][2] + sPA[r][m][0][3];
            float pim = sPA[r][m][1][0] + sPA[r][m][1][1] + sPA[r][m][1][2] + sPA[r][m][1][3];
            PA[(size_t)((b * MM + m) * NHH + h) * NN + it * 16 + r] = make_float2(pr, pim);
        }
    }

    // coalesced transposed write: pass p writes j = p*16 + jg for 16 i.
    int jg = tid >> 4;                    // 0..15
    int il = tid & 15;                    // 0..15
#pragma unroll
    for (int p = 0; p < 16; ++p) {
        int j = p * 16 + jg;
        AwT[(size_t)(bh * NN + j) * NN + it * 16 + il] = st[il][j];
    }
}

// ---------------------------------------------------------------------------
// Kernel 5 (qh-split + XCD swizzle, PA precomputed): 512 blocks.
// ---------------------------------------------------------------------------
__global__ __launch_bounds__(512)
void res_kernel(const float2* __restrict__ E, const float* __restrict__ AwT,
                const float2* __restrict__ PA,
                const float* __restrict__ encr, const float* __restrict__ enci,
                float2* __restrict__ Res) {
    int bid = blockIdx.x;
    int xcd = bid & 7;
    int idx = bid >> 3;                   // 0..63
    int bh = xcd * 8 + (idx & 7);         // b*NHH+h
    int mqh = idx >> 3;                   // 0..7
    int m  = mqh >> 1;
    int qh = mqh & 1;
    int h = bh & 7;
    int b = bh >> 3;
    int i = threadIdx.x & 255;
    int g = threadIdx.x >> 8;             // j-half 0/1

    __shared__ float2 sv[8][NN];          // 16 KB: this qh's 8 V rows
    __shared__ float2 spA[NN][8];         // 16 KB: g=1 partials (8 acc)
    __shared__ float2 senc[8];

    const float2* V = E + ((size_t)(((2 * BB + b) * MM + m) * NHH + h) * QDD + qh * 8) * NN;
    for (int i2 = threadIdx.x; i2 < 8 * NN; i2 += 512) sv[i2 >> 8][i2 & 255] = V[i2];
    if (threadIdx.x < 8) {
        int eb = ((MM + m) * NHH + h) * QDD + qh * 8 + threadIdx.x;   // enc[1,...]
        senc[threadIdx.x] = make_float2(encr[eb], enci[eb]);
    }
    __syncthreads();

    float accr[8], acci[8];
#pragma unroll
    for (int q = 0; q < 8; ++q) { accr[q] = 0.f; acci[q] = 0.f; }

    const float* awp = AwT + (size_t)((b * NHH + h) * NN) * NN + i;
    int j0 = g * (NN / 2);
    for (int j = j0; j < j0 + NN / 2; ++j) {
        float aw = awp[(size_t)j * NN];       // coalesced over i
#pragma unroll
        for (int q = 0; q < 8; ++q) {
            float2 vv = sv[q][j];             // wave-uniform -> broadcast
            accr[q] = fmaf(vv.x, aw, accr[q]);
            acci[q] = fmaf(vv.y, aw, acci[q]);
        }
    }

    if (g == 1) {
#pragma unroll
        for (int q = 0; q < 8; ++q) spA[i][q] = make_float2(accr[q], acci[q]);
    }
    __syncthreads();
    if (g == 0) {
#pragma unroll
        for (int q = 0; q < 8; ++q) {
            float2 o = spA[i][q];
            accr[q] += o.x; acci[q] += o.y;
        }
        float2 pa = PA[(size_t)((b * MM + m) * NHH + h) * NN + i];
        float par = pa.x, pai = pa.y;

        float2* rp = Res + ((size_t)((b * MM + m) * KO + h * QDD + qh * 8)) * NN + i;
#pragma unroll
        for (int q = 0; q < 8; ++q) {
            float2 e1 = senc[q];
            float rr = accr[q] + e1.x * par - e1.y * pai;
            float ri = acci[q] + e1.x * pai + e1.y * par;
            rp[(size_t)q * NN] = make_float2(rr, ri);
        }
    }
}

// ---------------------------------------------------------------------------
// Kernel 6 (DTILE=8 + XCD swizzle): out[b,m,D,n] = sum_k w_out*res.
// ---------------------------------------------------------------------------
__global__ void out_kernel(const float2* __restrict__ Res,
                           const float* __restrict__ wor, const float* __restrict__ woi,
                           float* __restrict__ out) {
    int bid = blockIdx.x;
    int xcd = bid & 7;
    int idx = bid >> 3;                   // 0..63
    int bm = xcd * 4 + (idx & 3);         // b*MM+m, 0..31
    int dt = idx >> 2;                    // 0..15
    int n = threadIdx.x;
    int D0 = dt * DTILE;
    int m = bm & 3;

    __shared__ float2 sw[DTILE][KO];      // 8 KB
    for (int i2 = threadIdx.x; i2 < DTILE * KO; i2 += 256) {
        int d = i2 >> 7, k = i2 & 127;
        int wb = (m * DD + D0 + d) * KO + k;
        sw[d][k] = make_float2(wor[wb], woi[wb]);
    }
    __syncthreads();

    const float2* rp = Res + (size_t)(bm * KO) * NN + n;
    float ar[DTILE], ai[DTILE];
#pragma unroll
    for (int d = 0; d < DTILE; ++d) { ar[d] = 0.f; ai[d] = 0.f; }

    for (int k = 0; k < KO; ++k) {
        float2 r = rp[(size_t)k * NN];    // coalesced
#pragma unroll
        for (int d = 0; d < DTILE; ++d) {
            float2 w = sw[d][k];          // broadcast
            ar[d] = fmaf(w.x, r.x, fmaf(-w.y, r.y, ar[d]));
            ai[d] = fmaf(w.x, r.y, fmaf( w.y, r.x, ai[d]));
        }
    }
#pragma unroll
    for (int d = 0; d < DTILE; ++d) {
        size_t ob = (size_t)(bm * DD + D0 + d) * NN + n;
        out[ob] = ar[d];
        out[(size_t)BB * MM * DD * NN + ob] = ai[d];
    }
}

// ---------------------------------------------------------------------------
extern "C" void kernel_launch(void* const* d_in, const int* in_sizes, int n_in,
                              void* d_out, int out_size, void* d_ws, size_t ws_size,
                              hipStream_t stream) {
    (void)in_sizes; (void)n_in; (void)out_size; (void)ws_size;

    const float* x_re   = (const float*)d_in[0];
    const float* x_im   = (const float*)d_in[1];
    const float* emb_re = (const float*)d_in[2];
    const float* emb_im = (const float*)d_in[3];
    const float* enc_re = (const float*)d_in[4];
    const float* enc_im = (const float*)d_in[5];
    const float* out_re = (const float*)d_in[6];
    const float* out_im = (const float*)d_in[7];
    float* out = (float*)d_out;

    // Workspace layout (floats). Total ~155.7 MB.
    float* ws = (float*)d_ws;
    size_t off = 0;
    float2* peIJ = (float2*)(ws + off); off += (size_t)MM * NN * NN * 2;          // 524288
    float2* peT  = (float2*)(ws + off); off += (size_t)MM * NN * NN * 2;          // 524288 (hosts PA)
    float2* E    = (float2*)(ws + off); off += (size_t)3 * BB * MM * NHH * QDD * NN * 2; // 25165824
    float2* QE   = (float2*)(ws + off); off += (size_t)BB * MM * NHH * NN * 2;    // 131072
    float2* A    = (float2*)(ws + off); off += (size_t)BB * NHH * NN * NN * 2;    // 8388608 fl
    float*  FRAG = (float*)(ws + off);  off += (size_t)BB * NHH * NN * NN;        // 4194304 fl

    // Region plan:
    //  1) convAB stages Abf/Bre at A start; e_mfma reads them ->
    //     writes E t2 (V) + QE + Ea/Kb fragments into FRAG region.
    //  2) score reads Ea/Kb(FRAG) + QE + peIJ -> AwT (A second half) + PA.
    //     (AwT must NOT alias Ea/Kb: reads and writes overlap in time.)
    //  3) res reads AwT + PA + V(E t2) -> Res into A first half.
    //  4) out reads Res.
    unsigned int* AbfHi = (unsigned int*)A;
    unsigned int* AbfLo = AbfHi + (size_t)96 * QDD * DD;
    unsigned int* BreHi = AbfLo + (size_t)96 * QDD * DD;
    unsigned int* BreLo = BreHi + (size_t)32 * 256 * 128;

    unsigned int* EaHi = (unsigned int*)FRAG;                     // 4 x 1048576 uints
    unsigned int* EaLo = EaHi + (size_t)64 * 16384;               //  = 16.78MB exact
    unsigned int* KbHi = EaLo + (size_t)64 * 16384;
    unsigned int* KbLo = KbHi + (size_t)64 * 16384;

    float2* Res = A;                                  // first 4.19M floats
    float*  AwT = (float*)A + (size_t)4194304;        // second 4.19M floats
    float2* PA  = peT;                                // 1MB in dead peT region

    pe_kernel<<<MM * NN, 256, 0, stream>>>(peIJ);
    convAB_kernel<<<96 + 256, 256, 0, stream>>>(emb_re, emb_im, x_re, x_im,
                                                AbfHi, AbfLo, BreHi, BreLo);
    e_mfma_kernel<<<512, 256, 0, stream>>>(
        (const unsigned short*)AbfHi, (const unsigned short*)AbfLo,
        (const unsigned short*)BreHi, (const unsigned short*)BreLo,
        enc_re, enc_im, E, QE,
        EaHi, EaLo, KbHi, KbLo);
    score_kernel<<<1024, 256, 0, stream>>>(
        (const unsigned short*)EaHi, (const unsigned short*)EaLo,
        (const unsigned short*)KbHi, (const unsigned short*)KbLo,
        QE, peIJ, AwT, PA);
    res_kernel<<<BB * MM * NHH * 2, 512, 0, stream>>>(E, AwT, PA, enc_re, enc_im, Res);
    out_kernel<<<BB * MM * (DD / DTILE), 256, 0, stream>>>(Res, out_re, out_im, out);
}

// Round 40
// 107.507 us; speedup vs baseline: 1.2970x; 1.0742x over previous
//
#include <hip/hip_runtime.h>
#include <math.h>

// Problem constants (from reference)
#define BB   8      // batch
#define MM   4      // MAXM
#define DD   128    // DIM
#define NHH  8      // heads
#define QDD  16     // head dim
#define NN   256    // H*W
#define KO   128    // NH*QD
#define DTILE 8     // D-rows per out_kernel block

typedef float v2f __attribute__((ext_vector_type(2)));

typedef __attribute__((ext_vector_type(8))) short bf16x8;   // 8 bf16 (4 VGPR)
typedef __attribute__((ext_vector_type(4))) float f32x4;    // MFMA acc

__device__ inline unsigned short f2bf(float f) {            // RNE float->bf16
    union { float f; unsigned u; } v; v.f = f;
    unsigned r = v.u + 0x7FFF + ((v.u >> 16) & 1);
    return (unsigned short)(r >> 16);
}
__device__ inline float bf2f(unsigned short h) {
    union { unsigned u; float f; } v; v.u = ((unsigned)h) << 16;
    return v.f;
}
// split x = hi + lo (both bf16)
__device__ inline void bfsplit(float x, unsigned short& hi, unsigned short& lo) {
    hi = f2bf(x);
    lo = f2bf(x - bf2f(hi));
}
// e_mfma: (br | -bi<<16) -> (bi | br<<16)
__device__ inline bf16x8 derive_im(bf16x8 v) {
    union { bf16x8 v; unsigned u[4]; } in, out;
    in.v = v;
#pragma unroll
    for (int w = 0; w < 4; ++w)
        out.u[w] = ((in.u[w] >> 16) ^ 0x8000u) | (in.u[w] << 16);
    return out.v;
}
// a_mfma: (kx | ky<<16) -> (ky | (-kx)<<16)
__device__ inline bf16x8 derive_im2(bf16x8 v) {
    union { bf16x8 v; unsigned u[4]; } in, out;
    in.v = v;
#pragma unroll
    for (int w = 0; w < 4; ++w)
        out.u[w] = (in.u[w] >> 16) | ((in.u[w] ^ 0x8000u) << 16);
    return out.v;
}

// ---------------------------------------------------------------------------
// Kernel 0 (trig-free): pe[m,i,j] = exp(i*m*theta) = ((dx+i*dy)/r)^m.
// ---------------------------------------------------------------------------
__global__ void pe_kernel(float2* __restrict__ peIJ) {
    int bid = blockIdx.x;           // m*N + i
    int m = bid >> 8;
    int i = bid & 255;
    int j = threadIdx.x;
    float dy = (float)((j >> 4) - (i >> 4));
    float dx = (float)((j & 15) - (i & 15));
    float r2 = dx * dx + dy * dy;
    float c1 = 1.f, s1 = 0.f;
    if (r2 > 0.f) {
        float rinv = rsqrtf(r2);
        c1 = dx * rinv; s1 = dy * rinv;
    }
    float c = 1.f, s = 0.f;
    for (int k = 0; k < m; ++k) {   // m is block-uniform (0..3)
        float nc = c * c1 - s * s1;
        s = c * s1 + s * c1;
        c = nc;
    }
    peIJ[(m * NN + i) * NN + j] = make_float2(c, s);
}

// ---------------------------------------------------------------------------
// Kernel 1 (merged convA+convB): blocks 0..95 = convA (emb -> A' split-bf16),
// blocks 96..351 = convB (x -> Bre split-bf16; Bim derived in e_mfma).
// ---------------------------------------------------------------------------
__global__ void convAB_kernel(const float* __restrict__ er, const float* __restrict__ ei,
                              const float* __restrict__ xr, const float* __restrict__ xi,
                              unsigned int* __restrict__ AbfHi, unsigned int* __restrict__ AbfLo,
                              unsigned int* __restrict__ BreHi, unsigned int* __restrict__ BreLo) {
    if (blockIdx.x < 96) {
        int tmh = blockIdx.x;             // 0..95
        int base = tmh * QDD * DD;
#pragma unroll
        for (int it = 0; it < 8; ++it) {
            int idx = threadIdx.x + it * 256;  // q*128+D
            float ar = er[base + idx];
            float ai = ei[base + idx];
            unsigned short arh, arl, aih, ail;
            bfsplit(ar, arh, arl);
            bfsplit(ai, aih, ail);
            AbfHi[base + idx] = (unsigned int)arh | ((unsigned int)aih << 16);
            AbfLo[base + idx] = (unsigned int)arl | ((unsigned int)ail << 16);
        }
        return;
    }
    int bid = blockIdx.x - 96;            // 0..255 = 32 bm x 8 Dg
    int bm = bid >> 3;
    int Dg = bid & 7;
    int D0 = Dg * 16;
    int tid = threadIdx.x;

    __shared__ float sxr[16][257];
    __shared__ float sxi[16][257];

    const float* xrp = xr + (size_t)bm * DD * NN;
    const float* xip = xi + (size_t)bm * DD * NN;
#pragma unroll
    for (int it = 0; it < 16; ++it) {
        int i2 = tid + it * 256;
        int r = i2 >> 8, c = i2 & 255;
        sxr[r][c] = xrp[(size_t)(D0 + r) * NN + c];
        sxi[r][c] = xip[(size_t)(D0 + r) * NN + c];
    }
    __syncthreads();

    int n = tid;
    unsigned int reh[16], rel_[16];
#pragma unroll
    for (int d = 0; d < 16; ++d) {
        float br = sxr[d][n];
        float bi = sxi[d][n];
        unsigned short brh, brl, bih, bil;
        bfsplit(br, brh, brl);
        bfsplit(bi, bih, bil);
        reh[d]  = (unsigned int)brh | ((unsigned int)(bih ^ 0x8000) << 16);
        rel_[d] = (unsigned int)brl | ((unsigned int)(bil ^ 0x8000) << 16);
    }
    size_t ob = (size_t)bm * 32768 + (size_t)n * 128 + D0;
#pragma unroll
    for (int w = 0; w < 4; ++w) {
        ((uint4*)(BreHi + ob))[w] = make_uint4(reh[4*w], reh[4*w+1], reh[4*w+2], reh[4*w+3]);
        ((uint4*)(BreLo + ob))[w] = make_uint4(rel_[4*w], rel_[4*w+1], rel_[4*w+2], rel_[4*w+3]);
    }
}

// ---------------------------------------------------------------------------
// Kernel 2 (e_mfma v5 = v4 + FUSED qe): block = (pair, h, nhalf). 512 blocks.
// ---------------------------------------------------------------------------
__global__ __launch_bounds__(256, 2)
void e_mfma_kernel(const unsigned short* __restrict__ AbfHi,
                   const unsigned short* __restrict__ AbfLo,
                   const unsigned short* __restrict__ BreHi,
                   const unsigned short* __restrict__ BreLo,
                   const float* __restrict__ encr, const float* __restrict__ enci,
                   float2* __restrict__ E,
                   float2* __restrict__ QE,
                   unsigned int* __restrict__ EaHi, unsigned int* __restrict__ EaLo,
                   unsigned int* __restrict__ KbHi, unsigned int* __restrict__ KbLo) {
    int bid = blockIdx.x;                 // 512 = 8 xcd x 64 idx
    int xcd = bid & 7;
    int idx = bid >> 3;                   // 0..63
    int pair = xcd * 4 + (idx & 3);       // b*MM+m (XCD-pinned B panels)
    int h = (idx >> 2) & 7;               // 0..7
    int nhalf = idx >> 5;                 // 0..1
    int b = pair >> 2, m = pair & 3;
    int tid = threadIdx.x;
    int wav = tid >> 6, lane = tid & 63;
    int lo = lane & 15, hi = lane >> 4;

    const unsigned short* AH[3];
    const unsigned short* AL[3];
#pragma unroll
    for (int t = 0; t < 3; ++t) {
        size_t aoff = ((size_t)((t * MM + m) * NHH + h)) * QDD * 256;
        AH[t] = AbfHi + aoff;
        AL[t] = AbfLo + aoff;
    }
    size_t boff = (size_t)pair * 256 * 256;
    const unsigned short* BrH = BreHi + boff;
    const unsigned short* BrL = BreLo + boff;

    f32x4 accRe[3][2], accIm[3][2];
#pragma unroll
    for (int t = 0; t < 3; ++t)
#pragma unroll
        for (int nt = 0; nt < 2; ++nt) {
            accRe[t][nt] = (f32x4)(0.f);
            accIm[t][nt] = (f32x4)(0.f);
        }

#pragma unroll
    for (int ks = 0; ks < 8; ++ks) {
        int k0 = ks * 32;
        int arow = lo * 256 + k0 + hi * 8;
        bf16x8 aH[3], aL[3];
#pragma unroll
        for (int t = 0; t < 3; ++t) {
            aH[t] = *(const bf16x8*)(AH[t] + arow);
            aL[t] = *(const bf16x8*)(AL[t] + arow);
        }
#pragma unroll
        for (int nt = 0; nt < 2; ++nt) {
            int n0 = nhalf * 128 + (wav * 2 + nt) * 16;
            size_t brow = (size_t)(n0 + lo) * 256 + k0 + hi * 8;
            bf16x8 brh = *(const bf16x8*)(BrH + brow);
            bf16x8 brl = *(const bf16x8*)(BrL + brow);
            bf16x8 bih = derive_im(brh);
            bf16x8 bil = derive_im(brl);
#pragma unroll
            for (int t = 0; t < 3; ++t) {
                accRe[t][nt] = __builtin_amdgcn_mfma_f32_16x16x32_bf16(aH[t], brh, accRe[t][nt], 0, 0, 0);
                accRe[t][nt] = __builtin_amdgcn_mfma_f32_16x16x32_bf16(aH[t], brl, accRe[t][nt], 0, 0, 0);
                accRe[t][nt] = __builtin_amdgcn_mfma_f32_16x16x32_bf16(aL[t], brh, accRe[t][nt], 0, 0, 0);
                accIm[t][nt] = __builtin_amdgcn_mfma_f32_16x16x32_bf16(aH[t], bih, accIm[t][nt], 0, 0, 0);
                accIm[t][nt] = __builtin_amdgcn_mfma_f32_16x16x32_bf16(aH[t], bil, accIm[t][nt], 0, 0, 0);
                accIm[t][nt] = __builtin_amdgcn_mfma_f32_16x16x32_bf16(aL[t], bih, accIm[t][nt], 0, 0, 0);
            }
        }
    }

    int bh = b * NHH + h;

    // --- fused qe: QE[b,m,h,i] = sum_q conj(E0[q,i])*enc0[m,h,q] ---
    {
        float cr[4], ci[4];
#pragma unroll
        for (int reg = 0; reg < 4; ++reg) {
            int q = hi * 4 + reg;
            int eb = (m * NHH + h) * QDD + q;
            cr[reg] = encr[eb];
            ci[reg] = enci[eb];
        }
#pragma unroll
        for (int nt = 0; nt < 2; ++nt) {
            int n0 = nhalf * 128 + (wav * 2 + nt) * 16;
            float sr = 0.f, si = 0.f;
#pragma unroll
            for (int reg = 0; reg < 4; ++reg) {
                float erv = accRe[0][nt][reg];
                float eiv = accIm[0][nt][reg];
                sr = fmaf(erv, cr[reg], fmaf( eiv, ci[reg], sr));
                si = fmaf(erv, ci[reg], fmaf(-eiv, cr[reg], si));
            }
            sr += __shfl_xor(sr, 16); si += __shfl_xor(si, 16);
            sr += __shfl_xor(sr, 32); si += __shfl_xor(si, 32);
            if (hi == 0)
                QE[(size_t)((b * MM + m) * NHH + h) * NN + n0 + lo] = make_float2(sr, si);
        }
    }

    // t=0: Ea fragments ; t=1: Kb fragments ; t=2: E float2 (V).
#pragma unroll
    for (int t = 0; t < 3; ++t) {
        size_t ebase = (size_t)((((t * BB + b) * MM + m) * NHH + h) * QDD) * NN;
#pragma unroll
        for (int nt = 0; nt < 2; ++nt) {
            int n0 = nhalf * 128 + (wav * 2 + nt) * 16;
            if (t == 2) {
#pragma unroll
                for (int reg = 0; reg < 4; ++reg) {
                    int q = hi * 4 + reg;
                    E[ebase + (size_t)q * NN + n0 + lo] =
                        make_float2(accRe[t][nt][reg], accIm[t][nt][reg]);
                }
            }
            if (t < 2) {
                unsigned int hiU[4], loU[4];
#pragma unroll
                for (int reg = 0; reg < 4; ++reg) {
                    unsigned short rh, rl, ih, il;
                    bfsplit(accRe[t][nt][reg], rh, rl);
                    bfsplit(accIm[t][nt][reg], ih, il);
                    hiU[reg] = (unsigned int)rh | ((unsigned int)ih << 16);
                    loU[reg] = (unsigned int)rl | ((unsigned int)il << 16);
                }
                int r = n0 >> 4;
                size_t fo = (size_t)bh * 16384 + (size_t)((r * 4 + m) * 64 + lane) * 4;
                unsigned int* tH = (t == 0) ? EaHi : KbHi;
                unsigned int* tL = (t == 0) ? EaLo : KbLo;
                *(uint4*)(tH + fo) = make_uint4(hiU[0], hiU[1], hiU[2], hiU[3]);
                *(uint4*)(tL + fo) = make_uint4(loU[0], loU[1], loU[2], loU[3]);
            }
        }
    }
}

// ---------------------------------------------------------------------------
// Kernel 3 (score = FUSED a_mfma + softmax + PA, v2: emits Aw as MFMA
// B-operand fragments): 1024 blocks = (bh, itile).
// AwFrag[((bh*16+it)*8+ks)*512 + lane*8 + r] = awH | awL<<16 for
// aw[i = it*16 + (lane&15)][j = ks*32 + (lane>>4)*8 + r].
// ---------------------------------------------------------------------------
__global__ __launch_bounds__(256)
void score_kernel(const unsigned short* __restrict__ EaHi,
                  const unsigned short* __restrict__ EaLo,
                  const unsigned short* __restrict__ KbHi,
                  const unsigned short* __restrict__ KbLo,
                  const float2* __restrict__ QE,
                  const float2* __restrict__ peIJ,
                  unsigned int* __restrict__ AwFrag,
                  float2* __restrict__ PA) {
    int bid = blockIdx.x;                 // 1024 = 8 xcd x 128 idx
    int xcd = bid & 7;
    int idx = bid >> 3;                   // 0..127
    int bh = xcd * 8 + (idx & 7);         // K-panel XCD-pinned
    int it = idx >> 3;                    // 0..15 i-tile
    int b = bh >> 3, h = bh & 7;
    int tid = threadIdx.x;
    int wav = tid >> 6, lane = tid & 63;
    int lo = lane & 15, hi = lane >> 4;

    const unsigned short* EaH = EaHi + (size_t)bh * 32768;
    const unsigned short* EaL = EaLo + (size_t)bh * 32768;
    const unsigned short* KbH = KbHi + (size_t)bh * 32768;
    const unsigned short* KbL = KbLo + (size_t)bh * 32768;

    __shared__ float st[16][257];         // aw staging (block's 16 rows x 256 j)
    __shared__ float sredA[16][4];        // cross-wave max
    __shared__ float sredB[16][4];        // cross-wave sum
    __shared__ float sPA[16][4][2][4];    // PA partials [row][m][comp][wav]

    f32x4 accRe[4], accIm[4];
#pragma unroll
    for (int nt = 0; nt < 4; ++nt) { accRe[nt] = (f32x4)(0.f); accIm[nt] = (f32x4)(0.f); }

#pragma unroll
    for (int ks = 0; ks < 4; ++ks) {
        size_t arow = (size_t)((it * 4 + ks) * 64 + lane) * 8;   // coalesced
        bf16x8 aH = *(const bf16x8*)(EaH + arow);
        bf16x8 aL = *(const bf16x8*)(EaL + arow);
#pragma unroll
        for (int nt = 0; nt < 4; ++nt) {
            int jt = wav * 4 + nt;
            size_t brow = (size_t)((jt * 4 + ks) * 64 + lane) * 8;  // coalesced
            bf16x8 brh = *(const bf16x8*)(KbH + brow);
            bf16x8 brl = *(const bf16x8*)(KbL + brow);
            bf16x8 bih = derive_im2(brh);
            bf16x8 bil = derive_im2(brl);
            accRe[nt] = __builtin_amdgcn_mfma_f32_16x16x32_bf16(aH, brh, accRe[nt], 0, 0, 0);
            accRe[nt] = __builtin_amdgcn_mfma_f32_16x16x32_bf16(aH, brl, accRe[nt], 0, 0, 0);
            accRe[nt] = __builtin_amdgcn_mfma_f32_16x16x32_bf16(aL, brh, accRe[nt], 0, 0, 0);
            accIm[nt] = __builtin_amdgcn_mfma_f32_16x16x32_bf16(aH, bih, accIm[nt], 0, 0, 0);
            accIm[nt] = __builtin_amdgcn_mfma_f32_16x16x32_bf16(aH, bil, accIm[nt], 0, 0, 0);
            accIm[nt] = __builtin_amdgcn_mfma_f32_16x16x32_bf16(aL, bih, accIm[nt], 0, 0, 0);
        }
    }

    // pass 1: + sum_m QE*pe, magnitude. vmag[nt][reg].
    float vmag[4][4];
#pragma unroll
    for (int reg = 0; reg < 4; ++reg) {
        int i = it * 16 + hi * 4 + reg;
        float2 qe4[MM];
#pragma unroll
        for (int m = 0; m < MM; ++m)
            qe4[m] = QE[(size_t)((b * MM + m) * NHH + h) * NN + i];
#pragma unroll
        for (int nt = 0; nt < 4; ++nt) {
            int j = (wav * 4 + nt) * 16 + lo;
            float ar = accRe[nt][reg];
            float ai = accIm[nt][reg];
#pragma unroll
            for (int m = 0; m < MM; ++m) {
                float2 p = peIJ[(size_t)(m * NN + i) * NN + j];
                ar = fmaf(qe4[m].x, p.x, fmaf(-qe4[m].y, p.y, ar));
                ai = fmaf(qe4[m].x, p.y, fmaf( qe4[m].y, p.x, ai));
            }
            vmag[nt][reg] = sqrtf(fmaf(ar, ar, ai * ai)) * 0.25f;
        }
    }

    // row max: over nt regs, then 16-lane lo group, then cross-wave via LDS.
    float mxr[4];
#pragma unroll
    for (int reg = 0; reg < 4; ++reg) {
        mxr[reg] = fmaxf(fmaxf(vmag[0][reg], vmag[1][reg]),
                         fmaxf(vmag[2][reg], vmag[3][reg]));
#pragma unroll
        for (int off = 1; off < 16; off <<= 1)
            mxr[reg] = fmaxf(mxr[reg], __shfl_xor(mxr[reg], off));
    }
    if (lo == 0) {
#pragma unroll
        for (int reg = 0; reg < 4; ++reg) sredA[hi * 4 + reg][wav] = mxr[reg];
    }
    __syncthreads();
    float mx[4];
#pragma unroll
    for (int reg = 0; reg < 4; ++reg) {
        int r = hi * 4 + reg;
        mx[reg] = fmaxf(fmaxf(sredA[r][0], sredA[r][1]),
                        fmaxf(sredA[r][2], sredA[r][3]));
    }

    // exp + row sum
    float smr[4];
#pragma unroll
    for (int reg = 0; reg < 4; ++reg) smr[reg] = 0.f;
#pragma unroll
    for (int nt = 0; nt < 4; ++nt)
#pragma unroll
        for (int reg = 0; reg < 4; ++reg) {
            vmag[nt][reg] = __expf(vmag[nt][reg] - mx[reg]);
            smr[reg] += vmag[nt][reg];
        }
#pragma unroll
    for (int reg = 0; reg < 4; ++reg) {
#pragma unroll
        for (int off = 1; off < 16; off <<= 1)
            smr[reg] += __shfl_xor(smr[reg], off);
    }
    if (lo == 0) {
#pragma unroll
        for (int reg = 0; reg < 4; ++reg) sredB[hi * 4 + reg][wav] = smr[reg];
    }
    __syncthreads();
    float inv[4];
#pragma unroll
    for (int reg = 0; reg < 4; ++reg) {
        int r = hi * 4 + reg;
        inv[reg] = 1.f / (sredB[r][0] + sredB[r][1] + sredB[r][2] + sredB[r][3]);
    }

    // pass 2: aw -> st; PA partials per (m, reg row).
    float par[MM][4], pai[MM][4];
#pragma unroll
    for (int m = 0; m < MM; ++m)
#pragma unroll
        for (int reg = 0; reg < 4; ++reg) { par[m][reg] = 0.f; pai[m][reg] = 0.f; }
#pragma unroll
    for (int reg = 0; reg < 4; ++reg) {
        int i = it * 16 + hi * 4 + reg;
#pragma unroll
        for (int nt = 0; nt < 4; ++nt) {
            int j = (wav * 4 + nt) * 16 + lo;
            float aw = vmag[nt][reg] * inv[reg];
            st[hi * 4 + reg][j] = aw;
#pragma unroll
            for (int m = 0; m < MM; ++m) {
                float2 p = peIJ[(size_t)(m * NN + i) * NN + j];
                par[m][reg] = fmaf(p.x, aw, par[m][reg]);
                pai[m][reg] = fmaf(p.y, aw, pai[m][reg]);
            }
        }
    }
#pragma unroll
    for (int m = 0; m < MM; ++m)
#pragma unroll
        for (int reg = 0; reg < 4; ++reg) {
#pragma unroll
            for (int off = 1; off < 16; off <<= 1) {
                par[m][reg] += __shfl_xor(par[m][reg], off);
                pai[m][reg] += __shfl_xor(pai[m][reg], off);
            }
        }
    if (lo == 0) {
#pragma unroll
        for (int m = 0; m < MM; ++m)
#pragma unroll
            for (int reg = 0; reg < 4; ++reg) {
                sPA[hi * 4 + reg][m][0][wav] = par[m][reg];
                sPA[hi * 4 + reg][m][1][wav] = pai[m][reg];
            }
    }
    __syncthreads();

    if (tid < 16) {
        int r = tid;
#pragma unroll
        for (int m = 0; m < MM; ++m) {
            float pr  = sPA[r][m][0][0] + sPA[r][m][0][1] + sPA[r][m][0][2] + sPA[r][m][0][3];
            float pim = sPA[r][m][1][0] + sPA[r][m][1][1] + sPA[r][m][1][2] + sPA[r][m][1][3];
            PA[(size_t)((b * MM + m) * NHH + h) * NN + it * 16 + r] = make_float2(pr, pim);
        }
    }

    // Aw fragment emission: wave wav handles ks = wav*2 + {0,1}.
    // Lane 'lane' produces the consumer-lane 'lane' entry:
    //   aw[i = it*16 + lo][j = ks*32 + hi*8 + r], packed awH|awL<<16.
#pragma unroll
    for (int ksl = 0; ksl < 2; ++ksl) {
        int ks = wav * 2 + ksl;
        unsigned int uu[8];
#pragma unroll
        for (int r = 0; r < 8; ++r) {
            float aw = st[lo][ks * 32 + hi * 8 + r];
            unsigned short h2, l2;
            bfsplit(aw, h2, l2);
            uu[r] = (unsigned int)h2 | ((unsigned int)l2 << 16);
        }
        unsigned int* ap = AwFrag + ((((size_t)bh * 16 + it) * 8 + ks) * 64 + lane) * 8;
        *(uint4*)ap = make_uint4(uu[0], uu[1], uu[2], uu[3]);
        *(uint4*)(ap + 4) = make_uint4(uu[4], uu[5], uu[6], uu[7]);
    }
}

// ---------------------------------------------------------------------------
// Kernel 4 (res_mfma: Aw x V via MFMA, split-bf16): 512 blocks = (bh, ih).
// Wave = m; each wave computes res[b,m,h,q(16),i(32)] for 2 i-tiles.
// A = V[m][q][j] (rows q, K=j), B = AwFrag (cols i, K=j).
// Epilogue: += enc1[m,h,q] * PA[b,m,h,i]; write Res[b,m,k=h*16+q,i].
// ---------------------------------------------------------------------------
__global__ __launch_bounds__(256, 2)
void res_mfma_kernel(const float2* __restrict__ E,
                     const unsigned int* __restrict__ AwFrag,
                     const float2* __restrict__ PA,
                     const float* __restrict__ encr, const float* __restrict__ enci,
                     float2* __restrict__ Res) {
    int bid = blockIdx.x;                 // 512 = 8 xcd x 64 idx
    int xcd = bid & 7;
    int idx = bid >> 3;                   // 0..63
    int bh = xcd * 8 + (idx & 7);         // XCD-pinned panels
    int ih = idx >> 3;                    // 0..7 (i-eighth: 2 i-tiles)
    int b = bh >> 3, h = bh & 7;
    int tid = threadIdx.x;
    int m = tid >> 6;                     // wave = m
    int lane = tid & 63;
    int lo = lane & 15, hi = lane >> 4;

    const float2* V = E + ((size_t)(((2 * BB + b) * MM + m) * NHH + h) * QDD) * NN;

    f32x4 accRe[2], accIm[2];
#pragma unroll
    for (int t2 = 0; t2 < 2; ++t2) { accRe[t2] = (f32x4)(0.f); accIm[t2] = (f32x4)(0.f); }

#pragma unroll
    for (int ks = 0; ks < 8; ++ks) {
        // A fragment: V[q=lo][j = ks*32 + hi*8 + r], bf16 split, re/im.
        const float2* vp = V + (size_t)lo * NN + ks * 32 + hi * 8;
        union { bf16x8 v; unsigned short s[8]; } vrh, vrl, vih, vil;
#pragma unroll
        for (int r = 0; r < 8; ++r) {
            float2 v = vp[r];
            unsigned short rh, rl, ih2, il2;
            bfsplit(v.x, rh, rl);
            bfsplit(v.y, ih2, il2);
            vrh.s[r] = rh; vrl.s[r] = rl; vih.s[r] = ih2; vil.s[r] = il2;
        }
#pragma unroll
        for (int t2 = 0; t2 < 2; ++t2) {
            int it = ih * 2 + t2;
            const unsigned int* ap = AwFrag + ((((size_t)bh * 16 + it) * 8 + ks) * 64 + lane) * 8;
            uint4 u0 = *(const uint4*)ap;
            uint4 u1 = *(const uint4*)(ap + 4);
            unsigned int uu[8] = {u0.x, u0.y, u0.z, u0.w, u1.x, u1.y, u1.z, u1.w};
            union { bf16x8 v; unsigned short s[8]; } awh, awl;
#pragma unroll
            for (int r = 0; r < 8; ++r) {
                awh.s[r] = (unsigned short)(uu[r] & 0xffffu);
                awl.s[r] = (unsigned short)(uu[r] >> 16);
            }
            accRe[t2] = __builtin_amdgcn_mfma_f32_16x16x32_bf16(vrh.v, awh.v, accRe[t2], 0, 0, 0);
            accRe[t2] = __builtin_amdgcn_mfma_f32_16x16x32_bf16(vrh.v, awl.v, accRe[t2], 0, 0, 0);
            accRe[t2] = __builtin_amdgcn_mfma_f32_16x16x32_bf16(vrl.v, awh.v, accRe[t2], 0, 0, 0);
            accIm[t2] = __builtin_amdgcn_mfma_f32_16x16x32_bf16(vih.v, awh.v, accIm[t2], 0, 0, 0);
            accIm[t2] = __builtin_amdgcn_mfma_f32_16x16x32_bf16(vih.v, awl.v, accIm[t2], 0, 0, 0);
            accIm[t2] = __builtin_amdgcn_mfma_f32_16x16x32_bf16(vil.v, awh.v, accIm[t2], 0, 0, 0);
        }
    }

    // epilogue: C/D layout col=lo (i in tile), row=hi*4+reg (q).
    float e1r[4], e1i[4];
#pragma unroll
    for (int reg = 0; reg < 4; ++reg) {
        int q = hi * 4 + reg;
        int eb = ((MM + m) * NHH + h) * QDD + q;   // enc[1,m,h,q]
        e1r[reg] = encr[eb];
        e1i[reg] = enci[eb];
    }
#pragma unroll
    for (int t2 = 0; t2 < 2; ++t2) {
        int i = (ih * 2 + t2) * 16 + lo;
        float2 pa = PA[(size_t)((b * MM + m) * NHH + h) * NN + i];
#pragma unroll
        for (int reg = 0; reg < 4; ++reg) {
            int q = hi * 4 + reg;
            float rr = accRe[t2][reg] + e1r[reg] * pa.x - e1i[reg] * pa.y;
            float ri = accIm[t2][reg] + e1r[reg] * pa.y + e1i[reg] * pa.x;
            Res[(size_t)((b * MM + m) * KO + h * QDD + q) * NN + i] = make_float2(rr, ri);
        }
    }
}

// ---------------------------------------------------------------------------
// Kernel 5 (DTILE=8 + XCD swizzle): out[b,m,D,n] = sum_k w_out*res.
// ---------------------------------------------------------------------------
__global__ void out_kernel(const float2* __restrict__ Res,
                           const float* __restrict__ wor, const float* __restrict__ woi,
                           float* __restrict__ out) {
    int bid = blockIdx.x;
    int xcd = bid & 7;
    int idx = bid >> 3;                   // 0..63
    int bm = xcd * 4 + (idx & 3);         // b*MM+m, 0..31
    int dt = idx >> 2;                    // 0..15
    int n = threadIdx.x;
    int D0 = dt * DTILE;
    int m = bm & 3;

    __shared__ float2 sw[DTILE][KO];      // 8 KB
    for (int i2 = threadIdx.x; i2 < DTILE * KO; i2 += 256) {
        int d = i2 >> 7, k = i2 & 127;
        int wb = (m * DD + D0 + d) * KO + k;
        sw[d][k] = make_float2(wor[wb], woi[wb]);
    }
    __syncthreads();

    const float2* rp = Res + (size_t)(bm * KO) * NN + n;
    float ar[DTILE], ai[DTILE];
#pragma unroll
    for (int d = 0; d < DTILE; ++d) { ar[d] = 0.f; ai[d] = 0.f; }

    for (int k = 0; k < KO; ++k) {
        float2 r = rp[(size_t)k * NN];    // coalesced
#pragma unroll
        for (int d = 0; d < DTILE; ++d) {
            float2 w = sw[d][k];          // broadcast
            ar[d] = fmaf(w.x, r.x, fmaf(-w.y, r.y, ar[d]));
            ai[d] = fmaf(w.x, r.y, fmaf( w.y, r.x, ai[d]));
        }
    }
#pragma unroll
    for (int d = 0; d < DTILE; ++d) {
        size_t ob = (size_t)(bm * DD + D0 + d) * NN + n;
        out[ob] = ar[d];
        out[(size_t)BB * MM * DD * NN + ob] = ai[d];
    }
}

// ---------------------------------------------------------------------------
extern "C" void kernel_launch(void* const* d_in, const int* in_sizes, int n_in,
                              void* d_out, int out_size, void* d_ws, size_t ws_size,
                              hipStream_t stream) {
    (void)in_sizes; (void)n_in; (void)out_size; (void)ws_size;

    const float* x_re   = (const float*)d_in[0];
    const float* x_im   = (const float*)d_in[1];
    const float* emb_re = (const float*)d_in[2];
    const float* emb_im = (const float*)d_in[3];
    const float* enc_re = (const float*)d_in[4];
    const float* enc_im = (const float*)d_in[5];
    const float* out_re = (const float*)d_in[6];
    const float* out_im = (const float*)d_in[7];
    float* out = (float*)d_out;

    // Workspace layout (floats). Total ~155.7 MB.
    float* ws = (float*)d_ws;
    size_t off = 0;
    float2* peIJ = (float2*)(ws + off); off += (size_t)MM * NN * NN * 2;          // 524288
    float2* peT  = (float2*)(ws + off); off += (size_t)MM * NN * NN * 2;          // 524288 (hosts PA)
    float2* E    = (float2*)(ws + off); off += (size_t)3 * BB * MM * NHH * QDD * NN * 2; // 25165824
    float2* QE   = (float2*)(ws + off); off += (size_t)BB * MM * NHH * NN * 2;    // 131072
    float2* A    = (float2*)(ws + off); off += (size_t)BB * NHH * NN * NN * 2;    // 8388608 fl
    float*  FRAG = (float*)(ws + off);  off += (size_t)BB * NHH * NN * NN;        // 4194304 fl

    // Region plan:
    //  1) convAB stages Abf/Bre at A start; e_mfma reads them ->
    //     writes E t2 (V) + QE + Ea/Kb fragments into FRAG region.
    //  2) score reads Ea/Kb(FRAG) + QE + peIJ -> AwFrag (A second half) + PA.
    //     (AwFrag must NOT alias Ea/Kb: reads and writes overlap in time.)
    //  3) res_mfma reads AwFrag + PA + V(E t2) -> Res into A first half.
    //  4) out reads Res.
    unsigned int* AbfHi = (unsigned int*)A;
    unsigned int* AbfLo = AbfHi + (size_t)96 * QDD * DD;
    unsigned int* BreHi = AbfLo + (size_t)96 * QDD * DD;
    unsigned int* BreLo = BreHi + (size_t)32 * 256 * 128;

    unsigned int* EaHi = (unsigned int*)FRAG;                     // 4 x 1048576 uints
    unsigned int* EaLo = EaHi + (size_t)64 * 16384;               //  = 16.78MB exact
    unsigned int* KbHi = EaLo + (size_t)64 * 16384;
    unsigned int* KbLo = KbHi + (size_t)64 * 16384;

    float2* Res = A;                                          // first 4.19M floats
    unsigned int* AwFrag = (unsigned int*)((float*)A + (size_t)4194304); // second half
    float2* PA  = peT;                                        // 1MB in dead peT region

    pe_kernel<<<MM * NN, 256, 0, stream>>>(peIJ);
    convAB_kernel<<<96 + 256, 256, 0, stream>>>(emb_re, emb_im, x_re, x_im,
                                                AbfHi, AbfLo, BreHi, BreLo);
    e_mfma_kernel<<<512, 256, 0, stream>>>(
        (const unsigned short*)AbfHi, (const unsigned short*)AbfLo,
        (const unsigned short*)BreHi, (const unsigned short*)BreLo,
        enc_re, enc_im, E, QE,
        EaHi, EaLo, KbHi, KbLo);
    score_kernel<<<1024, 256, 0, stream>>>(
        (const unsigned short*)EaHi, (const unsigned short*)EaLo,
        (const unsigned short*)KbHi, (const unsigned short*)KbLo,
        QE, peIJ, AwFrag, PA);
    res_mfma_kernel<<<512, 256, 0, stream>>>(E, AwFrag, PA, enc_re, enc_im, Res);
    out_kernel<<<BB * MM * (DD / DTILE), 256, 0, stream>>>(Res, out_re, out_im, out);
}

// Round 41
// 98.614 us; speedup vs baseline: 1.4140x; 1.0902x over previous
//
#include <hip/hip_runtime.h>
#include <math.h>

// Problem constants (from reference)
#define BB   8      // batch
#define MM   4      // MAXM
#define DD   128    // DIM
#define NHH  8      // heads
#define QDD  16     // head dim
#define NN   256    // H*W
#define KO   128    // NH*QD

typedef __attribute__((ext_vector_type(8))) short bf16x8;   // 8 bf16 (4 VGPR)
typedef __attribute__((ext_vector_type(4))) float f32x4;    // MFMA acc

__device__ inline unsigned short f2bf(float f) {            // RNE float->bf16
    union { float f; unsigned u; } v; v.f = f;
    unsigned r = v.u + 0x7FFF + ((v.u >> 16) & 1);
    return (unsigned short)(r >> 16);
}
__device__ inline float bf2f(unsigned short h) {
    union { unsigned u; float f; } v; v.u = ((unsigned)h) << 16;
    return v.f;
}
// split x = hi + lo (both bf16)
__device__ inline void bfsplit(float x, unsigned short& hi, unsigned short& lo) {
    hi = f2bf(x);
    lo = f2bf(x - bf2f(hi));
}
// e_mfma: (br | -bi<<16) -> (bi | br<<16)
__device__ inline bf16x8 derive_im(bf16x8 v) {
    union { bf16x8 v; unsigned u[4]; } in, out;
    in.v = v;
#pragma unroll
    for (int w = 0; w < 4; ++w)
        out.u[w] = ((in.u[w] >> 16) ^ 0x8000u) | (in.u[w] << 16);
    return out.v;
}
// a_mfma: (kx | ky<<16) -> (ky | (-kx)<<16)
__device__ inline bf16x8 derive_im2(bf16x8 v) {
    union { bf16x8 v; unsigned u[4]; } in, out;
    in.v = v;
#pragma unroll
    for (int w = 0; w < 4; ++w)
        out.u[w] = (in.u[w] >> 16) | ((in.u[w] ^ 0x8000u) << 16);
    return out.v;
}

// ---------------------------------------------------------------------------
// Kernel 0 (trig-free): pe[m,i,j] = exp(i*m*theta) = ((dx+i*dy)/r)^m.
// ---------------------------------------------------------------------------
__global__ void pe_kernel(float2* __restrict__ peIJ) {
    int bid = blockIdx.x;           // m*N + i
    int m = bid >> 8;
    int i = bid & 255;
    int j = threadIdx.x;
    float dy = (float)((j >> 4) - (i >> 4));
    float dx = (float)((j & 15) - (i & 15));
    float r2 = dx * dx + dy * dy;
    float c1 = 1.f, s1 = 0.f;
    if (r2 > 0.f) {
        float rinv = rsqrtf(r2);
        c1 = dx * rinv; s1 = dy * rinv;
    }
    float c = 1.f, s = 0.f;
    for (int k = 0; k < m; ++k) {   // m is block-uniform (0..3)
        float nc = c * c1 - s * s1;
        s = c * s1 + s * c1;
        c = nc;
    }
    peIJ[(m * NN + i) * NN + j] = make_float2(c, s);
}

// ---------------------------------------------------------------------------
// Kernel 1 (merged convA+convB+convW):
// blocks 0..95: emb -> A' split-bf16 ; 96..351: x -> Bre split-bf16 ;
// 352..415: w_out -> WFrag A-operand fragments (K2 = 2k = (wr,wi) packed).
// ---------------------------------------------------------------------------
__global__ void convAB_kernel(const float* __restrict__ er, const float* __restrict__ ei,
                              const float* __restrict__ xr, const float* __restrict__ xi,
                              const float* __restrict__ wor, const float* __restrict__ woi,
                              unsigned int* __restrict__ AbfHi, unsigned int* __restrict__ AbfLo,
                              unsigned int* __restrict__ BreHi, unsigned int* __restrict__ BreLo,
                              unsigned int* __restrict__ WFrag) {
    if (blockIdx.x < 96) {
        int tmh = blockIdx.x;             // 0..95
        int base = tmh * QDD * DD;
#pragma unroll
        for (int it = 0; it < 8; ++it) {
            int idx = threadIdx.x + it * 256;  // q*128+D
            float ar = er[base + idx];
            float ai = ei[base + idx];
            unsigned short arh, arl, aih, ail;
            bfsplit(ar, arh, arl);
            bfsplit(ai, aih, ail);
            AbfHi[base + idx] = (unsigned int)arh | ((unsigned int)aih << 16);
            AbfLo[base + idx] = (unsigned int)arl | ((unsigned int)ail << 16);
        }
        return;
    }
    if (blockIdx.x >= 352) {
        // convW: WFrag[((m*8+dt)*8+ks)*64 + lane][r] = wH | wL<<16 for
        // A[row = dt*16+(lane&15)][K2 = ks*32+(lane>>4)*8+r]; K2 even->wr, odd->wi.
        int c = blockIdx.x - 352;         // 0..63
        int m = c >> 4;
        int dt = (c >> 1) & 7;
        int kshalf = c & 1;
        int tid = threadIdx.x;
        int wav = tid >> 6, lane = tid & 63;
        int ks = kshalf * 4 + wav;
        int D = dt * 16 + (lane & 15);
        unsigned int uu[8];
#pragma unroll
        for (int r = 0; r < 8; ++r) {
            int K2 = ks * 32 + ((lane >> 4) * 8) + r;
            int k = K2 >> 1;
            float v = (K2 & 1) ? woi[(m * DD + D) * KO + k] : wor[(m * DD + D) * KO + k];
            unsigned short hh, ll;
            bfsplit(v, hh, ll);
            uu[r] = (unsigned int)hh | ((unsigned int)ll << 16);
        }
        unsigned int* wp = WFrag + (((size_t)(m * 8 + dt) * 8 + ks) * 64 + lane) * 8;
        *(uint4*)wp = make_uint4(uu[0], uu[1], uu[2], uu[3]);
        *(uint4*)(wp + 4) = make_uint4(uu[4], uu[5], uu[6], uu[7]);
        return;
    }
    int bid = blockIdx.x - 96;            // 0..255 = 32 bm x 8 Dg
    int bm = bid >> 3;
    int Dg = bid & 7;
    int D0 = Dg * 16;
    int tid = threadIdx.x;

    __shared__ float sxr[16][257];
    __shared__ float sxi[16][257];

    const float* xrp = xr + (size_t)bm * DD * NN;
    const float* xip = xi + (size_t)bm * DD * NN;
#pragma unroll
    for (int it = 0; it < 16; ++it) {
        int i2 = tid + it * 256;
        int r = i2 >> 8, c = i2 & 255;
        sxr[r][c] = xrp[(size_t)(D0 + r) * NN + c];
        sxi[r][c] = xip[(size_t)(D0 + r) * NN + c];
    }
    __syncthreads();

    int n = tid;
    unsigned int reh[16], rel_[16];
#pragma unroll
    for (int d = 0; d < 16; ++d) {
        float br = sxr[d][n];
        float bi = sxi[d][n];
        unsigned short brh, brl, bih, bil;
        bfsplit(br, brh, brl);
        bfsplit(bi, bih, bil);
        reh[d]  = (unsigned int)brh | ((unsigned int)(bih ^ 0x8000) << 16);
        rel_[d] = (unsigned int)brl | ((unsigned int)(bil ^ 0x8000) << 16);
    }
    size_t ob = (size_t)bm * 32768 + (size_t)n * 128 + D0;
#pragma unroll
    for (int w = 0; w < 4; ++w) {
        ((uint4*)(BreHi + ob))[w] = make_uint4(reh[4*w], reh[4*w+1], reh[4*w+2], reh[4*w+3]);
        ((uint4*)(BreLo + ob))[w] = make_uint4(rel_[4*w], rel_[4*w+1], rel_[4*w+2], rel_[4*w+3]);
    }
}

// ---------------------------------------------------------------------------
// Kernel 2 (e_mfma v5 = v4 + FUSED qe): block = (pair, h, nhalf). 512 blocks.
// ---------------------------------------------------------------------------
__global__ __launch_bounds__(256, 2)
void e_mfma_kernel(const unsigned short* __restrict__ AbfHi,
                   const unsigned short* __restrict__ AbfLo,
                   const unsigned short* __restrict__ BreHi,
                   const unsigned short* __restrict__ BreLo,
                   const float* __restrict__ encr, const float* __restrict__ enci,
                   float2* __restrict__ E,
                   float2* __restrict__ QE,
                   unsigned int* __restrict__ EaHi, unsigned int* __restrict__ EaLo,
                   unsigned int* __restrict__ KbHi, unsigned int* __restrict__ KbLo) {
    int bid = blockIdx.x;                 // 512 = 8 xcd x 64 idx
    int xcd = bid & 7;
    int idx = bid >> 3;                   // 0..63
    int pair = xcd * 4 + (idx & 3);       // b*MM+m (XCD-pinned B panels)
    int h = (idx >> 2) & 7;               // 0..7
    int nhalf = idx >> 5;                 // 0..1
    int b = pair >> 2, m = pair & 3;
    int tid = threadIdx.x;
    int wav = tid >> 6, lane = tid & 63;
    int lo = lane & 15, hi = lane >> 4;

    const unsigned short* AH[3];
    const unsigned short* AL[3];
#pragma unroll
    for (int t = 0; t < 3; ++t) {
        size_t aoff = ((size_t)((t * MM + m) * NHH + h)) * QDD * 256;
        AH[t] = AbfHi + aoff;
        AL[t] = AbfLo + aoff;
    }
    size_t boff = (size_t)pair * 256 * 256;
    const unsigned short* BrH = BreHi + boff;
    const unsigned short* BrL = BreLo + boff;

    f32x4 accRe[3][2], accIm[3][2];
#pragma unroll
    for (int t = 0; t < 3; ++t)
#pragma unroll
        for (int nt = 0; nt < 2; ++nt) {
            accRe[t][nt] = (f32x4)(0.f);
            accIm[t][nt] = (f32x4)(0.f);
        }

#pragma unroll
    for (int ks = 0; ks < 8; ++ks) {
        int k0 = ks * 32;
        int arow = lo * 256 + k0 + hi * 8;
        bf16x8 aH[3], aL[3];
#pragma unroll
        for (int t = 0; t < 3; ++t) {
            aH[t] = *(const bf16x8*)(AH[t] + arow);
            aL[t] = *(const bf16x8*)(AL[t] + arow);
        }
#pragma unroll
        for (int nt = 0; nt < 2; ++nt) {
            int n0 = nhalf * 128 + (wav * 2 + nt) * 16;
            size_t brow = (size_t)(n0 + lo) * 256 + k0 + hi * 8;
            bf16x8 brh = *(const bf16x8*)(BrH + brow);
            bf16x8 brl = *(const bf16x8*)(BrL + brow);
            bf16x8 bih = derive_im(brh);
            bf16x8 bil = derive_im(brl);
#pragma unroll
            for (int t = 0; t < 3; ++t) {
                accRe[t][nt] = __builtin_amdgcn_mfma_f32_16x16x32_bf16(aH[t], brh, accRe[t][nt], 0, 0, 0);
                accRe[t][nt] = __builtin_amdgcn_mfma_f32_16x16x32_bf16(aH[t], brl, accRe[t][nt], 0, 0, 0);
                accRe[t][nt] = __builtin_amdgcn_mfma_f32_16x16x32_bf16(aL[t], brh, accRe[t][nt], 0, 0, 0);
                accIm[t][nt] = __builtin_amdgcn_mfma_f32_16x16x32_bf16(aH[t], bih, accIm[t][nt], 0, 0, 0);
                accIm[t][nt] = __builtin_amdgcn_mfma_f32_16x16x32_bf16(aH[t], bil, accIm[t][nt], 0, 0, 0);
                accIm[t][nt] = __builtin_amdgcn_mfma_f32_16x16x32_bf16(aL[t], bih, accIm[t][nt], 0, 0, 0);
            }
        }
    }

    int bh = b * NHH + h;

    // --- fused qe: QE[b,m,h,i] = sum_q conj(E0[q,i])*enc0[m,h,q] ---
    {
        float cr[4], ci[4];
#pragma unroll
        for (int reg = 0; reg < 4; ++reg) {
            int q = hi * 4 + reg;
            int eb = (m * NHH + h) * QDD + q;
            cr[reg] = encr[eb];
            ci[reg] = enci[eb];
        }
#pragma unroll
        for (int nt = 0; nt < 2; ++nt) {
            int n0 = nhalf * 128 + (wav * 2 + nt) * 16;
            float sr = 0.f, si = 0.f;
#pragma unroll
            for (int reg = 0; reg < 4; ++reg) {
                float erv = accRe[0][nt][reg];
                float eiv = accIm[0][nt][reg];
                sr = fmaf(erv, cr[reg], fmaf( eiv, ci[reg], sr));
                si = fmaf(erv, ci[reg], fmaf(-eiv, cr[reg], si));
            }
            sr += __shfl_xor(sr, 16); si += __shfl_xor(si, 16);
            sr += __shfl_xor(sr, 32); si += __shfl_xor(si, 32);
            if (hi == 0)
                QE[(size_t)((b * MM + m) * NHH + h) * NN + n0 + lo] = make_float2(sr, si);
        }
    }

    // t=0: Ea fragments ; t=1: Kb fragments ; t=2: E float2 (V).
#pragma unroll
    for (int t = 0; t < 3; ++t) {
        size_t ebase = (size_t)((((t * BB + b) * MM + m) * NHH + h) * QDD) * NN;
#pragma unroll
        for (int nt = 0; nt < 2; ++nt) {
            int n0 = nhalf * 128 + (wav * 2 + nt) * 16;
            if (t == 2) {
#pragma unroll
                for (int reg = 0; reg < 4; ++reg) {
                    int q = hi * 4 + reg;
                    E[ebase + (size_t)q * NN + n0 + lo] =
                        make_float2(accRe[t][nt][reg], accIm[t][nt][reg]);
                }
            }
            if (t < 2) {
                unsigned int hiU[4], loU[4];
#pragma unroll
                for (int reg = 0; reg < 4; ++reg) {
                    unsigned short rh, rl, ih, il;
                    bfsplit(accRe[t][nt][reg], rh, rl);
                    bfsplit(accIm[t][nt][reg], ih, il);
                    hiU[reg] = (unsigned int)rh | ((unsigned int)ih << 16);
                    loU[reg] = (unsigned int)rl | ((unsigned int)il << 16);
                }
                int r = n0 >> 4;
                size_t fo = (size_t)bh * 16384 + (size_t)((r * 4 + m) * 64 + lane) * 4;
                unsigned int* tH = (t == 0) ? EaHi : KbHi;
                unsigned int* tL = (t == 0) ? EaLo : KbLo;
                *(uint4*)(tH + fo) = make_uint4(hiU[0], hiU[1], hiU[2], hiU[3]);
                *(uint4*)(tL + fo) = make_uint4(loU[0], loU[1], loU[2], loU[3]);
            }
        }
    }
}

// ---------------------------------------------------------------------------
// Kernel 3 (score = FUSED a_mfma + softmax + PA, emits Aw B-fragments):
// 1024 blocks = (bh, itile).
// ---------------------------------------------------------------------------
__global__ __launch_bounds__(256)
void score_kernel(const unsigned short* __restrict__ EaHi,
                  const unsigned short* __restrict__ EaLo,
                  const unsigned short* __restrict__ KbHi,
                  const unsigned short* __restrict__ KbLo,
                  const float2* __restrict__ QE,
                  const float2* __restrict__ peIJ,
                  unsigned int* __restrict__ AwFrag,
                  float2* __restrict__ PA) {
    int bid = blockIdx.x;                 // 1024 = 8 xcd x 128 idx
    int xcd = bid & 7;
    int idx = bid >> 3;                   // 0..127
    int bh = xcd * 8 + (idx & 7);         // K-panel XCD-pinned
    int it = idx >> 3;                    // 0..15 i-tile
    int b = bh >> 3, h = bh & 7;
    int tid = threadIdx.x;
    int wav = tid >> 6, lane = tid & 63;
    int lo = lane & 15, hi = lane >> 4;

    const unsigned short* EaH = EaHi + (size_t)bh * 32768;
    const unsigned short* EaL = EaLo + (size_t)bh * 32768;
    const unsigned short* KbH = KbHi + (size_t)bh * 32768;
    const unsigned short* KbL = KbLo + (size_t)bh * 32768;

    __shared__ float st[16][257];         // aw staging (block's 16 rows x 256 j)
    __shared__ float sredA[16][4];        // cross-wave max
    __shared__ float sredB[16][4];        // cross-wave sum
    __shared__ float sPA[16][4][2][4];    // PA partials [row][m][comp][wav]

    f32x4 accRe[4], accIm[4];
#pragma unroll
    for (int nt = 0; nt < 4; ++nt) { accRe[nt] = (f32x4)(0.f); accIm[nt] = (f32x4)(0.f); }

#pragma unroll
    for (int ks = 0; ks < 4; ++ks) {
        size_t arow = (size_t)((it * 4 + ks) * 64 + lane) * 8;   // coalesced
        bf16x8 aH = *(const bf16x8*)(EaH + arow);
        bf16x8 aL = *(const bf16x8*)(EaL + arow);
#pragma unroll
        for (int nt = 0; nt < 4; ++nt) {
            int jt = wav * 4 + nt;
            size_t brow = (size_t)((jt * 4 + ks) * 64 + lane) * 8;  // coalesced
            bf16x8 brh = *(const bf16x8*)(KbH + brow);
            bf16x8 brl = *(const bf16x8*)(KbL + brow);
            bf16x8 bih = derive_im2(brh);
            bf16x8 bil = derive_im2(brl);
            accRe[nt] = __builtin_amdgcn_mfma_f32_16x16x32_bf16(aH, brh, accRe[nt], 0, 0, 0);
            accRe[nt] = __builtin_amdgcn_mfma_f32_16x16x32_bf16(aH, brl, accRe[nt], 0, 0, 0);
            accRe[nt] = __builtin_amdgcn_mfma_f32_16x16x32_bf16(aL, brh, accRe[nt], 0, 0, 0);
            accIm[nt] = __builtin_amdgcn_mfma_f32_16x16x32_bf16(aH, bih, accIm[nt], 0, 0, 0);
            accIm[nt] = __builtin_amdgcn_mfma_f32_16x16x32_bf16(aH, bil, accIm[nt], 0, 0, 0);
            accIm[nt] = __builtin_amdgcn_mfma_f32_16x16x32_bf16(aL, bih, accIm[nt], 0, 0, 0);
        }
    }

    // pass 1: + sum_m QE*pe, magnitude. vmag[nt][reg].
    float vmag[4][4];
#pragma unroll
    for (int reg = 0; reg < 4; ++reg) {
        int i = it * 16 + hi * 4 + reg;
        float2 qe4[MM];
#pragma unroll
        for (int m = 0; m < MM; ++m)
            qe4[m] = QE[(size_t)((b * MM + m) * NHH + h) * NN + i];
#pragma unroll
        for (int nt = 0; nt < 4; ++nt) {
            int j = (wav * 4 + nt) * 16 + lo;
            float ar = accRe[nt][reg];
            float ai = accIm[nt][reg];
#pragma unroll
            for (int m = 0; m < MM; ++m) {
                float2 p = peIJ[(size_t)(m * NN + i) * NN + j];
                ar = fmaf(qe4[m].x, p.x, fmaf(-qe4[m].y, p.y, ar));
                ai = fmaf(qe4[m].x, p.y, fmaf( qe4[m].y, p.x, ai));
            }
            vmag[nt][reg] = sqrtf(fmaf(ar, ar, ai * ai)) * 0.25f;
        }
    }

    // row max: over nt regs, then 16-lane lo group, then cross-wave via LDS.
    float mxr[4];
#pragma unroll
    for (int reg = 0; reg < 4; ++reg) {
        mxr[reg] = fmaxf(fmaxf(vmag[0][reg], vmag[1][reg]),
                         fmaxf(vmag[2][reg], vmag[3][reg]));
#pragma unroll
        for (int off = 1; off < 16; off <<= 1)
            mxr[reg] = fmaxf(mxr[reg], __shfl_xor(mxr[reg], off));
    }
    if (lo == 0) {
#pragma unroll
        for (int reg = 0; reg < 4; ++reg) sredA[hi * 4 + reg][wav] = mxr[reg];
    }
    __syncthreads();
    float mx[4];
#pragma unroll
    for (int reg = 0; reg < 4; ++reg) {
        int r = hi * 4 + reg;
        mx[reg] = fmaxf(fmaxf(sredA[r][0], sredA[r][1]),
                        fmaxf(sredA[r][2], sredA[r][3]));
    }

    // exp + row sum
    float smr[4];
#pragma unroll
    for (int reg = 0; reg < 4; ++reg) smr[reg] = 0.f;
#pragma unroll
    for (int nt = 0; nt < 4; ++nt)
#pragma unroll
        for (int reg = 0; reg < 4; ++reg) {
            vmag[nt][reg] = __expf(vmag[nt][reg] - mx[reg]);
            smr[reg] += vmag[nt][reg];
        }
#pragma unroll
    for (int reg = 0; reg < 4; ++reg) {
#pragma unroll
        for (int off = 1; off < 16; off <<= 1)
            smr[reg] += __shfl_xor(smr[reg], off);
    }
    if (lo == 0) {
#pragma unroll
        for (int reg = 0; reg < 4; ++reg) sredB[hi * 4 + reg][wav] = smr[reg];
    }
    __syncthreads();
    float inv[4];
#pragma unroll
    for (int reg = 0; reg < 4; ++reg) {
        int r = hi * 4 + reg;
        inv[reg] = 1.f / (sredB[r][0] + sredB[r][1] + sredB[r][2] + sredB[r][3]);
    }

    // pass 2: aw -> st; PA partials per (m, reg row).
    float par[MM][4], pai[MM][4];
#pragma unroll
    for (int m = 0; m < MM; ++m)
#pragma unroll
        for (int reg = 0; reg < 4; ++reg) { par[m][reg] = 0.f; pai[m][reg] = 0.f; }
#pragma unroll
    for (int reg = 0; reg < 4; ++reg) {
        int i = it * 16 + hi * 4 + reg;
#pragma unroll
        for (int nt = 0; nt < 4; ++nt) {
            int j = (wav * 4 + nt) * 16 + lo;
            float aw = vmag[nt][reg] * inv[reg];
            st[hi * 4 + reg][j] = aw;
#pragma unroll
            for (int m = 0; m < MM; ++m) {
                float2 p = peIJ[(size_t)(m * NN + i) * NN + j];
                par[m][reg] = fmaf(p.x, aw, par[m][reg]);
                pai[m][reg] = fmaf(p.y, aw, pai[m][reg]);
            }
        }
    }
#pragma unroll
    for (int m = 0; m < MM; ++m)
#pragma unroll
        for (int reg = 0; reg < 4; ++reg) {
#pragma unroll
            for (int off = 1; off < 16; off <<= 1) {
                par[m][reg] += __shfl_xor(par[m][reg], off);
                pai[m][reg] += __shfl_xor(pai[m][reg], off);
            }
        }
    if (lo == 0) {
#pragma unroll
        for (int m = 0; m < MM; ++m)
#pragma unroll
            for (int reg = 0; reg < 4; ++reg) {
                sPA[hi * 4 + reg][m][0][wav] = par[m][reg];
                sPA[hi * 4 + reg][m][1][wav] = pai[m][reg];
            }
    }
    __syncthreads();

    if (tid < 16) {
        int r = tid;
#pragma unroll
        for (int m = 0; m < MM; ++m) {
            float pr  = sPA[r][m][0][0] + sPA[r][m][0][1] + sPA[r][m][0][2] + sPA[r][m][0][3];
            float pim = sPA[r][m][1][0] + sPA[r][m][1][1] + sPA[r][m][1][2] + sPA[r][m][1][3];
            PA[(size_t)((b * MM + m) * NHH + h) * NN + it * 16 + r] = make_float2(pr, pim);
        }
    }

    // Aw fragment emission: wave wav handles ks = wav*2 + {0,1}.
#pragma unroll
    for (int ksl = 0; ksl < 2; ++ksl) {
        int ks = wav * 2 + ksl;
        unsigned int uu[8];
#pragma unroll
        for (int r = 0; r < 8; ++r) {
            float aw = st[lo][ks * 32 + hi * 8 + r];
            unsigned short h2, l2;
            bfsplit(aw, h2, l2);
            uu[r] = (unsigned int)h2 | ((unsigned int)l2 << 16);
        }
        unsigned int* ap = AwFrag + ((((size_t)bh * 16 + it) * 8 + ks) * 64 + lane) * 8;
        *(uint4*)ap = make_uint4(uu[0], uu[1], uu[2], uu[3]);
        *(uint4*)(ap + 4) = make_uint4(uu[4], uu[5], uu[6], uu[7]);
    }
}

// ---------------------------------------------------------------------------
// Kernel 4 (res_mfma v2: Aw x V via MFMA; emits ResFrag B-fragments for
// out_mfma): 512 blocks = (bh, ih). Wave = m.
// ResFrag[((bm*16+nt)*8 + h)*64 + lane][r]: K2 = 32h + (lane>>4)*8 + r,
// even K2 -> rr, odd -> -ri, each packed H|L<<16. (Producer lane mapping is
// identity: lane'=lane, r'=2*reg+c.)
// ---------------------------------------------------------------------------
__global__ __launch_bounds__(256, 2)
void res_mfma_kernel(const float2* __restrict__ E,
                     const unsigned int* __restrict__ AwFrag,
                     const float2* __restrict__ PA,
                     const float* __restrict__ encr, const float* __restrict__ enci,
                     unsigned int* __restrict__ ResFrag) {
    int bid = blockIdx.x;                 // 512 = 8 xcd x 64 idx
    int xcd = bid & 7;
    int idx = bid >> 3;                   // 0..63
    int bh = xcd * 8 + (idx & 7);         // XCD-pinned panels
    int ih = idx >> 3;                    // 0..7 (i-eighth: 2 i-tiles)
    int b = bh >> 3, h = bh & 7;
    int tid = threadIdx.x;
    int m = tid >> 6;                     // wave = m
    int lane = tid & 63;
    int lo = lane & 15, hi = lane >> 4;

    const float2* V = E + ((size_t)(((2 * BB + b) * MM + m) * NHH + h) * QDD) * NN;

    f32x4 accRe[2], accIm[2];
#pragma unroll
    for (int t2 = 0; t2 < 2; ++t2) { accRe[t2] = (f32x4)(0.f); accIm[t2] = (f32x4)(0.f); }

#pragma unroll
    for (int ks = 0; ks < 8; ++ks) {
        // A fragment: V[q=lo][j = ks*32 + hi*8 + r], bf16 split, re/im.
        const float2* vp = V + (size_t)lo * NN + ks * 32 + hi * 8;
        union { bf16x8 v; unsigned short s[8]; } vrh, vrl, vih, vil;
#pragma unroll
        for (int r = 0; r < 8; ++r) {
            float2 v = vp[r];
            unsigned short rh, rl, ih2, il2;
            bfsplit(v.x, rh, rl);
            bfsplit(v.y, ih2, il2);
            vrh.s[r] = rh; vrl.s[r] = rl; vih.s[r] = ih2; vil.s[r] = il2;
        }
#pragma unroll
        for (int t2 = 0; t2 < 2; ++t2) {
            int it = ih * 2 + t2;
            const unsigned int* ap = AwFrag + ((((size_t)bh * 16 + it) * 8 + ks) * 64 + lane) * 8;
            uint4 u0 = *(const uint4*)ap;
            uint4 u1 = *(const uint4*)(ap + 4);
            unsigned int uu[8] = {u0.x, u0.y, u0.z, u0.w, u1.x, u1.y, u1.z, u1.w};
            union { bf16x8 v; unsigned short s[8]; } awh, awl;
#pragma unroll
            for (int r = 0; r < 8; ++r) {
                awh.s[r] = (unsigned short)(uu[r] & 0xffffu);
                awl.s[r] = (unsigned short)(uu[r] >> 16);
            }
            accRe[t2] = __builtin_amdgcn_mfma_f32_16x16x32_bf16(vrh.v, awh.v, accRe[t2], 0, 0, 0);
            accRe[t2] = __builtin_amdgcn_mfma_f32_16x16x32_bf16(vrh.v, awl.v, accRe[t2], 0, 0, 0);
            accRe[t2] = __builtin_amdgcn_mfma_f32_16x16x32_bf16(vrl.v, awh.v, accRe[t2], 0, 0, 0);
            accIm[t2] = __builtin_amdgcn_mfma_f32_16x16x32_bf16(vih.v, awh.v, accIm[t2], 0, 0, 0);
            accIm[t2] = __builtin_amdgcn_mfma_f32_16x16x32_bf16(vih.v, awl.v, accIm[t2], 0, 0, 0);
            accIm[t2] = __builtin_amdgcn_mfma_f32_16x16x32_bf16(vil.v, awh.v, accIm[t2], 0, 0, 0);
        }
    }

    // epilogue: C/D layout col=lo (i in tile), row=hi*4+reg (q).
    float e1r[4], e1i[4];
#pragma unroll
    for (int reg = 0; reg < 4; ++reg) {
        int q = hi * 4 + reg;
        int eb = ((MM + m) * NHH + h) * QDD + q;   // enc[1,m,h,q]
        e1r[reg] = encr[eb];
        e1i[reg] = enci[eb];
    }
    int bm = b * MM + m;
#pragma unroll
    for (int t2 = 0; t2 < 2; ++t2) {
        int nt = ih * 2 + t2;
        int i = nt * 16 + lo;
        float2 pa = PA[(size_t)((b * MM + m) * NHH + h) * NN + i];
        unsigned int uu[8];
#pragma unroll
        for (int reg = 0; reg < 4; ++reg) {
            float rr = accRe[t2][reg] + e1r[reg] * pa.x - e1i[reg] * pa.y;
            float ri = accIm[t2][reg] + e1r[reg] * pa.y + e1i[reg] * pa.x;
            unsigned short hh, ll;
            bfsplit(rr, hh, ll);
            uu[2 * reg] = (unsigned int)hh | ((unsigned int)ll << 16);
            bfsplit(-ri, hh, ll);
            uu[2 * reg + 1] = (unsigned int)hh | ((unsigned int)ll << 16);
        }
        unsigned int* rp = ResFrag + ((((size_t)bm * 16 + nt) * 8 + h) * 64 + lane) * 8;
        *(uint4*)rp = make_uint4(uu[0], uu[1], uu[2], uu[3]);
        *(uint4*)(rp + 4) = make_uint4(uu[4], uu[5], uu[6], uu[7]);
    }
}

// ---------------------------------------------------------------------------
// Kernel 5 (out_mfma: out = w_out x res via MFMA over K2=2k):
// 512 blocks = (bm, dt, nhalf); wave handles 2 ntiles. B_re = ResFrag direct
// unpack (rr, -ri); B_im derived (ri, rr) by pair-swap + negate.
// ---------------------------------------------------------------------------
__global__ __launch_bounds__(256, 2)
void out_mfma_kernel(const unsigned int* __restrict__ ResFrag,
                     const unsigned int* __restrict__ WFrag,
                     float* __restrict__ out) {
    int bid = blockIdx.x;                 // 512 = 8 xcd x 64 idx
    int xcd = bid & 7;
    int idx = bid >> 3;                   // 0..63
    int bm = xcd * 4 + (idx & 3);         // XCD-pinned
    int rest = idx >> 2;                  // 0..15
    int dt = rest >> 1;                   // 0..7
    int nh = rest & 1;
    int m = bm & 3;
    int tid = threadIdx.x;
    int wav = tid >> 6, lane = tid & 63;
    int lo = lane & 15, hi = lane >> 4;

    f32x4 accRe[2], accIm[2];
#pragma unroll
    for (int t = 0; t < 2; ++t) { accRe[t] = (f32x4)(0.f); accIm[t] = (f32x4)(0.f); }

#pragma unroll
    for (int ks = 0; ks < 8; ++ks) {
        const unsigned int* wp = WFrag + (((size_t)(m * 8 + dt) * 8 + ks) * 64 + lane) * 8;
        uint4 w0 = *(const uint4*)wp;
        uint4 w1 = *(const uint4*)(wp + 4);
        unsigned int wu[8] = {w0.x, w0.y, w0.z, w0.w, w1.x, w1.y, w1.z, w1.w};
        union { bf16x8 v; unsigned short s[8]; } aH, aL;
#pragma unroll
        for (int r = 0; r < 8; ++r) {
            aH.s[r] = (unsigned short)(wu[r] & 0xffffu);
            aL.s[r] = (unsigned short)(wu[r] >> 16);
        }
#pragma unroll
        for (int nt2 = 0; nt2 < 2; ++nt2) {
            int nt = nh * 8 + wav * 2 + nt2;
            const unsigned int* rp = ResFrag + ((((size_t)bm * 16 + nt) * 8 + ks) * 64 + lane) * 8;
            uint4 r0 = *(const uint4*)rp;
            uint4 r1 = *(const uint4*)(rp + 4);
            unsigned int ru[8] = {r0.x, r0.y, r0.z, r0.w, r1.x, r1.y, r1.z, r1.w};
            union { bf16x8 v; unsigned short s[8]; } brH, brL, biH, biL;
#pragma unroll
            for (int t = 0; t < 4; ++t) {
                unsigned int ue = ru[2 * t], uo = ru[2 * t + 1];
                brH.s[2 * t]     = (unsigned short)(ue & 0xffffu);
                brL.s[2 * t]     = (unsigned short)(ue >> 16);
                brH.s[2 * t + 1] = (unsigned short)(uo & 0xffffu);
                brL.s[2 * t + 1] = (unsigned short)(uo >> 16);
                biH.s[2 * t]     = (unsigned short)((uo & 0xffffu) ^ 0x8000u);
                biL.s[2 * t]     = (unsigned short)((uo >> 16) ^ 0x8000u);
                biH.s[2 * t + 1] = (unsigned short)(ue & 0xffffu);
                biL.s[2 * t + 1] = (unsigned short)(ue >> 16);
            }
            accRe[nt2] = __builtin_amdgcn_mfma_f32_16x16x32_bf16(aH.v, brH.v, accRe[nt2], 0, 0, 0);
            accRe[nt2] = __builtin_amdgcn_mfma_f32_16x16x32_bf16(aH.v, brL.v, accRe[nt2], 0, 0, 0);
            accRe[nt2] = __builtin_amdgcn_mfma_f32_16x16x32_bf16(aL.v, brH.v, accRe[nt2], 0, 0, 0);
            accIm[nt2] = __builtin_amdgcn_mfma_f32_16x16x32_bf16(aH.v, biH.v, accIm[nt2], 0, 0, 0);
            accIm[nt2] = __builtin_amdgcn_mfma_f32_16x16x32_bf16(aH.v, biL.v, accIm[nt2], 0, 0, 0);
            accIm[nt2] = __builtin_amdgcn_mfma_f32_16x16x32_bf16(aL.v, biH.v, accIm[nt2], 0, 0, 0);
        }
    }

    // epilogue: C/D col = lo (n in tile), row = hi*4+reg (D in tile).
#pragma unroll
    for (int nt2 = 0; nt2 < 2; ++nt2) {
        int n = (nh * 8 + wav * 2 + nt2) * 16 + lo;
#pragma unroll
        for (int reg = 0; reg < 4; ++reg) {
            int D = dt * 16 + hi * 4 + reg;
            size_t ob = (size_t)(bm * DD + D) * NN + n;
            out[ob] = accRe[nt2][reg];
            out[(size_t)BB * MM * DD * NN + ob] = accIm[nt2][reg];
        }
    }
}

// ---------------------------------------------------------------------------
extern "C" void kernel_launch(void* const* d_in, const int* in_sizes, int n_in,
                              void* d_out, int out_size, void* d_ws, size_t ws_size,
                              hipStream_t stream) {
    (void)in_sizes; (void)n_in; (void)out_size; (void)ws_size;

    const float* x_re   = (const float*)d_in[0];
    const float* x_im   = (const float*)d_in[1];
    const float* emb_re = (const float*)d_in[2];
    const float* emb_im = (const float*)d_in[3];
    const float* enc_re = (const float*)d_in[4];
    const float* enc_im = (const float*)d_in[5];
    const float* out_re = (const float*)d_in[6];
    const float* out_im = (const float*)d_in[7];
    float* out = (float*)d_out;

    // Workspace layout (floats). Total ~155.7 MB.
    float* ws = (float*)d_ws;
    size_t off = 0;
    float2* peIJ = (float2*)(ws + off); off += (size_t)MM * NN * NN * 2;          // 524288
    float*  peT  = (float*)(ws + off);  off += (size_t)MM * NN * NN * 2;          // 524288 (hosts PA + WFrag)
    float2* E    = (float2*)(ws + off); off += (size_t)3 * BB * MM * NHH * QDD * NN * 2; // 25165824
    float2* QE   = (float2*)(ws + off); off += (size_t)BB * MM * NHH * NN * 2;    // 131072
    float2* A    = (float2*)(ws + off); off += (size_t)BB * NHH * NN * NN * 2;    // 8388608 fl
    float*  FRAG = (float*)(ws + off);  off += (size_t)BB * NHH * NN * NN;        // 4194304 fl

    // Region plan:
    //  1) convAB stages Abf/Bre at A start + WFrag (peT+1MB); e_mfma reads
    //     Abf/Bre -> writes E t2 (V) + QE + Ea/Kb fragments into FRAG region.
    //  2) score reads Ea/Kb(FRAG) + QE + peIJ -> AwFrag (A +16.8MB) + PA (peT).
    //  3) res_mfma reads AwFrag + PA + V(E t2) -> ResFrag at A start
    //     (Abf/Bre dead; disjoint from AwFrag).
    //  4) out_mfma reads ResFrag + WFrag -> out.
    unsigned int* AbfHi = (unsigned int*)A;
    unsigned int* AbfLo = AbfHi + (size_t)96 * QDD * DD;
    unsigned int* BreHi = AbfLo + (size_t)96 * QDD * DD;
    unsigned int* BreLo = BreHi + (size_t)32 * 256 * 128;

    unsigned int* EaHi = (unsigned int*)FRAG;                     // 4 x 1048576 uints
    unsigned int* EaLo = EaHi + (size_t)64 * 16384;               //  = 16.78MB exact
    unsigned int* KbHi = EaLo + (size_t)64 * 16384;
    unsigned int* KbLo = KbHi + (size_t)64 * 16384;

    unsigned int* ResFrag = (unsigned int*)A;                     // 2.10M uints (8.4MB)
    unsigned int* AwFrag  = (unsigned int*)((float*)A + (size_t)4194304); // A+16.8MB, 8.4MB
    float2* PA    = (float2*)peT;                                 // 0.5MB at peT start
    unsigned int* WFrag = (unsigned int*)(peT + 262144);          // 0.5MB at peT+1MB

    pe_kernel<<<MM * NN, 256, 0, stream>>>(peIJ);
    convAB_kernel<<<96 + 256 + 64, 256, 0, stream>>>(emb_re, emb_im, x_re, x_im,
                                                     out_re, out_im,
                                                     AbfHi, AbfLo, BreHi, BreLo, WFrag);
    e_mfma_kernel<<<512, 256, 0, stream>>>(
        (const unsigned short*)AbfHi, (const unsigned short*)AbfLo,
        (const unsigned short*)BreHi, (const unsigned short*)BreLo,
        enc_re, enc_im, E, QE,
        EaHi, EaLo, KbHi, KbLo);
    score_kernel<<<1024, 256, 0, stream>>>(
        (const unsigned short*)EaHi, (const unsigned short*)EaLo,
        (const unsigned short*)KbHi, (const unsigned short*)KbLo,
        QE, peIJ, AwFrag, PA);
    res_mfma_kernel<<<512, 256, 0, stream>>>(E, AwFrag, PA, enc_re, enc_im, ResFrag);
    out_mfma_kernel<<<512, 256, 0, stream>>>(ResFrag, WFrag, out);
}

// Round 42
// 83.652 us; speedup vs baseline: 1.6669x; 1.1789x over previous
//
#include <hip/hip_runtime.h>
#include <math.h>

// Problem constants (from reference)
#define BB   8      // batch
#define MM   4      // MAXM
#define DD   128    // DIM
#define NHH  8      // heads
#define QDD  16     // head dim
#define NN   256    // H*W
#define KO   128    // NH*QD

typedef __attribute__((ext_vector_type(8))) short bf16x8;   // 8 bf16 (4 VGPR)
typedef __attribute__((ext_vector_type(4))) float f32x4;    // MFMA acc

__device__ inline unsigned short f2bf(float f) {            // RNE float->bf16
    union { float f; unsigned u; } v; v.f = f;
    unsigned r = v.u + 0x7FFF + ((v.u >> 16) & 1);
    return (unsigned short)(r >> 16);
}
__device__ inline float bf2f(unsigned short h) {
    union { unsigned u; float f; } v; v.u = ((unsigned)h) << 16;
    return v.f;
}
// split x = hi + lo (both bf16)
__device__ inline void bfsplit(float x, unsigned short& hi, unsigned short& lo) {
    hi = f2bf(x);
    lo = f2bf(x - bf2f(hi));
}
// e_mfma: (br | -bi<<16) -> (bi | br<<16)
__device__ inline bf16x8 derive_im(bf16x8 v) {
    union { bf16x8 v; unsigned u[4]; } in, out;
    in.v = v;
#pragma unroll
    for (int w = 0; w < 4; ++w)
        out.u[w] = ((in.u[w] >> 16) ^ 0x8000u) | (in.u[w] << 16);
    return out.v;
}
// a_mfma: (kx | ky<<16) -> (ky | (-kx)<<16)
__device__ inline bf16x8 derive_im2(bf16x8 v) {
    union { bf16x8 v; unsigned u[4]; } in, out;
    in.v = v;
#pragma unroll
    for (int w = 0; w < 4; ++w)
        out.u[w] = (in.u[w] >> 16) | ((in.u[w] ^ 0x8000u) << 16);
    return out.v;
}
// trig-free pe base: (c1,s1) = (dx+i*dy)/r  (bitwise same as old pe_kernel)
__device__ inline void pe_base(int i, int j, float& c1, float& s1) {
    float dy = (float)((j >> 4) - (i >> 4));
    float dx = (float)((j & 15) - (i & 15));
    float r2 = dx * dx + dy * dy;
    c1 = 1.f; s1 = 0.f;
    if (r2 > 0.f) {
        float rinv = rsqrtf(r2);
        c1 = dx * rinv; s1 = dy * rinv;
    }
}

// ---------------------------------------------------------------------------
// Kernel 1 (merged convA+convB+convW):
// blocks 0..95: emb -> A' split-bf16 ; 96..351: x -> Bre split-bf16 ;
// 352..415: w_out -> WFrag A-operand fragments (K2 = 2k = (wr,wi) packed).
// ---------------------------------------------------------------------------
__global__ void convAB_kernel(const float* __restrict__ er, const float* __restrict__ ei,
                              const float* __restrict__ xr, const float* __restrict__ xi,
                              const float* __restrict__ wor, const float* __restrict__ woi,
                              unsigned int* __restrict__ AbfHi, unsigned int* __restrict__ AbfLo,
                              unsigned int* __restrict__ BreHi, unsigned int* __restrict__ BreLo,
                              unsigned int* __restrict__ WFrag) {
    if (blockIdx.x < 96) {
        int tmh = blockIdx.x;             // 0..95
        int base = tmh * QDD * DD;
#pragma unroll
        for (int it = 0; it < 8; ++it) {
            int idx = threadIdx.x + it * 256;  // q*128+D
            float ar = er[base + idx];
            float ai = ei[base + idx];
            unsigned short arh, arl, aih, ail;
            bfsplit(ar, arh, arl);
            bfsplit(ai, aih, ail);
            AbfHi[base + idx] = (unsigned int)arh | ((unsigned int)aih << 16);
            AbfLo[base + idx] = (unsigned int)arl | ((unsigned int)ail << 16);
        }
        return;
    }
    if (blockIdx.x >= 352) {
        // convW: WFrag A-operand fragments.
        int c = blockIdx.x - 352;         // 0..63
        int m = c >> 4;
        int dt = (c >> 1) & 7;
        int kshalf = c & 1;
        int tid = threadIdx.x;
        int wav = tid >> 6, lane = tid & 63;
        int ks = kshalf * 4 + wav;
        int D = dt * 16 + (lane & 15);
        unsigned int uu[8];
#pragma unroll
        for (int r = 0; r < 8; ++r) {
            int K2 = ks * 32 + ((lane >> 4) * 8) + r;
            int k = K2 >> 1;
            float v = (K2 & 1) ? woi[(m * DD + D) * KO + k] : wor[(m * DD + D) * KO + k];
            unsigned short hh, ll;
            bfsplit(v, hh, ll);
            uu[r] = (unsigned int)hh | ((unsigned int)ll << 16);
        }
        unsigned int* wp = WFrag + (((size_t)(m * 8 + dt) * 8 + ks) * 64 + lane) * 8;
        *(uint4*)wp = make_uint4(uu[0], uu[1], uu[2], uu[3]);
        *(uint4*)(wp + 4) = make_uint4(uu[4], uu[5], uu[6], uu[7]);
        return;
    }
    int bid = blockIdx.x - 96;            // 0..255 = 32 bm x 8 Dg
    int bm = bid >> 3;
    int Dg = bid & 7;
    int D0 = Dg * 16;
    int tid = threadIdx.x;

    __shared__ float sxr[16][257];
    __shared__ float sxi[16][257];

    const float* xrp = xr + (size_t)bm * DD * NN;
    const float* xip = xi + (size_t)bm * DD * NN;
#pragma unroll
    for (int it = 0; it < 16; ++it) {
        int i2 = tid + it * 256;
        int r = i2 >> 8, c = i2 & 255;
        sxr[r][c] = xrp[(size_t)(D0 + r) * NN + c];
        sxi[r][c] = xip[(size_t)(D0 + r) * NN + c];
    }
    __syncthreads();

    int n = tid;
    unsigned int reh[16], rel_[16];
#pragma unroll
    for (int d = 0; d < 16; ++d) {
        float br = sxr[d][n];
        float bi = sxi[d][n];
        unsigned short brh, brl, bih, bil;
        bfsplit(br, brh, brl);
        bfsplit(bi, bih, bil);
        reh[d]  = (unsigned int)brh | ((unsigned int)(bih ^ 0x8000) << 16);
        rel_[d] = (unsigned int)brl | ((unsigned int)(bil ^ 0x8000) << 16);
    }
    size_t ob = (size_t)bm * 32768 + (size_t)n * 128 + D0;
#pragma unroll
    for (int w = 0; w < 4; ++w) {
        ((uint4*)(BreHi + ob))[w] = make_uint4(reh[4*w], reh[4*w+1], reh[4*w+2], reh[4*w+3]);
        ((uint4*)(BreLo + ob))[w] = make_uint4(rel_[4*w], rel_[4*w+1], rel_[4*w+2], rel_[4*w+3]);
    }
}

// ---------------------------------------------------------------------------
// Kernel 2 (e_mfma v6 = v5 + VFrag emission): block = (pair, h, nhalf).
// 512 blocks. t=0 -> Ea fragments + fused qe; t=1 -> Kb fragments;
// t=2 (V) -> LDS transpose -> pre-split A-operand fragments VFragRe/Im
// (E float2 plane deleted; V split done ONCE here instead of 8x in res).
// ---------------------------------------------------------------------------
__global__ __launch_bounds__(256, 2)
void e_mfma_kernel(const unsigned short* __restrict__ AbfHi,
                   const unsigned short* __restrict__ AbfLo,
                   const unsigned short* __restrict__ BreHi,
                   const unsigned short* __restrict__ BreLo,
                   const float* __restrict__ encr, const float* __restrict__ enci,
                   float2* __restrict__ QE,
                   unsigned int* __restrict__ EaHi, unsigned int* __restrict__ EaLo,
                   unsigned int* __restrict__ KbHi, unsigned int* __restrict__ KbLo,
                   unsigned int* __restrict__ VFragRe, unsigned int* __restrict__ VFragIm) {
    int bid = blockIdx.x;                 // 512 = 8 xcd x 64 idx
    int xcd = bid & 7;
    int idx = bid >> 3;                   // 0..63
    int pair = xcd * 4 + (idx & 3);       // b*MM+m (XCD-pinned B panels)
    int h = (idx >> 2) & 7;               // 0..7
    int nhalf = idx >> 5;                 // 0..1
    int b = pair >> 2, m = pair & 3;
    int tid = threadIdx.x;
    int wav = tid >> 6, lane = tid & 63;
    int lo = lane & 15, hi = lane >> 4;

    __shared__ float2 sv[16][130];        // V transpose staging (16.6 KB)

    const unsigned short* AH[3];
    const unsigned short* AL[3];
#pragma unroll
    for (int t = 0; t < 3; ++t) {
        size_t aoff = ((size_t)((t * MM + m) * NHH + h)) * QDD * 256;
        AH[t] = AbfHi + aoff;
        AL[t] = AbfLo + aoff;
    }
    size_t boff = (size_t)pair * 256 * 256;
    const unsigned short* BrH = BreHi + boff;
    const unsigned short* BrL = BreLo + boff;

    f32x4 accRe[3][2], accIm[3][2];
#pragma unroll
    for (int t = 0; t < 3; ++t)
#pragma unroll
        for (int nt = 0; nt < 2; ++nt) {
            accRe[t][nt] = (f32x4)(0.f);
            accIm[t][nt] = (f32x4)(0.f);
        }

#pragma unroll
    for (int ks = 0; ks < 8; ++ks) {
        int k0 = ks * 32;
        int arow = lo * 256 + k0 + hi * 8;
        bf16x8 aH[3], aL[3];
#pragma unroll
        for (int t = 0; t < 3; ++t) {
            aH[t] = *(const bf16x8*)(AH[t] + arow);
            aL[t] = *(const bf16x8*)(AL[t] + arow);
        }
#pragma unroll
        for (int nt = 0; nt < 2; ++nt) {
            int n0 = nhalf * 128 + (wav * 2 + nt) * 16;
            size_t brow = (size_t)(n0 + lo) * 256 + k0 + hi * 8;
            bf16x8 brh = *(const bf16x8*)(BrH + brow);
            bf16x8 brl = *(const bf16x8*)(BrL + brow);
            bf16x8 bih = derive_im(brh);
            bf16x8 bil = derive_im(brl);
#pragma unroll
            for (int t = 0; t < 3; ++t) {
                accRe[t][nt] = __builtin_amdgcn_mfma_f32_16x16x32_bf16(aH[t], brh, accRe[t][nt], 0, 0, 0);
                accRe[t][nt] = __builtin_amdgcn_mfma_f32_16x16x32_bf16(aH[t], brl, accRe[t][nt], 0, 0, 0);
                accRe[t][nt] = __builtin_amdgcn_mfma_f32_16x16x32_bf16(aL[t], brh, accRe[t][nt], 0, 0, 0);
                accIm[t][nt] = __builtin_amdgcn_mfma_f32_16x16x32_bf16(aH[t], bih, accIm[t][nt], 0, 0, 0);
                accIm[t][nt] = __builtin_amdgcn_mfma_f32_16x16x32_bf16(aH[t], bil, accIm[t][nt], 0, 0, 0);
                accIm[t][nt] = __builtin_amdgcn_mfma_f32_16x16x32_bf16(aL[t], bih, accIm[t][nt], 0, 0, 0);
            }
        }
    }

    int bh = b * NHH + h;

    // t=2 (V) -> LDS staging (block covers q 0..15 x j-local 0..127)
#pragma unroll
    for (int nt = 0; nt < 2; ++nt) {
        int nl = (wav * 2 + nt) * 16;
#pragma unroll
        for (int reg = 0; reg < 4; ++reg)
            sv[hi * 4 + reg][nl + lo] = make_float2(accRe[2][nt][reg], accIm[2][nt][reg]);
    }

    // --- fused qe: QE[b,m,h,i] = sum_q conj(E0[q,i])*enc0[m,h,q] ---
    {
        float cr[4], ci[4];
#pragma unroll
        for (int reg = 0; reg < 4; ++reg) {
            int q = hi * 4 + reg;
            int eb = (m * NHH + h) * QDD + q;
            cr[reg] = encr[eb];
            ci[reg] = enci[eb];
        }
#pragma unroll
        for (int nt = 0; nt < 2; ++nt) {
            int n0 = nhalf * 128 + (wav * 2 + nt) * 16;
            float sr = 0.f, si = 0.f;
#pragma unroll
            for (int reg = 0; reg < 4; ++reg) {
                float erv = accRe[0][nt][reg];
                float eiv = accIm[0][nt][reg];
                sr = fmaf(erv, cr[reg], fmaf( eiv, ci[reg], sr));
                si = fmaf(erv, ci[reg], fmaf(-eiv, cr[reg], si));
            }
            sr += __shfl_xor(sr, 16); si += __shfl_xor(si, 16);
            sr += __shfl_xor(sr, 32); si += __shfl_xor(si, 32);
            if (hi == 0)
                QE[(size_t)((b * MM + m) * NHH + h) * NN + n0 + lo] = make_float2(sr, si);
        }
    }

    // t=0: Ea fragments ; t=1: Kb fragments.
#pragma unroll
    for (int t = 0; t < 2; ++t) {
#pragma unroll
        for (int nt = 0; nt < 2; ++nt) {
            int n0 = nhalf * 128 + (wav * 2 + nt) * 16;
            unsigned int hiU[4], loU[4];
#pragma unroll
            for (int reg = 0; reg < 4; ++reg) {
                unsigned short rh, rl, ih, il;
                bfsplit(accRe[t][nt][reg], rh, rl);
                bfsplit(accIm[t][nt][reg], ih, il);
                hiU[reg] = (unsigned int)rh | ((unsigned int)ih << 16);
                loU[reg] = (unsigned int)rl | ((unsigned int)il << 16);
            }
            int r = n0 >> 4;
            size_t fo = (size_t)bh * 16384 + (size_t)((r * 4 + m) * 64 + lane) * 4;
            unsigned int* tH = (t == 0) ? EaHi : KbHi;
            unsigned int* tL = (t == 0) ? EaLo : KbLo;
            *(uint4*)(tH + fo) = make_uint4(hiU[0], hiU[1], hiU[2], hiU[3]);
            *(uint4*)(tL + fo) = make_uint4(loU[0], loU[1], loU[2], loU[3]);
        }
    }

    __syncthreads();

    // VFrag emission: wave wav -> ks = nhalf*4 + wav. Consumer-lane identity:
    // lane (lo,hi), elem r = V[q=lo][j = ks*32 + hi*8 + r], re/im split.
    {
        int ks = nhalf * 4 + wav;
        unsigned int uR[8], uI[8];
#pragma unroll
        for (int r = 0; r < 8; ++r) {
            float2 v = sv[lo][wav * 32 + hi * 8 + r];
            unsigned short rh, rl, ih2, il2;
            bfsplit(v.x, rh, rl);
            bfsplit(v.y, ih2, il2);
            uR[r] = (unsigned int)rh | ((unsigned int)rl << 16);
            uI[r] = (unsigned int)ih2 | ((unsigned int)il2 << 16);
        }
        size_t vo = ((((size_t)((b * MM + m) * NHH + h)) * 8 + ks) * 64 + lane) * 8;
        *(uint4*)(VFragRe + vo)     = make_uint4(uR[0], uR[1], uR[2], uR[3]);
        *(uint4*)(VFragRe + vo + 4) = make_uint4(uR[4], uR[5], uR[6], uR[7]);
        *(uint4*)(VFragIm + vo)     = make_uint4(uI[0], uI[1], uI[2], uI[3]);
        *(uint4*)(VFragIm + vo + 4) = make_uint4(uI[4], uI[5], uI[6], uI[7]);
    }
}

// ---------------------------------------------------------------------------
// Kernel 3 (score = FUSED a_mfma + softmax + PA; pe computed INLINE
// trig-free — pe_kernel + peIJ buffer deleted): 1024 blocks = (bh, itile).
// ---------------------------------------------------------------------------
__global__ __launch_bounds__(256)
void score_kernel(const unsigned short* __restrict__ EaHi,
                  const unsigned short* __restrict__ EaLo,
                  const unsigned short* __restrict__ KbHi,
                  const unsigned short* __restrict__ KbLo,
                  const float2* __restrict__ QE,
                  unsigned int* __restrict__ AwFrag,
                  float2* __restrict__ PA) {
    int bid = blockIdx.x;                 // 1024 = 8 xcd x 128 idx
    int xcd = bid & 7;
    int idx = bid >> 3;                   // 0..127
    int bh = xcd * 8 + (idx & 7);         // K-panel XCD-pinned
    int it = idx >> 3;                    // 0..15 i-tile
    int b = bh >> 3, h = bh & 7;
    int tid = threadIdx.x;
    int wav = tid >> 6, lane = tid & 63;
    int lo = lane & 15, hi = lane >> 4;

    const unsigned short* EaH = EaHi + (size_t)bh * 32768;
    const unsigned short* EaL = EaLo + (size_t)bh * 32768;
    const unsigned short* KbH = KbHi + (size_t)bh * 32768;
    const unsigned short* KbL = KbLo + (size_t)bh * 32768;

    __shared__ float st[16][257];         // aw staging (block's 16 rows x 256 j)
    __shared__ float sredA[16][4];        // cross-wave max
    __shared__ float sredB[16][4];        // cross-wave sum
    __shared__ float sPA[16][4][2][4];    // PA partials [row][m][comp][wav]

    f32x4 accRe[4], accIm[4];
#pragma unroll
    for (int nt = 0; nt < 4; ++nt) { accRe[nt] = (f32x4)(0.f); accIm[nt] = (f32x4)(0.f); }

#pragma unroll
    for (int ks = 0; ks < 4; ++ks) {
        size_t arow = (size_t)((it * 4 + ks) * 64 + lane) * 8;   // coalesced
        bf16x8 aH = *(const bf16x8*)(EaH + arow);
        bf16x8 aL = *(const bf16x8*)(EaL + arow);
#pragma unroll
        for (int nt = 0; nt < 4; ++nt) {
            int jt = wav * 4 + nt;
            size_t brow = (size_t)((jt * 4 + ks) * 64 + lane) * 8;  // coalesced
            bf16x8 brh = *(const bf16x8*)(KbH + brow);
            bf16x8 brl = *(const bf16x8*)(KbL + brow);
            bf16x8 bih = derive_im2(brh);
            bf16x8 bil = derive_im2(brl);
            accRe[nt] = __builtin_amdgcn_mfma_f32_16x16x32_bf16(aH, brh, accRe[nt], 0, 0, 0);
            accRe[nt] = __builtin_amdgcn_mfma_f32_16x16x32_bf16(aH, brl, accRe[nt], 0, 0, 0);
            accRe[nt] = __builtin_amdgcn_mfma_f32_16x16x32_bf16(aL, brh, accRe[nt], 0, 0, 0);
            accIm[nt] = __builtin_amdgcn_mfma_f32_16x16x32_bf16(aH, bih, accIm[nt], 0, 0, 0);
            accIm[nt] = __builtin_amdgcn_mfma_f32_16x16x32_bf16(aH, bil, accIm[nt], 0, 0, 0);
            accIm[nt] = __builtin_amdgcn_mfma_f32_16x16x32_bf16(aL, bih, accIm[nt], 0, 0, 0);
        }
    }

    // pass 1: + sum_m QE*pe (pe inline), magnitude. vmag[nt][reg].
    float vmag[4][4];
#pragma unroll
    for (int reg = 0; reg < 4; ++reg) {
        int i = it * 16 + hi * 4 + reg;
        float2 qe4[MM];
#pragma unroll
        for (int m = 0; m < MM; ++m)
            qe4[m] = QE[(size_t)((b * MM + m) * NHH + h) * NN + i];
#pragma unroll
        for (int nt = 0; nt < 4; ++nt) {
            int j = (wav * 4 + nt) * 16 + lo;
            float c1, s1;
            pe_base(i, j, c1, s1);
            float ar = accRe[nt][reg];
            float ai = accIm[nt][reg];
            float c = 1.f, s = 0.f;
#pragma unroll
            for (int m = 0; m < MM; ++m) {
                ar = fmaf(qe4[m].x, c, fmaf(-qe4[m].y, s, ar));
                ai = fmaf(qe4[m].x, s, fmaf( qe4[m].y, c, ai));
                float nc = c * c1 - s * s1;
                s = c * s1 + s * c1;
                c = nc;
            }
            vmag[nt][reg] = sqrtf(fmaf(ar, ar, ai * ai)) * 0.25f;
        }
    }

    // row max: over nt regs, then 16-lane lo group, then cross-wave via LDS.
    float mxr[4];
#pragma unroll
    for (int reg = 0; reg < 4; ++reg) {
        mxr[reg] = fmaxf(fmaxf(vmag[0][reg], vmag[1][reg]),
                         fmaxf(vmag[2][reg], vmag[3][reg]));
#pragma unroll
        for (int off = 1; off < 16; off <<= 1)
            mxr[reg] = fmaxf(mxr[reg], __shfl_xor(mxr[reg], off));
    }
    if (lo == 0) {
#pragma unroll
        for (int reg = 0; reg < 4; ++reg) sredA[hi * 4 + reg][wav] = mxr[reg];
    }
    __syncthreads();
    float mx[4];
#pragma unroll
    for (int reg = 0; reg < 4; ++reg) {
        int r = hi * 4 + reg;
        mx[reg] = fmaxf(fmaxf(sredA[r][0], sredA[r][1]),
                        fmaxf(sredA[r][2], sredA[r][3]));
    }

    // exp + row sum
    float smr[4];
#pragma unroll
    for (int reg = 0; reg < 4; ++reg) smr[reg] = 0.f;
#pragma unroll
    for (int nt = 0; nt < 4; ++nt)
#pragma unroll
        for (int reg = 0; reg < 4; ++reg) {
            vmag[nt][reg] = __expf(vmag[nt][reg] - mx[reg]);
            smr[reg] += vmag[nt][reg];
        }
#pragma unroll
    for (int reg = 0; reg < 4; ++reg) {
#pragma unroll
        for (int off = 1; off < 16; off <<= 1)
            smr[reg] += __shfl_xor(smr[reg], off);
    }
    if (lo == 0) {
#pragma unroll
        for (int reg = 0; reg < 4; ++reg) sredB[hi * 4 + reg][wav] = smr[reg];
    }
    __syncthreads();
    float inv[4];
#pragma unroll
    for (int reg = 0; reg < 4; ++reg) {
        int r = hi * 4 + reg;
        inv[reg] = 1.f / (sredB[r][0] + sredB[r][1] + sredB[r][2] + sredB[r][3]);
    }

    // pass 2: aw -> st; PA partials per (m, reg row); pe inline again.
    float par[MM][4], pai[MM][4];
#pragma unroll
    for (int m = 0; m < MM; ++m)
#pragma unroll
        for (int reg = 0; reg < 4; ++reg) { par[m][reg] = 0.f; pai[m][reg] = 0.f; }
#pragma unroll
    for (int reg = 0; reg < 4; ++reg) {
        int i = it * 16 + hi * 4 + reg;
#pragma unroll
        for (int nt = 0; nt < 4; ++nt) {
            int j = (wav * 4 + nt) * 16 + lo;
            float aw = vmag[nt][reg] * inv[reg];
            st[hi * 4 + reg][j] = aw;
            float c1, s1;
            pe_base(i, j, c1, s1);
            float c = 1.f, s = 0.f;
#pragma unroll
            for (int m = 0; m < MM; ++m) {
                par[m][reg] = fmaf(c, aw, par[m][reg]);
                pai[m][reg] = fmaf(s, aw, pai[m][reg]);
                float nc = c * c1 - s * s1;
                s = c * s1 + s * c1;
                c = nc;
            }
        }
    }
#pragma unroll
    for (int m = 0; m < MM; ++m)
#pragma unroll
        for (int reg = 0; reg < 4; ++reg) {
#pragma unroll
            for (int off = 1; off < 16; off <<= 1) {
                par[m][reg] += __shfl_xor(par[m][reg], off);
                pai[m][reg] += __shfl_xor(pai[m][reg], off);
            }
        }
    if (lo == 0) {
#pragma unroll
        for (int m = 0; m < MM; ++m)
#pragma unroll
            for (int reg = 0; reg < 4; ++reg) {
                sPA[hi * 4 + reg][m][0][wav] = par[m][reg];
                sPA[hi * 4 + reg][m][1][wav] = pai[m][reg];
            }
    }
    __syncthreads();

    if (tid < 16) {
        int r = tid;
#pragma unroll
        for (int m = 0; m < MM; ++m) {
            float pr  = sPA[r][m][0][0] + sPA[r][m][0][1] + sPA[r][m][0][2] + sPA[r][m][0][3];
            float pim = sPA[r][m][1][0] + sPA[r][m][1][1] + sPA[r][m][1][2] + sPA[r][m][1][3];
            PA[(size_t)((b * MM + m) * NHH + h) * NN + it * 16 + r] = make_float2(pr, pim);
        }
    }

    // Aw fragment emission: wave wav handles ks = wav*2 + {0,1}.
#pragma unroll
    for (int ksl = 0; ksl < 2; ++ksl) {
        int ks = wav * 2 + ksl;
        unsigned int uu[8];
#pragma unroll
        for (int r = 0; r < 8; ++r) {
            float aw = st[lo][ks * 32 + hi * 8 + r];
            unsigned short h2, l2;
            bfsplit(aw, h2, l2);
            uu[r] = (unsigned int)h2 | ((unsigned int)l2 << 16);
        }
        unsigned int* ap = AwFrag + ((((size_t)bh * 16 + it) * 8 + ks) * 64 + lane) * 8;
        *(uint4*)ap = make_uint4(uu[0], uu[1], uu[2], uu[3]);
        *(uint4*)(ap + 4) = make_uint4(uu[4], uu[5], uu[6], uu[7]);
    }
}

// ---------------------------------------------------------------------------
// Kernel 4 (res_mfma v3: pure fragment-load + MFMA; V pre-split by e_mfma):
// 512 blocks = (bh, ih). Wave = m. Emits ResFrag for out_mfma.
// ---------------------------------------------------------------------------
__global__ __launch_bounds__(256, 2)
void res_mfma_kernel(const unsigned int* __restrict__ VFragRe,
                     const unsigned int* __restrict__ VFragIm,
                     const unsigned int* __restrict__ AwFrag,
                     const float2* __restrict__ PA,
                     const float* __restrict__ encr, const float* __restrict__ enci,
                     unsigned int* __restrict__ ResFrag) {
    int bid = blockIdx.x;                 // 512 = 8 xcd x 64 idx
    int xcd = bid & 7;
    int idx = bid >> 3;                   // 0..63
    int bh = xcd * 8 + (idx & 7);         // XCD-pinned panels
    int ih = idx >> 3;                    // 0..7 (i-eighth: 2 i-tiles)
    int b = bh >> 3, h = bh & 7;
    int tid = threadIdx.x;
    int m = tid >> 6;                     // wave = m
    int lane = tid & 63;
    int lo = lane & 15, hi = lane >> 4;

    f32x4 accRe[2], accIm[2];
#pragma unroll
    for (int t2 = 0; t2 < 2; ++t2) { accRe[t2] = (f32x4)(0.f); accIm[t2] = (f32x4)(0.f); }

#pragma unroll
    for (int ks = 0; ks < 8; ++ks) {
        size_t vo = ((((size_t)((b * MM + m) * NHH + h)) * 8 + ks) * 64 + lane) * 8;
        uint4 vr0 = *(const uint4*)(VFragRe + vo);
        uint4 vr1 = *(const uint4*)(VFragRe + vo + 4);
        uint4 vi0 = *(const uint4*)(VFragIm + vo);
        uint4 vi1 = *(const uint4*)(VFragIm + vo + 4);
        unsigned int uR[8] = {vr0.x, vr0.y, vr0.z, vr0.w, vr1.x, vr1.y, vr1.z, vr1.w};
        unsigned int uI[8] = {vi0.x, vi0.y, vi0.z, vi0.w, vi1.x, vi1.y, vi1.z, vi1.w};
        union { bf16x8 v; unsigned short s[8]; } vrh, vrl, vih, vil;
#pragma unroll
        for (int r = 0; r < 8; ++r) {
            vrh.s[r] = (unsigned short)(uR[r] & 0xffffu);
            vrl.s[r] = (unsigned short)(uR[r] >> 16);
            vih.s[r] = (unsigned short)(uI[r] & 0xffffu);
            vil.s[r] = (unsigned short)(uI[r] >> 16);
        }
#pragma unroll
        for (int t2 = 0; t2 < 2; ++t2) {
            int it = ih * 2 + t2;
            const unsigned int* ap = AwFrag + ((((size_t)bh * 16 + it) * 8 + ks) * 64 + lane) * 8;
            uint4 u0 = *(const uint4*)ap;
            uint4 u1 = *(const uint4*)(ap + 4);
            unsigned int uu[8] = {u0.x, u0.y, u0.z, u0.w, u1.x, u1.y, u1.z, u1.w};
            union { bf16x8 v; unsigned short s[8]; } awh, awl;
#pragma unroll
            for (int r = 0; r < 8; ++r) {
                awh.s[r] = (unsigned short)(uu[r] & 0xffffu);
                awl.s[r] = (unsigned short)(uu[r] >> 16);
            }
            accRe[t2] = __builtin_amdgcn_mfma_f32_16x16x32_bf16(vrh.v, awh.v, accRe[t2], 0, 0, 0);
            accRe[t2] = __builtin_amdgcn_mfma_f32_16x16x32_bf16(vrh.v, awl.v, accRe[t2], 0, 0, 0);
            accRe[t2] = __builtin_amdgcn_mfma_f32_16x16x32_bf16(vrl.v, awh.v, accRe[t2], 0, 0, 0);
            accIm[t2] = __builtin_amdgcn_mfma_f32_16x16x32_bf16(vih.v, awh.v, accIm[t2], 0, 0, 0);
            accIm[t2] = __builtin_amdgcn_mfma_f32_16x16x32_bf16(vih.v, awl.v, accIm[t2], 0, 0, 0);
            accIm[t2] = __builtin_amdgcn_mfma_f32_16x16x32_bf16(vil.v, awh.v, accIm[t2], 0, 0, 0);
        }
    }

    // epilogue: C/D layout col=lo (i in tile), row=hi*4+reg (q).
    float e1r[4], e1i[4];
#pragma unroll
    for (int reg = 0; reg < 4; ++reg) {
        int q = hi * 4 + reg;
        int eb = ((MM + m) * NHH + h) * QDD + q;   // enc[1,m,h,q]
        e1r[reg] = encr[eb];
        e1i[reg] = enci[eb];
    }
    int bm = b * MM + m;
#pragma unroll
    for (int t2 = 0; t2 < 2; ++t2) {
        int nt = ih * 2 + t2;
        int i = nt * 16 + lo;
        float2 pa = PA[(size_t)((b * MM + m) * NHH + h) * NN + i];
        unsigned int uu[8];
#pragma unroll
        for (int reg = 0; reg < 4; ++reg) {
            float rr = accRe[t2][reg] + e1r[reg] * pa.x - e1i[reg] * pa.y;
            float ri = accIm[t2][reg] + e1r[reg] * pa.y + e1i[reg] * pa.x;
            unsigned short hh, ll;
            bfsplit(rr, hh, ll);
            uu[2 * reg] = (unsigned int)hh | ((unsigned int)ll << 16);
            bfsplit(-ri, hh, ll);
            uu[2 * reg + 1] = (unsigned int)hh | ((unsigned int)ll << 16);
        }
        unsigned int* rp = ResFrag + ((((size_t)bm * 16 + nt) * 8 + h) * 64 + lane) * 8;
        *(uint4*)rp = make_uint4(uu[0], uu[1], uu[2], uu[3]);
        *(uint4*)(rp + 4) = make_uint4(uu[4], uu[5], uu[6], uu[7]);
    }
}

// ---------------------------------------------------------------------------
// Kernel 5 (out_mfma: out = w_out x res via MFMA over K2=2k):
// 512 blocks = (bm, dt, nhalf); wave handles 2 ntiles.
// ---------------------------------------------------------------------------
__global__ __launch_bounds__(256, 2)
void out_mfma_kernel(const unsigned int* __restrict__ ResFrag,
                     const unsigned int* __restrict__ WFrag,
                     float* __restrict__ out) {
    int bid = blockIdx.x;                 // 512 = 8 xcd x 64 idx
    int xcd = bid & 7;
    int idx = bid >> 3;                   // 0..63
    int bm = xcd * 4 + (idx & 3);         // XCD-pinned
    int rest = idx >> 2;                  // 0..15
    int dt = rest >> 1;                   // 0..7
    int nh = rest & 1;
    int m = bm & 3;
    int tid = threadIdx.x;
    int wav = tid >> 6, lane = tid & 63;
    int lo = lane & 15, hi = lane >> 4;

    f32x4 accRe[2], accIm[2];
#pragma unroll
    for (int t = 0; t < 2; ++t) { accRe[t] = (f32x4)(0.f); accIm[t] = (f32x4)(0.f); }

#pragma unroll
    for (int ks = 0; ks < 8; ++ks) {
        const unsigned int* wp = WFrag + (((size_t)(m * 8 + dt) * 8 + ks) * 64 + lane) * 8;
        uint4 w0 = *(const uint4*)wp;
        uint4 w1 = *(const uint4*)(wp + 4);
        unsigned int wu[8] = {w0.x, w0.y, w0.z, w0.w, w1.x, w1.y, w1.z, w1.w};
        union { bf16x8 v; unsigned short s[8]; } aH, aL;
#pragma unroll
        for (int r = 0; r < 8; ++r) {
            aH.s[r] = (unsigned short)(wu[r] & 0xffffu);
            aL.s[r] = (unsigned short)(wu[r] >> 16);
        }
#pragma unroll
        for (int nt2 = 0; nt2 < 2; ++nt2) {
            int nt = nh * 8 + wav * 2 + nt2;
            const unsigned int* rp = ResFrag + ((((size_t)bm * 16 + nt) * 8 + ks) * 64 + lane) * 8;
            uint4 r0 = *(const uint4*)rp;
            uint4 r1 = *(const uint4*)(rp + 4);
            unsigned int ru[8] = {r0.x, r0.y, r0.z, r0.w, r1.x, r1.y, r1.z, r1.w};
            union { bf16x8 v; unsigned short s[8]; } brH, brL, biH, biL;
#pragma unroll
            for (int t = 0; t < 4; ++t) {
                unsigned int ue = ru[2 * t], uo = ru[2 * t + 1];
                brH.s[2 * t]     = (unsigned short)(ue & 0xffffu);
                brL.s[2 * t]     = (unsigned short)(ue >> 16);
                brH.s[2 * t + 1] = (unsigned short)(uo & 0xffffu);
                brL.s[2 * t + 1] = (unsigned short)(uo >> 16);
                biH.s[2 * t]     = (unsigned short)((uo & 0xffffu) ^ 0x8000u);
                biL.s[2 * t]     = (unsigned short)((uo >> 16) ^ 0x8000u);
                biH.s[2 * t + 1] = (unsigned short)(ue & 0xffffu);
                biL.s[2 * t + 1] = (unsigned short)(ue >> 16);
            }
            accRe[nt2] = __builtin_amdgcn_mfma_f32_16x16x32_bf16(aH.v, brH.v, accRe[nt2], 0, 0, 0);
            accRe[nt2] = __builtin_amdgcn_mfma_f32_16x16x32_bf16(aH.v, brL.v, accRe[nt2], 0, 0, 0);
            accRe[nt2] = __builtin_amdgcn_mfma_f32_16x16x32_bf16(aL.v, brH.v, accRe[nt2], 0, 0, 0);
            accIm[nt2] = __builtin_amdgcn_mfma_f32_16x16x32_bf16(aH.v, biH.v, accIm[nt2], 0, 0, 0);
            accIm[nt2] = __builtin_amdgcn_mfma_f32_16x16x32_bf16(aH.v, biL.v, accIm[nt2], 0, 0, 0);
            accIm[nt2] = __builtin_amdgcn_mfma_f32_16x16x32_bf16(aL.v, biH.v, accIm[nt2], 0, 0, 0);
        }
    }

    // epilogue: C/D col = lo (n in tile), row = hi*4+reg (D in tile).
#pragma unroll
    for (int nt2 = 0; nt2 < 2; ++nt2) {
        int n = (nh * 8 + wav * 2 + nt2) * 16 + lo;
#pragma unroll
        for (int reg = 0; reg < 4; ++reg) {
            int D = dt * 16 + hi * 4 + reg;
            size_t ob = (size_t)(bm * DD + D) * NN + n;
            out[ob] = accRe[nt2][reg];
            out[(size_t)BB * MM * DD * NN + ob] = accIm[nt2][reg];
        }
    }
}

// ---------------------------------------------------------------------------
extern "C" void kernel_launch(void* const* d_in, const int* in_sizes, int n_in,
                              void* d_out, int out_size, void* d_ws, size_t ws_size,
                              hipStream_t stream) {
    (void)in_sizes; (void)n_in; (void)out_size; (void)ws_size;

    const float* x_re   = (const float*)d_in[0];
    const float* x_im   = (const float*)d_in[1];
    const float* emb_re = (const float*)d_in[2];
    const float* emb_im = (const float*)d_in[3];
    const float* enc_re = (const float*)d_in[4];
    const float* enc_im = (const float*)d_in[5];
    const float* out_re = (const float*)d_in[6];
    const float* out_im = (const float*)d_in[7];
    float* out = (float*)d_out;

    // Workspace layout (floats). Same offsets as r41 (peIJ region now dead).
    float* ws = (float*)d_ws;
    size_t off = 0;
    off += (size_t)MM * NN * NN * 2;                                              // (dead peIJ)
    float*  peT  = (float*)(ws + off);  off += (size_t)MM * NN * NN * 2;          // hosts PA + WFrag
    float*  Ereg = (float*)(ws + off);  off += (size_t)3 * BB * MM * NHH * QDD * NN * 2; // hosts VFrag
    float2* QE   = (float2*)(ws + off); off += (size_t)BB * MM * NHH * NN * 2;    // 131072
    float2* A    = (float2*)(ws + off); off += (size_t)BB * NHH * NN * NN * 2;    // 8388608 fl
    float*  FRAG = (float*)(ws + off);  off += (size_t)BB * NHH * NN * NN;        // 4194304 fl

    // Region plan:
    //  1) convAB stages Abf/Bre at A start + WFrag (peT+1MB); e_mfma reads
    //     Abf/Bre -> QE + Ea/Kb fragments (FRAG) + VFragRe/Im (Ereg).
    //  2) score reads Ea/Kb(FRAG) + QE -> AwFrag (A +16.8MB) + PA (peT).
    //  3) res_mfma reads VFrag + AwFrag + PA -> ResFrag at A start.
    //  4) out_mfma reads ResFrag + WFrag -> out.
    unsigned int* AbfHi = (unsigned int*)A;
    unsigned int* AbfLo = AbfHi + (size_t)96 * QDD * DD;
    unsigned int* BreHi = AbfLo + (size_t)96 * QDD * DD;
    unsigned int* BreLo = BreHi + (size_t)32 * 256 * 128;

    unsigned int* EaHi = (unsigned int*)FRAG;                     // 4 x 1048576 uints
    unsigned int* EaLo = EaHi + (size_t)64 * 16384;               //  = 16.78MB exact
    unsigned int* KbHi = EaLo + (size_t)64 * 16384;
    unsigned int* KbLo = KbHi + (size_t)64 * 16384;

    unsigned int* VFragRe = (unsigned int*)Ereg;                  // 1.05M uints (4MB)
    unsigned int* VFragIm = VFragRe + (size_t)1048576;            // 4MB

    unsigned int* ResFrag = (unsigned int*)A;                     // 2.10M uints (8.4MB)
    unsigned int* AwFrag  = (unsigned int*)((float*)A + (size_t)4194304); // A+16.8MB, 8.4MB
    float2* PA    = (float2*)peT;                                 // 0.5MB at peT start
    unsigned int* WFrag = (unsigned int*)(peT + 262144);          // 0.5MB at peT+1MB

    convAB_kernel<<<96 + 256 + 64, 256, 0, stream>>>(emb_re, emb_im, x_re, x_im,
                                                     out_re, out_im,
                                                     AbfHi, AbfLo, BreHi, BreLo, WFrag);
    e_mfma_kernel<<<512, 256, 0, stream>>>(
        (const unsigned short*)AbfHi, (const unsigned short*)AbfLo,
        (const unsigned short*)BreHi, (const unsigned short*)BreLo,
        enc_re, enc_im, QE,
        EaHi, EaLo, KbHi, KbLo, VFragRe, VFragIm);
    score_kernel<<<1024, 256, 0, stream>>>(
        (const unsigned short*)EaHi, (const unsigned short*)EaLo,
        (const unsigned short*)KbHi, (const unsigned short*)KbLo,
        QE, AwFrag, PA);
    res_mfma_kernel<<<512, 256, 0, stream>>>(VFragRe, VFragIm, AwFrag, PA,
                                             enc_re, enc_im, ResFrag);
    out_mfma_kernel<<<512, 256, 0, stream>>>(ResFrag, WFrag, out);
}

// Round 43
// 81.508 us; speedup vs baseline: 1.7108x; 1.0263x over previous
//
#include <hip/hip_runtime.h>
#include <math.h>

// Problem constants (from reference)
#define BB   8      // batch
#define MM   4      // MAXM
#define DD   128    // DIM
#define NHH  8      // heads
#define QDD  16     // head dim
#define NN   256    // H*W
#define KO   128    // NH*QD

typedef __attribute__((ext_vector_type(8))) short bf16x8;   // 8 bf16 (4 VGPR)
typedef __attribute__((ext_vector_type(4))) float f32x4;    // MFMA acc

__device__ inline unsigned short f2bf(float f) {            // RNE float->bf16
    union { float f; unsigned u; } v; v.f = f;
    unsigned r = v.u + 0x7FFF + ((v.u >> 16) & 1);
    return (unsigned short)(r >> 16);
}
__device__ inline float bf2f(unsigned short h) {
    union { unsigned u; float f; } v; v.u = ((unsigned)h) << 16;
    return v.f;
}
// split x = hi + lo (both bf16)
__device__ inline void bfsplit(float x, unsigned short& hi, unsigned short& lo) {
    hi = f2bf(x);
    lo = f2bf(x - bf2f(hi));
}
// e_mfma: (br | -bi<<16) -> (bi | br<<16)
__device__ inline bf16x8 derive_im(bf16x8 v) {
    union { bf16x8 v; unsigned u[4]; } in, out;
    in.v = v;
#pragma unroll
    for (int w = 0; w < 4; ++w)
        out.u[w] = ((in.u[w] >> 16) ^ 0x8000u) | (in.u[w] << 16);
    return out.v;
}
// a_mfma: (kx | ky<<16) -> (ky | (-kx)<<16)
__device__ inline bf16x8 derive_im2(bf16x8 v) {
    union { bf16x8 v; unsigned u[4]; } in, out;
    in.v = v;
#pragma unroll
    for (int w = 0; w < 4; ++w)
        out.u[w] = (in.u[w] >> 16) | ((in.u[w] ^ 0x8000u) << 16);
    return out.v;
}

// ---------------------------------------------------------------------------
// Kernel 1 (merged convA+convB+convW+peTab):
// blocks 0..95: emb -> A' split-bf16 ; 96..351: x -> Bre split-bf16 ;
// 352..415: w_out -> WFrag A-fragments ; 416..419: pe table (31x31x4, 30KB).
// peTab[((dy+15)*31 + dx+15)*4 + m] = ((dx+i*dy)/r)^m  (bitwise same math
// as the old pe_kernel / pe_base recurrence).
// ---------------------------------------------------------------------------
__global__ void convAB_kernel(const float* __restrict__ er, const float* __restrict__ ei,
                              const float* __restrict__ xr, const float* __restrict__ xi,
                              const float* __restrict__ wor, const float* __restrict__ woi,
                              unsigned int* __restrict__ AbfHi, unsigned int* __restrict__ AbfLo,
                              unsigned int* __restrict__ BreHi, unsigned int* __restrict__ BreLo,
                              unsigned int* __restrict__ WFrag,
                              float2* __restrict__ peTab) {
    if (blockIdx.x >= 416) {
        int m = blockIdx.x - 416;         // 0..3 (block-uniform)
        for (int e = threadIdx.x; e < 961; e += 256) {
            int dy = e / 31 - 15;
            int dx = e % 31 - 15;
            float fdy = (float)dy, fdx = (float)dx;
            float r2 = fdx * fdx + fdy * fdy;
            float c1 = 1.f, s1 = 0.f;
            if (r2 > 0.f) {
                float rinv = rsqrtf(r2);
                c1 = fdx * rinv; s1 = fdy * rinv;
            }
            float c = 1.f, s = 0.f;
            for (int k = 0; k < m; ++k) {
                float nc = c * c1 - s * s1;
                s = c * s1 + s * c1;
                c = nc;
            }
            peTab[e * 4 + m] = make_float2(c, s);
        }
        return;
    }
    if (blockIdx.x < 96) {
        int tmh = blockIdx.x;             // 0..95
        int base = tmh * QDD * DD;
#pragma unroll
        for (int it = 0; it < 8; ++it) {
            int idx = threadIdx.x + it * 256;  // q*128+D
            float ar = er[base + idx];
            float ai = ei[base + idx];
            unsigned short arh, arl, aih, ail;
            bfsplit(ar, arh, arl);
            bfsplit(ai, aih, ail);
            AbfHi[base + idx] = (unsigned int)arh | ((unsigned int)aih << 16);
            AbfLo[base + idx] = (unsigned int)arl | ((unsigned int)ail << 16);
        }
        return;
    }
    if (blockIdx.x >= 352) {
        // convW: WFrag A-operand fragments.
        int c = blockIdx.x - 352;         // 0..63
        int m = c >> 4;
        int dt = (c >> 1) & 7;
        int kshalf = c & 1;
        int tid = threadIdx.x;
        int wav = tid >> 6, lane = tid & 63;
        int ks = kshalf * 4 + wav;
        int D = dt * 16 + (lane & 15);
        unsigned int uu[8];
#pragma unroll
        for (int r = 0; r < 8; ++r) {
            int K2 = ks * 32 + ((lane >> 4) * 8) + r;
            int k = K2 >> 1;
            float v = (K2 & 1) ? woi[(m * DD + D) * KO + k] : wor[(m * DD + D) * KO + k];
            unsigned short hh, ll;
            bfsplit(v, hh, ll);
            uu[r] = (unsigned int)hh | ((unsigned int)ll << 16);
        }
        unsigned int* wp = WFrag + (((size_t)(m * 8 + dt) * 8 + ks) * 64 + lane) * 8;
        *(uint4*)wp = make_uint4(uu[0], uu[1], uu[2], uu[3]);
        *(uint4*)(wp + 4) = make_uint4(uu[4], uu[5], uu[6], uu[7]);
        return;
    }
    int bid = blockIdx.x - 96;            // 0..255 = 32 bm x 8 Dg
    int bm = bid >> 3;
    int Dg = bid & 7;
    int D0 = Dg * 16;
    int tid = threadIdx.x;

    __shared__ float sxr[16][257];
    __shared__ float sxi[16][257];

    const float* xrp = xr + (size_t)bm * DD * NN;
    const float* xip = xi + (size_t)bm * DD * NN;
#pragma unroll
    for (int it = 0; it < 16; ++it) {
        int i2 = tid + it * 256;
        int r = i2 >> 8, c = i2 & 255;
        sxr[r][c] = xrp[(size_t)(D0 + r) * NN + c];
        sxi[r][c] = xip[(size_t)(D0 + r) * NN + c];
    }
    __syncthreads();

    int n = tid;
    unsigned int reh[16], rel_[16];
#pragma unroll
    for (int d = 0; d < 16; ++d) {
        float br = sxr[d][n];
        float bi = sxi[d][n];
        unsigned short brh, brl, bih, bil;
        bfsplit(br, brh, brl);
        bfsplit(bi, bih, bil);
        reh[d]  = (unsigned int)brh | ((unsigned int)(bih ^ 0x8000) << 16);
        rel_[d] = (unsigned int)brl | ((unsigned int)(bil ^ 0x8000) << 16);
    }
    size_t ob = (size_t)bm * 32768 + (size_t)n * 128 + D0;
#pragma unroll
    for (int w = 0; w < 4; ++w) {
        ((uint4*)(BreHi + ob))[w] = make_uint4(reh[4*w], reh[4*w+1], reh[4*w+2], reh[4*w+3]);
        ((uint4*)(BreLo + ob))[w] = make_uint4(rel_[4*w], rel_[4*w+1], rel_[4*w+2], rel_[4*w+3]);
    }
}

// ---------------------------------------------------------------------------
// Kernel 2 (e_mfma v6: fused qe + Ea/Kb fragments + VFrag emission):
// block = (pair, h, nhalf). 512 blocks.
// ---------------------------------------------------------------------------
__global__ __launch_bounds__(256, 2)
void e_mfma_kernel(const unsigned short* __restrict__ AbfHi,
                   const unsigned short* __restrict__ AbfLo,
                   const unsigned short* __restrict__ BreHi,
                   const unsigned short* __restrict__ BreLo,
                   const float* __restrict__ encr, const float* __restrict__ enci,
                   float2* __restrict__ QE,
                   unsigned int* __restrict__ EaHi, unsigned int* __restrict__ EaLo,
                   unsigned int* __restrict__ KbHi, unsigned int* __restrict__ KbLo,
                   unsigned int* __restrict__ VFragRe, unsigned int* __restrict__ VFragIm) {
    int bid = blockIdx.x;                 // 512 = 8 xcd x 64 idx
    int xcd = bid & 7;
    int idx = bid >> 3;                   // 0..63
    int pair = xcd * 4 + (idx & 3);       // b*MM+m (XCD-pinned B panels)
    int h = (idx >> 2) & 7;               // 0..7
    int nhalf = idx >> 5;                 // 0..1
    int b = pair >> 2, m = pair & 3;
    int tid = threadIdx.x;
    int wav = tid >> 6, lane = tid & 63;
    int lo = lane & 15, hi = lane >> 4;

    __shared__ float2 sv[16][130];        // V transpose staging (16.6 KB)

    const unsigned short* AH[3];
    const unsigned short* AL[3];
#pragma unroll
    for (int t = 0; t < 3; ++t) {
        size_t aoff = ((size_t)((t * MM + m) * NHH + h)) * QDD * 256;
        AH[t] = AbfHi + aoff;
        AL[t] = AbfLo + aoff;
    }
    size_t boff = (size_t)pair * 256 * 256;
    const unsigned short* BrH = BreHi + boff;
    const unsigned short* BrL = BreLo + boff;

    f32x4 accRe[3][2], accIm[3][2];
#pragma unroll
    for (int t = 0; t < 3; ++t)
#pragma unroll
        for (int nt = 0; nt < 2; ++nt) {
            accRe[t][nt] = (f32x4)(0.f);
            accIm[t][nt] = (f32x4)(0.f);
        }

#pragma unroll
    for (int ks = 0; ks < 8; ++ks) {
        int k0 = ks * 32;
        int arow = lo * 256 + k0 + hi * 8;
        bf16x8 aH[3], aL[3];
#pragma unroll
        for (int t = 0; t < 3; ++t) {
            aH[t] = *(const bf16x8*)(AH[t] + arow);
            aL[t] = *(const bf16x8*)(AL[t] + arow);
        }
#pragma unroll
        for (int nt = 0; nt < 2; ++nt) {
            int n0 = nhalf * 128 + (wav * 2 + nt) * 16;
            size_t brow = (size_t)(n0 + lo) * 256 + k0 + hi * 8;
            bf16x8 brh = *(const bf16x8*)(BrH + brow);
            bf16x8 brl = *(const bf16x8*)(BrL + brow);
            bf16x8 bih = derive_im(brh);
            bf16x8 bil = derive_im(brl);
#pragma unroll
            for (int t = 0; t < 3; ++t) {
                accRe[t][nt] = __builtin_amdgcn_mfma_f32_16x16x32_bf16(aH[t], brh, accRe[t][nt], 0, 0, 0);
                accRe[t][nt] = __builtin_amdgcn_mfma_f32_16x16x32_bf16(aH[t], brl, accRe[t][nt], 0, 0, 0);
                accRe[t][nt] = __builtin_amdgcn_mfma_f32_16x16x32_bf16(aL[t], brh, accRe[t][nt], 0, 0, 0);
                accIm[t][nt] = __builtin_amdgcn_mfma_f32_16x16x32_bf16(aH[t], bih, accIm[t][nt], 0, 0, 0);
                accIm[t][nt] = __builtin_amdgcn_mfma_f32_16x16x32_bf16(aH[t], bil, accIm[t][nt], 0, 0, 0);
                accIm[t][nt] = __builtin_amdgcn_mfma_f32_16x16x32_bf16(aL[t], bih, accIm[t][nt], 0, 0, 0);
            }
        }
    }

    int bh = b * NHH + h;

    // t=2 (V) -> LDS staging (block covers q 0..15 x j-local 0..127)
#pragma unroll
    for (int nt = 0; nt < 2; ++nt) {
        int nl = (wav * 2 + nt) * 16;
#pragma unroll
        for (int reg = 0; reg < 4; ++reg)
            sv[hi * 4 + reg][nl + lo] = make_float2(accRe[2][nt][reg], accIm[2][nt][reg]);
    }

    // --- fused qe: QE[b,m,h,i] = sum_q conj(E0[q,i])*enc0[m,h,q] ---
    {
        float cr[4], ci[4];
#pragma unroll
        for (int reg = 0; reg < 4; ++reg) {
            int q = hi * 4 + reg;
            int eb = (m * NHH + h) * QDD + q;
            cr[reg] = encr[eb];
            ci[reg] = enci[eb];
        }
#pragma unroll
        for (int nt = 0; nt < 2; ++nt) {
            int n0 = nhalf * 128 + (wav * 2 + nt) * 16;
            float sr = 0.f, si = 0.f;
#pragma unroll
            for (int reg = 0; reg < 4; ++reg) {
                float erv = accRe[0][nt][reg];
                float eiv = accIm[0][nt][reg];
                sr = fmaf(erv, cr[reg], fmaf( eiv, ci[reg], sr));
                si = fmaf(erv, ci[reg], fmaf(-eiv, cr[reg], si));
            }
            sr += __shfl_xor(sr, 16); si += __shfl_xor(si, 16);
            sr += __shfl_xor(sr, 32); si += __shfl_xor(si, 32);
            if (hi == 0)
                QE[(size_t)((b * MM + m) * NHH + h) * NN + n0 + lo] = make_float2(sr, si);
        }
    }

    // t=0: Ea fragments ; t=1: Kb fragments.
#pragma unroll
    for (int t = 0; t < 2; ++t) {
#pragma unroll
        for (int nt = 0; nt < 2; ++nt) {
            int n0 = nhalf * 128 + (wav * 2 + nt) * 16;
            unsigned int hiU[4], loU[4];
#pragma unroll
            for (int reg = 0; reg < 4; ++reg) {
                unsigned short rh, rl, ih, il;
                bfsplit(accRe[t][nt][reg], rh, rl);
                bfsplit(accIm[t][nt][reg], ih, il);
                hiU[reg] = (unsigned int)rh | ((unsigned int)ih << 16);
                loU[reg] = (unsigned int)rl | ((unsigned int)il << 16);
            }
            int r = n0 >> 4;
            size_t fo = (size_t)bh * 16384 + (size_t)((r * 4 + m) * 64 + lane) * 4;
            unsigned int* tH = (t == 0) ? EaHi : KbHi;
            unsigned int* tL = (t == 0) ? EaLo : KbLo;
            *(uint4*)(tH + fo) = make_uint4(hiU[0], hiU[1], hiU[2], hiU[3]);
            *(uint4*)(tL + fo) = make_uint4(loU[0], loU[1], loU[2], loU[3]);
        }
    }

    __syncthreads();

    // VFrag emission: wave wav -> ks = nhalf*4 + wav.
    {
        int ks = nhalf * 4 + wav;
        unsigned int uR[8], uI[8];
#pragma unroll
        for (int r = 0; r < 8; ++r) {
            float2 v = sv[lo][wav * 32 + hi * 8 + r];
            unsigned short rh, rl, ih2, il2;
            bfsplit(v.x, rh, rl);
            bfsplit(v.y, ih2, il2);
            uR[r] = (unsigned int)rh | ((unsigned int)rl << 16);
            uI[r] = (unsigned int)ih2 | ((unsigned int)il2 << 16);
        }
        size_t vo = ((((size_t)((b * MM + m) * NHH + h)) * 8 + ks) * 64 + lane) * 8;
        *(uint4*)(VFragRe + vo)     = make_uint4(uR[0], uR[1], uR[2], uR[3]);
        *(uint4*)(VFragRe + vo + 4) = make_uint4(uR[4], uR[5], uR[6], uR[7]);
        *(uint4*)(VFragIm + vo)     = make_uint4(uI[0], uI[1], uI[2], uI[3]);
        *(uint4*)(VFragIm + vo + 4) = make_uint4(uI[4], uI[5], uI[6], uI[7]);
    }
}

// ---------------------------------------------------------------------------
// Kernel 3 (score = FUSED a_mfma + softmax + PA; pe via 30KB L1-resident
// lookup table): 1024 blocks = (bh, itile).
// ---------------------------------------------------------------------------
__global__ __launch_bounds__(256, 2)
void score_kernel(const unsigned short* __restrict__ EaHi,
                  const unsigned short* __restrict__ EaLo,
                  const unsigned short* __restrict__ KbHi,
                  const unsigned short* __restrict__ KbLo,
                  const float2* __restrict__ QE,
                  const float2* __restrict__ peTab,
                  unsigned int* __restrict__ AwFrag,
                  float2* __restrict__ PA) {
    int bid = blockIdx.x;                 // 1024 = 8 xcd x 128 idx
    int xcd = bid & 7;
    int idx = bid >> 3;                   // 0..127
    int bh = xcd * 8 + (idx & 7);         // K-panel XCD-pinned
    int it = idx >> 3;                    // 0..15 i-tile
    int b = bh >> 3, h = bh & 7;
    int tid = threadIdx.x;
    int wav = tid >> 6, lane = tid & 63;
    int lo = lane & 15, hi = lane >> 4;

    const unsigned short* EaH = EaHi + (size_t)bh * 32768;
    const unsigned short* EaL = EaLo + (size_t)bh * 32768;
    const unsigned short* KbH = KbHi + (size_t)bh * 32768;
    const unsigned short* KbL = KbLo + (size_t)bh * 32768;

    __shared__ float st[16][257];         // aw staging (block's 16 rows x 256 j)
    __shared__ float sredA[16][4];        // cross-wave max
    __shared__ float sredB[16][4];        // cross-wave sum
    __shared__ float sPA[16][4][2][4];    // PA partials [row][m][comp][wav]

    f32x4 accRe[4], accIm[4];
#pragma unroll
    for (int nt = 0; nt < 4; ++nt) { accRe[nt] = (f32x4)(0.f); accIm[nt] = (f32x4)(0.f); }

#pragma unroll
    for (int ks = 0; ks < 4; ++ks) {
        size_t arow = (size_t)((it * 4 + ks) * 64 + lane) * 8;   // coalesced
        bf16x8 aH = *(const bf16x8*)(EaH + arow);
        bf16x8 aL = *(const bf16x8*)(EaL + arow);
#pragma unroll
        for (int nt = 0; nt < 4; ++nt) {
            int jt = wav * 4 + nt;
            size_t brow = (size_t)((jt * 4 + ks) * 64 + lane) * 8;  // coalesced
            bf16x8 brh = *(const bf16x8*)(KbH + brow);
            bf16x8 brl = *(const bf16x8*)(KbL + brow);
            bf16x8 bih = derive_im2(brh);
            bf16x8 bil = derive_im2(brl);
            accRe[nt] = __builtin_amdgcn_mfma_f32_16x16x32_bf16(aH, brh, accRe[nt], 0, 0, 0);
            accRe[nt] = __builtin_amdgcn_mfma_f32_16x16x32_bf16(aH, brl, accRe[nt], 0, 0, 0);
            accRe[nt] = __builtin_amdgcn_mfma_f32_16x16x32_bf16(aL, brh, accRe[nt], 0, 0, 0);
            accIm[nt] = __builtin_amdgcn_mfma_f32_16x16x32_bf16(aH, bih, accIm[nt], 0, 0, 0);
            accIm[nt] = __builtin_amdgcn_mfma_f32_16x16x32_bf16(aH, bil, accIm[nt], 0, 0, 0);
            accIm[nt] = __builtin_amdgcn_mfma_f32_16x16x32_bf16(aL, bih, accIm[nt], 0, 0, 0);
        }
    }

    // pass 1: + sum_m QE*pe (pe via table), magnitude. vmag[nt][reg].
    float vmag[4][4];
#pragma unroll
    for (int reg = 0; reg < 4; ++reg) {
        int i = it * 16 + hi * 4 + reg;
        float2 qe4[MM];
#pragma unroll
        for (int m = 0; m < MM; ++m)
            qe4[m] = QE[(size_t)((b * MM + m) * NHH + h) * NN + i];
#pragma unroll
        for (int nt = 0; nt < 4; ++nt) {
            int j = (wav * 4 + nt) * 16 + lo;
            int dy = (j >> 4) - (i >> 4);
            int dx = (j & 15) - (i & 15);
            const float2* pt = peTab + ((dy + 15) * 31 + (dx + 15)) * 4;
            float ar = accRe[nt][reg];
            float ai = accIm[nt][reg];
#pragma unroll
            for (int m = 0; m < MM; ++m) {
                float2 p = pt[m];
                ar = fmaf(qe4[m].x, p.x, fmaf(-qe4[m].y, p.y, ar));
                ai = fmaf(qe4[m].x, p.y, fmaf( qe4[m].y, p.x, ai));
            }
            vmag[nt][reg] = sqrtf(fmaf(ar, ar, ai * ai)) * 0.25f;
        }
    }

    // row max: over nt regs, then 16-lane lo group, then cross-wave via LDS.
    float mxr[4];
#pragma unroll
    for (int reg = 0; reg < 4; ++reg) {
        mxr[reg] = fmaxf(fmaxf(vmag[0][reg], vmag[1][reg]),
                         fmaxf(vmag[2][reg], vmag[3][reg]));
#pragma unroll
        for (int off = 1; off < 16; off <<= 1)
            mxr[reg] = fmaxf(mxr[reg], __shfl_xor(mxr[reg], off));
    }
    if (lo == 0) {
#pragma unroll
        for (int reg = 0; reg < 4; ++reg) sredA[hi * 4 + reg][wav] = mxr[reg];
    }
    __syncthreads();
    float mx[4];
#pragma unroll
    for (int reg = 0; reg < 4; ++reg) {
        int r = hi * 4 + reg;
        mx[reg] = fmaxf(fmaxf(sredA[r][0], sredA[r][1]),
                        fmaxf(sredA[r][2], sredA[r][3]));
    }

    // exp + row sum
    float smr[4];
#pragma unroll
    for (int reg = 0; reg < 4; ++reg) smr[reg] = 0.f;
#pragma unroll
    for (int nt = 0; nt < 4; ++nt)
#pragma unroll
        for (int reg = 0; reg < 4; ++reg) {
            vmag[nt][reg] = __expf(vmag[nt][reg] - mx[reg]);
            smr[reg] += vmag[nt][reg];
        }
#pragma unroll
    for (int reg = 0; reg < 4; ++reg) {
#pragma unroll
        for (int off = 1; off < 16; off <<= 1)
            smr[reg] += __shfl_xor(smr[reg], off);
    }
    if (lo == 0) {
#pragma unroll
        for (int reg = 0; reg < 4; ++reg) sredB[hi * 4 + reg][wav] = smr[reg];
    }
    __syncthreads();
    float inv[4];
#pragma unroll
    for (int reg = 0; reg < 4; ++reg) {
        int r = hi * 4 + reg;
        inv[reg] = 1.f / (sredB[r][0] + sredB[r][1] + sredB[r][2] + sredB[r][3]);
    }

    // pass 2: aw -> st; PA partials per (m, reg row); pe via table again.
    float par[MM][4], pai[MM][4];
#pragma unroll
    for (int m = 0; m < MM; ++m)
#pragma unroll
        for (int reg = 0; reg < 4; ++reg) { par[m][reg] = 0.f; pai[m][reg] = 0.f; }
#pragma unroll
    for (int reg = 0; reg < 4; ++reg) {
        int i = it * 16 + hi * 4 + reg;
#pragma unroll
        for (int nt = 0; nt < 4; ++nt) {
            int j = (wav * 4 + nt) * 16 + lo;
            float aw = vmag[nt][reg] * inv[reg];
            st[hi * 4 + reg][j] = aw;
            int dy = (j >> 4) - (i >> 4);
            int dx = (j & 15) - (i & 15);
            const float2* pt = peTab + ((dy + 15) * 31 + (dx + 15)) * 4;
#pragma unroll
            for (int m = 0; m < MM; ++m) {
                float2 p = pt[m];
                par[m][reg] = fmaf(p.x, aw, par[m][reg]);
                pai[m][reg] = fmaf(p.y, aw, pai[m][reg]);
            }
        }
    }
#pragma unroll
    for (int m = 0; m < MM; ++m)
#pragma unroll
        for (int reg = 0; reg < 4; ++reg) {
#pragma unroll
            for (int off = 1; off < 16; off <<= 1) {
                par[m][reg] += __shfl_xor(par[m][reg], off);
                pai[m][reg] += __shfl_xor(pai[m][reg], off);
            }
        }
    if (lo == 0) {
#pragma unroll
        for (int m = 0; m < MM; ++m)
#pragma unroll
            for (int reg = 0; reg < 4; ++reg) {
                sPA[hi * 4 + reg][m][0][wav] = par[m][reg];
                sPA[hi * 4 + reg][m][1][wav] = pai[m][reg];
            }
    }
    __syncthreads();

    if (tid < 16) {
        int r = tid;
#pragma unroll
        for (int m = 0; m < MM; ++m) {
            float pr  = sPA[r][m][0][0] + sPA[r][m][0][1] + sPA[r][m][0][2] + sPA[r][m][0][3];
            float pim = sPA[r][m][1][0] + sPA[r][m][1][1] + sPA[r][m][1][2] + sPA[r][m][1][3];
            PA[(size_t)((b * MM + m) * NHH + h) * NN + it * 16 + r] = make_float2(pr, pim);
        }
    }

    // Aw fragment emission: wave wav handles ks = wav*2 + {0,1}.
#pragma unroll
    for (int ksl = 0; ksl < 2; ++ksl) {
        int ks = wav * 2 + ksl;
        unsigned int uu[8];
#pragma unroll
        for (int r = 0; r < 8; ++r) {
            float aw = st[lo][ks * 32 + hi * 8 + r];
            unsigned short h2, l2;
            bfsplit(aw, h2, l2);
            uu[r] = (unsigned int)h2 | ((unsigned int)l2 << 16);
        }
        unsigned int* ap = AwFrag + ((((size_t)bh * 16 + it) * 8 + ks) * 64 + lane) * 8;
        *(uint4*)ap = make_uint4(uu[0], uu[1], uu[2], uu[3]);
        *(uint4*)(ap + 4) = make_uint4(uu[4], uu[5], uu[6], uu[7]);
    }
}

// ---------------------------------------------------------------------------
// Kernel 4 (res_mfma v3: pure fragment-load + MFMA; V pre-split by e_mfma):
// 512 blocks = (bh, ih). Wave = m. Emits ResFrag for out_mfma.
// ---------------------------------------------------------------------------
__global__ __launch_bounds__(256, 2)
void res_mfma_kernel(const unsigned int* __restrict__ VFragRe,
                     const unsigned int* __restrict__ VFragIm,
                     const unsigned int* __restrict__ AwFrag,
                     const float2* __restrict__ PA,
                     const float* __restrict__ encr, const float* __restrict__ enci,
                     unsigned int* __restrict__ ResFrag) {
    int bid = blockIdx.x;                 // 512 = 8 xcd x 64 idx
    int xcd = bid & 7;
    int idx = bid >> 3;                   // 0..63
    int bh = xcd * 8 + (idx & 7);         // XCD-pinned panels
    int ih = idx >> 3;                    // 0..7 (i-eighth: 2 i-tiles)
    int b = bh >> 3, h = bh & 7;
    int tid = threadIdx.x;
    int m = tid >> 6;                     // wave = m
    int lane = tid & 63;
    int lo = lane & 15, hi = lane >> 4;

    f32x4 accRe[2], accIm[2];
#pragma unroll
    for (int t2 = 0; t2 < 2; ++t2) { accRe[t2] = (f32x4)(0.f); accIm[t2] = (f32x4)(0.f); }

#pragma unroll
    for (int ks = 0; ks < 8; ++ks) {
        size_t vo = ((((size_t)((b * MM + m) * NHH + h)) * 8 + ks) * 64 + lane) * 8;
        uint4 vr0 = *(const uint4*)(VFragRe + vo);
        uint4 vr1 = *(const uint4*)(VFragRe + vo + 4);
        uint4 vi0 = *(const uint4*)(VFragIm + vo);
        uint4 vi1 = *(const uint4*)(VFragIm + vo + 4);
        unsigned int uR[8] = {vr0.x, vr0.y, vr0.z, vr0.w, vr1.x, vr1.y, vr1.z, vr1.w};
        unsigned int uI[8] = {vi0.x, vi0.y, vi0.z, vi0.w, vi1.x, vi1.y, vi1.z, vi1.w};
        union { bf16x8 v; unsigned short s[8]; } vrh, vrl, vih, vil;
#pragma unroll
        for (int r = 0; r < 8; ++r) {
            vrh.s[r] = (unsigned short)(uR[r] & 0xffffu);
            vrl.s[r] = (unsigned short)(uR[r] >> 16);
            vih.s[r] = (unsigned short)(uI[r] & 0xffffu);
            vil.s[r] = (unsigned short)(uI[r] >> 16);
        }
#pragma unroll
        for (int t2 = 0; t2 < 2; ++t2) {
            int it = ih * 2 + t2;
            const unsigned int* ap = AwFrag + ((((size_t)bh * 16 + it) * 8 + ks) * 64 + lane) * 8;
            uint4 u0 = *(const uint4*)ap;
            uint4 u1 = *(const uint4*)(ap + 4);
            unsigned int uu[8] = {u0.x, u0.y, u0.z, u0.w, u1.x, u1.y, u1.z, u1.w};
            union { bf16x8 v; unsigned short s[8]; } awh, awl;
#pragma unroll
            for (int r = 0; r < 8; ++r) {
                awh.s[r] = (unsigned short)(uu[r] & 0xffffu);
                awl.s[r] = (unsigned short)(uu[r] >> 16);
            }
            accRe[t2] = __builtin_amdgcn_mfma_f32_16x16x32_bf16(vrh.v, awh.v, accRe[t2], 0, 0, 0);
            accRe[t2] = __builtin_amdgcn_mfma_f32_16x16x32_bf16(vrh.v, awl.v, accRe[t2], 0, 0, 0);
            accRe[t2] = __builtin_amdgcn_mfma_f32_16x16x32_bf16(vrl.v, awh.v, accRe[t2], 0, 0, 0);
            accIm[t2] = __builtin_amdgcn_mfma_f32_16x16x32_bf16(vih.v, awh.v, accIm[t2], 0, 0, 0);
            accIm[t2] = __builtin_amdgcn_mfma_f32_16x16x32_bf16(vih.v, awl.v, accIm[t2], 0, 0, 0);
            accIm[t2] = __builtin_amdgcn_mfma_f32_16x16x32_bf16(vil.v, awh.v, accIm[t2], 0, 0, 0);
        }
    }

    // epilogue: C/D layout col=lo (i in tile), row=hi*4+reg (q).
    float e1r[4], e1i[4];
#pragma unroll
    for (int reg = 0; reg < 4; ++reg) {
        int q = hi * 4 + reg;
        int eb = ((MM + m) * NHH + h) * QDD + q;   // enc[1,m,h,q]
        e1r[reg] = encr[eb];
        e1i[reg] = enci[eb];
    }
    int bm = b * MM + m;
#pragma unroll
    for (int t2 = 0; t2 < 2; ++t2) {
        int nt = ih * 2 + t2;
        int i = nt * 16 + lo;
        float2 pa = PA[(size_t)((b * MM + m) * NHH + h) * NN + i];
        unsigned int uu[8];
#pragma unroll
        for (int reg = 0; reg < 4; ++reg) {
            float rr = accRe[t2][reg] + e1r[reg] * pa.x - e1i[reg] * pa.y;
            float ri = accIm[t2][reg] + e1r[reg] * pa.y + e1i[reg] * pa.x;
            unsigned short hh, ll;
            bfsplit(rr, hh, ll);
            uu[2 * reg] = (unsigned int)hh | ((unsigned int)ll << 16);
            bfsplit(-ri, hh, ll);
            uu[2 * reg + 1] = (unsigned int)hh | ((unsigned int)ll << 16);
        }
        unsigned int* rp = ResFrag + ((((size_t)bm * 16 + nt) * 8 + h) * 64 + lane) * 8;
        *(uint4*)rp = make_uint4(uu[0], uu[1], uu[2], uu[3]);
        *(uint4*)(rp + 4) = make_uint4(uu[4], uu[5], uu[6], uu[7]);
    }
}

// ---------------------------------------------------------------------------
// Kernel 5 (out_mfma: out = w_out x res via MFMA over K2=2k):
// 512 blocks = (bm, dt, nhalf); wave handles 2 ntiles.
// ---------------------------------------------------------------------------
__global__ __launch_bounds__(256, 2)
void out_mfma_kernel(const unsigned int* __restrict__ ResFrag,
                     const unsigned int* __restrict__ WFrag,
                     float* __restrict__ out) {
    int bid = blockIdx.x;                 // 512 = 8 xcd x 64 idx
    int xcd = bid & 7;
    int idx = bid >> 3;                   // 0..63
    int bm = xcd * 4 + (idx & 3);         // XCD-pinned
    int rest = idx >> 2;                  // 0..15
    int dt = rest >> 1;                   // 0..7
    int nh = rest & 1;
    int m = bm & 3;
    int tid = threadIdx.x;
    int wav = tid >> 6, lane = tid & 63;
    int lo = lane & 15, hi = lane >> 4;

    f32x4 accRe[2], accIm[2];
#pragma unroll
    for (int t = 0; t < 2; ++t) { accRe[t] = (f32x4)(0.f); accIm[t] = (f32x4)(0.f); }

#pragma unroll
    for (int ks = 0; ks < 8; ++ks) {
        const unsigned int* wp = WFrag + (((size_t)(m * 8 + dt) * 8 + ks) * 64 + lane) * 8;
        uint4 w0 = *(const uint4*)wp;
        uint4 w1 = *(const uint4*)(wp + 4);
        unsigned int wu[8] = {w0.x, w0.y, w0.z, w0.w, w1.x, w1.y, w1.z, w1.w};
        union { bf16x8 v; unsigned short s[8]; } aH, aL;
#pragma unroll
        for (int r = 0; r < 8; ++r) {
            aH.s[r] = (unsigned short)(wu[r] & 0xffffu);
            aL.s[r] = (unsigned short)(wu[r] >> 16);
        }
#pragma unroll
        for (int nt2 = 0; nt2 < 2; ++nt2) {
            int nt = nh * 8 + wav * 2 + nt2;
            const unsigned int* rp = ResFrag + ((((size_t)bm * 16 + nt) * 8 + ks) * 64 + lane) * 8;
            uint4 r0 = *(const uint4*)rp;
            uint4 r1 = *(const uint4*)(rp + 4);
            unsigned int ru[8] = {r0.x, r0.y, r0.z, r0.w, r1.x, r1.y, r1.z, r1.w};
            union { bf16x8 v; unsigned short s[8]; } brH, brL, biH, biL;
#pragma unroll
            for (int t = 0; t < 4; ++t) {
                unsigned int ue = ru[2 * t], uo = ru[2 * t + 1];
                brH.s[2 * t]     = (unsigned short)(ue & 0xffffu);
                brL.s[2 * t]     = (unsigned short)(ue >> 16);
                brH.s[2 * t + 1] = (unsigned short)(uo & 0xffffu);
                brL.s[2 * t + 1] = (unsigned short)(uo >> 16);
                biH.s[2 * t]     = (unsigned short)((uo & 0xffffu) ^ 0x8000u);
                biL.s[2 * t]     = (unsigned short)((uo >> 16) ^ 0x8000u);
                biH.s[2 * t + 1] = (unsigned short)(ue & 0xffffu);
                biL.s[2 * t + 1] = (unsigned short)(ue >> 16);
            }
            accRe[nt2] = __builtin_amdgcn_mfma_f32_16x16x32_bf16(aH.v, brH.v, accRe[nt2], 0, 0, 0);
            accRe[nt2] = __builtin_amdgcn_mfma_f32_16x16x32_bf16(aH.v, brL.v, accRe[nt2], 0, 0, 0);
            accRe[nt2] = __builtin_amdgcn_mfma_f32_16x16x32_bf16(aL.v, brH.v, accRe[nt2], 0, 0, 0);
            accIm[nt2] = __builtin_amdgcn_mfma_f32_16x16x32_bf16(aH.v, biH.v, accIm[nt2], 0, 0, 0);
            accIm[nt2] = __builtin_amdgcn_mfma_f32_16x16x32_bf16(aH.v, biL.v, accIm[nt2], 0, 0, 0);
            accIm[nt2] = __builtin_amdgcn_mfma_f32_16x16x32_bf16(aL.v, biH.v, accIm[nt2], 0, 0, 0);
        }
    }

    // epilogue: C/D col = lo (n in tile), row = hi*4+reg (D in tile).
#pragma unroll
    for (int nt2 = 0; nt2 < 2; ++nt2) {
        int n = (nh * 8 + wav * 2 + nt2) * 16 + lo;
#pragma unroll
        for (int reg = 0; reg < 4; ++reg) {
            int D = dt * 16 + hi * 4 + reg;
            size_t ob = (size_t)(bm * DD + D) * NN + n;
            out[ob] = accRe[nt2][reg];
            out[(size_t)BB * MM * DD * NN + ob] = accIm[nt2][reg];
        }
    }
}

// ---------------------------------------------------------------------------
extern "C" void kernel_launch(void* const* d_in, const int* in_sizes, int n_in,
                              void* d_out, int out_size, void* d_ws, size_t ws_size,
                              hipStream_t stream) {
    (void)in_sizes; (void)n_in; (void)out_size; (void)ws_size;

    const float* x_re   = (const float*)d_in[0];
    const float* x_im   = (const float*)d_in[1];
    const float* emb_re = (const float*)d_in[2];
    const float* emb_im = (const float*)d_in[3];
    const float* enc_re = (const float*)d_in[4];
    const float* enc_im = (const float*)d_in[5];
    const float* out_re = (const float*)d_in[6];
    const float* out_im = (const float*)d_in[7];
    float* out = (float*)d_out;

    // Workspace layout (floats). Same offsets as r42; peTab in old peIJ region.
    float* ws = (float*)d_ws;
    size_t off = 0;
    float2* peTab = (float2*)ws;                                                  // 30KB in dead peIJ region
    off += (size_t)MM * NN * NN * 2;
    float*  peT  = (float*)(ws + off);  off += (size_t)MM * NN * NN * 2;          // hosts PA + WFrag
    float*  Ereg = (float*)(ws + off);  off += (size_t)3 * BB * MM * NHH * QDD * NN * 2; // hosts VFrag
    float2* QE   = (float2*)(ws + off); off += (size_t)BB * MM * NHH * NN * 2;    // 131072
    float2* A    = (float2*)(ws + off); off += (size_t)BB * NHH * NN * NN * 2;    // 8388608 fl
    float*  FRAG = (float*)(ws + off);  off += (size_t)BB * NHH * NN * NN;        // 4194304 fl

    // Region plan:
    //  1) convAB stages Abf/Bre at A start + WFrag (peT+1MB) + peTab; e_mfma
    //     reads Abf/Bre -> QE + Ea/Kb fragments (FRAG) + VFragRe/Im (Ereg).
    //  2) score reads Ea/Kb(FRAG) + QE + peTab -> AwFrag (A +16.8MB) + PA (peT).
    //  3) res_mfma reads VFrag + AwFrag + PA -> ResFrag at A start.
    //  4) out_mfma reads ResFrag + WFrag -> out.
    unsigned int* AbfHi = (unsigned int*)A;
    unsigned int* AbfLo = AbfHi + (size_t)96 * QDD * DD;
    unsigned int* BreHi = AbfLo + (size_t)96 * QDD * DD;
    unsigned int* BreLo = BreHi + (size_t)32 * 256 * 128;

    unsigned int* EaHi = (unsigned int*)FRAG;                     // 4 x 1048576 uints
    unsigned int* EaLo = EaHi + (size_t)64 * 16384;               //  = 16.78MB exact
    unsigned int* KbHi = EaLo + (size_t)64 * 16384;
    unsigned int* KbLo = KbHi + (size_t)64 * 16384;

    unsigned int* VFragRe = (unsigned int*)Ereg;                  // 1.05M uints (4MB)
    unsigned int* VFragIm = VFragRe + (size_t)1048576;            // 4MB

    unsigned int* ResFrag = (unsigned int*)A;                     // 2.10M uints (8.4MB)
    unsigned int* AwFrag  = (unsigned int*)((float*)A + (size_t)4194304); // A+16.8MB, 8.4MB
    float2* PA    = (float2*)peT;                                 // 0.5MB at peT start
    unsigned int* WFrag = (unsigned int*)(peT + 262144);          // 0.5MB at peT+1MB

    convAB_kernel<<<96 + 256 + 64 + 4, 256, 0, stream>>>(emb_re, emb_im, x_re, x_im,
                                                         out_re, out_im,
                                                         AbfHi, AbfLo, BreHi, BreLo,
                                                         WFrag, peTab);
    e_mfma_kernel<<<512, 256, 0, stream>>>(
        (const unsigned short*)AbfHi, (const unsigned short*)AbfLo,
        (const unsigned short*)BreHi, (const unsigned short*)BreLo,
        enc_re, enc_im, QE,
        EaHi, EaLo, KbHi, KbLo, VFragRe, VFragIm);
    score_kernel<<<1024, 256, 0, stream>>>(
        (const unsigned short*)EaHi, (const unsigned short*)EaLo,
        (const unsigned short*)KbHi, (const unsigned short*)KbLo,
        QE, peTab, AwFrag, PA);
    res_mfma_kernel<<<512, 256, 0, stream>>>(VFragRe, VFragIm, AwFrag, PA,
                                             enc_re, enc_im, ResFrag);
    out_mfma_kernel<<<512, 256, 0, stream>>>(ResFrag, WFrag, out);
}